// Round 1
// baseline (5242.801 us; speedup 1.0000x reference)
//
#include <hip/hip_runtime.h>

#define BLK 256

constexpr int BB   = 2048;  // batch
constexpr int CH   = 256;   // batch chunk for conv1/pool1/conv2
constexpr int NCH  = BB / CH;
constexpr int KD   = 2048;  // codebook size
constexpr int CD   = 400;   // feature dim

// ---------------- conv stack ----------------

// x: [B][200][5][5] (1 in-chan), out chunk: [CH][20][198][3][3], relu
__global__ __launch_bounds__(BLK) void conv1_k(const float* __restrict__ x,
                                               const float* __restrict__ w,
                                               const float* __restrict__ bias,
                                               float* __restrict__ out, int b0) {
    int idx = blockIdx.x * BLK + threadIdx.x;
    const int total = CH * 20 * 198 * 9;
    if (idx >= total) return;
    int ow = idx % 3;
    int oh = (idx / 3) % 3;
    int od = (idx / 9) % 198;
    int oc = (idx / (9 * 198)) % 20;
    int b  = idx / (9 * 198 * 20);
    const float* xin = x + (size_t)(b0 + b) * 5000;
    const float* wp  = w + oc * 27;
    float acc = bias[oc];
#pragma unroll
    for (int kd = 0; kd < 3; ++kd)
#pragma unroll
        for (int kh = 0; kh < 3; ++kh)
#pragma unroll
            for (int kw = 0; kw < 3; ++kw)
                acc += xin[(od + kd) * 25 + (oh + kh) * 5 + (ow + kw)] * wp[kd * 9 + kh * 3 + kw];
    out[idx] = fmaxf(acc, 0.f);
}

// h1: [CH][20][198][9] -> out: [CH][20][99][9], stride2 pad1 in D, no relu
__global__ __launch_bounds__(BLK) void pool1_k(const float* __restrict__ h1,
                                               const float* __restrict__ w,
                                               const float* __restrict__ bias,
                                               float* __restrict__ out) {
    int idx = blockIdx.x * BLK + threadIdx.x;
    const int total = CH * 20 * 99 * 9;
    if (idx >= total) return;
    int hw = idx % 9;
    int od = (idx / 9) % 99;
    int oc = (idx / (9 * 99)) % 20;
    int b  = idx / (9 * 99 * 20);
    float acc = bias[oc];
#pragma unroll
    for (int kd = 0; kd < 3; ++kd) {
        int id = od * 2 - 1 + kd;
        if (id < 0 || id >= 198) continue;
        const float* hp = h1 + ((size_t)b * 20 * 198 + id) * 9 + hw;
        const float* wp = w + oc * 60 + kd;  // w[oc][ic][kd]
        for (int ic = 0; ic < 20; ++ic)
            acc += hp[(size_t)ic * 198 * 9] * wp[ic * 3];
    }
    out[idx] = acc;
}

// h2: [CH][20][99][9] -> h3 global: [B][35][99], pad1 D, relu
__global__ __launch_bounds__(BLK) void conv2_k(const float* __restrict__ h2,
                                               const float* __restrict__ w,
                                               const float* __restrict__ bias,
                                               float* __restrict__ out, int b0) {
    int idx = blockIdx.x * BLK + threadIdx.x;
    const int total = CH * 35 * 99;
    if (idx >= total) return;
    int od = idx % 99;
    int oc = (idx / 99) % 35;
    int b  = idx / (99 * 35);
    float acc = bias[oc];
    for (int ic = 0; ic < 20; ++ic) {
        const float* wp = w + ((size_t)(oc * 20 + ic) * 3) * 9;  // [3][9]
        const float* hp = h2 + ((size_t)(b * 20 + ic) * 99) * 9;
#pragma unroll
        for (int kd = 0; kd < 3; ++kd) {
            int id = od - 1 + kd;
            if (id < 0 || id >= 99) continue;
            const float* hpp = hp + (size_t)id * 9;
#pragma unroll
            for (int j = 0; j < 9; ++j) acc += hpp[j] * wp[kd * 9 + j];
        }
    }
    out[((size_t)(b0 + b) * 35 + oc) * 99 + od] = fmaxf(acc, 0.f);
}

// h3: [B][35][99] -> h4: [B][35][50], k3 s2 p1, no relu
__global__ __launch_bounds__(BLK) void pool2_k(const float* __restrict__ h3,
                                               const float* __restrict__ w,
                                               const float* __restrict__ bias,
                                               float* __restrict__ out) {
    int idx = blockIdx.x * BLK + threadIdx.x;
    const int total = BB * 35 * 50;
    if (idx >= total) return;
    int od = idx % 50;
    int oc = (idx / 50) % 35;
    int b  = idx / (50 * 35);
    float acc = bias[oc];
#pragma unroll
    for (int kd = 0; kd < 3; ++kd) {
        int id = od * 2 - 1 + kd;
        if (id < 0 || id >= 99) continue;
        for (int ic = 0; ic < 35; ++ic)
            acc += h3[((size_t)b * 35 + ic) * 99 + id] * w[(oc * 35 + ic) * 3 + kd];
    }
    out[idx] = acc;
}

// h4: [B][35][50] -> h5: [B][35][50], k3 s1 p1, relu
__global__ __launch_bounds__(BLK) void conv3_k(const float* __restrict__ h4,
                                               const float* __restrict__ w,
                                               const float* __restrict__ bias,
                                               float* __restrict__ out) {
    int idx = blockIdx.x * BLK + threadIdx.x;
    const int total = BB * 35 * 50;
    if (idx >= total) return;
    int od = idx % 50;
    int oc = (idx / 50) % 35;
    int b  = idx / (50 * 35);
    float acc = bias[oc];
#pragma unroll
    for (int kd = 0; kd < 3; ++kd) {
        int id = od - 1 + kd;
        if (id < 0 || id >= 50) continue;
        for (int ic = 0; ic < 35; ++ic)
            acc += h4[((size_t)b * 35 + ic) * 50 + id] * w[(oc * 35 + ic) * 3 + kd];
    }
    out[idx] = fmaxf(acc, 0.f);
}

// h5: [B][35][50] -> h6: [B][35][26] = [B][910], k2 s2 p1, relu
__global__ __launch_bounds__(BLK) void conv4_k(const float* __restrict__ h5,
                                               const float* __restrict__ w,
                                               const float* __restrict__ bias,
                                               float* __restrict__ out) {
    int idx = blockIdx.x * BLK + threadIdx.x;
    const int total = BB * 35 * 26;
    if (idx >= total) return;
    int od = idx % 26;
    int oc = (idx / 26) % 35;
    int b  = idx / (26 * 35);
    float acc = bias[oc];
#pragma unroll
    for (int kd = 0; kd < 2; ++kd) {
        int id = od * 2 - 1 + kd;
        if (id < 0 || id >= 50) continue;
        for (int ic = 0; ic < 35; ++ic)
            acc += h5[((size_t)b * 35 + ic) * 50 + id] * w[(oc * 35 + ic) * 2 + kd];
    }
    out[idx] = fmaxf(acc, 0.f);
}

// ---------------- generic helpers ----------------

// w: [O][I] -> wT: [I][O]
__global__ __launch_bounds__(BLK) void transpose_k(const float* __restrict__ w,
                                                   float* __restrict__ wT, int O, int I) {
    int idx = blockIdx.x * BLK + threadIdx.x;
    if (idx >= O * I) return;
    int o = idx / I, i = idx % I;
    wT[(size_t)i * O + o] = w[idx];
}

// out[b][o] = bias[o] + sum_i in[b][i]*wT[i][o]
__global__ __launch_bounds__(BLK) void linear_k(const float* __restrict__ in,
                                                const float* __restrict__ wT,
                                                const float* __restrict__ bias,
                                                float* __restrict__ out, int I, int O) {
    int o = blockIdx.x * BLK + threadIdx.x;
    int b = blockIdx.y;
    if (o >= O) return;
    const float* ip = in + (size_t)b * I;
    float acc = bias[o];
    for (int i = 0; i < I; ++i) acc += ip[i] * wT[(size_t)i * O + o];
    out[(size_t)b * O + o] = acc;
}

// one wave per row: nrm[r] = ||in[r,:]||
__global__ __launch_bounds__(BLK) void rownorm_k(const float* __restrict__ in,
                                                 float* __restrict__ nrm, int rows, int cols) {
    int row  = blockIdx.x * (BLK / 64) + ((int)threadIdx.x / 64);
    int lane = threadIdx.x & 63;
    if (row >= rows) return;
    const float* p = in + (size_t)row * cols;
    float s = 0.f;
    for (int c = lane; c < cols; c += 64) { float v = p[c]; s += v * v; }
#pragma unroll
    for (int off = 32; off; off >>= 1) s += __shfl_down(s, off);
    if (lane == 0) nrm[row] = sqrtf(s);
}

// out[r][c] = in[r][c] / max(nrm[r], eps)
__global__ __launch_bounds__(BLK) void normrow_k(const float* __restrict__ in,
                                                 const float* __restrict__ nrm,
                                                 float* __restrict__ out, int rows, int cols) {
    int idx = blockIdx.x * BLK + threadIdx.x;
    if (idx >= rows * cols) return;
    int r = idx / cols;
    out[idx] = in[idx] / fmaxf(nrm[r], 1e-12f);
}

// outT[c][r] = in[r][c] / max(nrm[r], eps)   (rows x cols -> cols x rows)
__global__ __launch_bounds__(BLK) void normT_k(const float* __restrict__ in,
                                               const float* __restrict__ nrm,
                                               float* __restrict__ outT, int rows, int cols) {
    int idx = blockIdx.x * BLK + threadIdx.x;
    if (idx >= rows * cols) return;
    int r = idx / cols, c = idx % cols;
    outT[(size_t)c * rows + r] = in[idx] / fmaxf(nrm[r], 1e-12f);
}

// score[n][k] = sum_c xn[n][c] * mnT[c][k]
__global__ __launch_bounds__(BLK) void score_k(const float* __restrict__ xn,
                                               const float* __restrict__ mnT,
                                               float* __restrict__ score) {
    int k = blockIdx.x * BLK + threadIdx.x;
    int n = blockIdx.y;
    const float* xp = xn + (size_t)n * CD;
    float acc = 0.f;
    for (int c = 0; c < CD; ++c) acc += xp[c] * mnT[(size_t)c * KD + k];
    score[(size_t)n * KD + k] = acc;
}

__global__ __launch_bounds__(BLK) void argmax_k(const float* __restrict__ score,
                                                int* __restrict__ ind) {
    int n = blockIdx.x, tid = threadIdx.x;
    const float* sp = score + (size_t)n * KD;
    float best = -1e30f; int bi = 0;
    for (int k = tid; k < KD; k += BLK) {
        float v = sp[k];
        if (v > best) { best = v; bi = k; }
    }
    __shared__ float sv[BLK];
    __shared__ int   si[BLK];
    sv[tid] = best; si[tid] = bi;
    __syncthreads();
    for (int s = BLK / 2; s; s >>= 1) {
        if (tid < s) {
            if (sv[tid + s] > sv[tid] || (sv[tid + s] == sv[tid] && si[tid + s] < si[tid])) {
                sv[tid] = sv[tid + s]; si[tid] = si[tid + s];
            }
        }
        __syncthreads();
    }
    if (tid == 0) ind[n] = si[0];
}

__global__ __launch_bounds__(BLK) void scatter_k(const float* __restrict__ xx,
                                                 const int* __restrict__ ind,
                                                 float* __restrict__ esum,
                                                 float* __restrict__ counts) {
    int idx = blockIdx.x * BLK + threadIdx.x;
    if (idx >= BB * CD) return;
    int n = idx / CD, c = idx % CD;
    int k = ind[n];
    atomicAdd(&esum[(size_t)k * CD + c], xx[idx]);
    if (c == 0) atomicAdd(&counts[k], 1.0f);
}

// ss[c] = sum_k esum[k][c]/(counts[k]+1e-6)
__global__ __launch_bounds__(BLK) void ss_k(const float* __restrict__ esum,
                                            const float* __restrict__ counts,
                                            float* __restrict__ ss) {
    int c = blockIdx.x * BLK + threadIdx.x;
    if (c >= CD) return;
    float s = 0.f;
    for (int k = 0; k < KD; ++k) s += esum[(size_t)k * CD + c] / (counts[k] + 1e-6f);
    ss[c] = s;
}

__global__ __launch_bounds__(BLK) void mnew_k(const float* __restrict__ m,
                                              const float* __restrict__ esum,
                                              const float* __restrict__ counts,
                                              const float* __restrict__ ss,
                                              float* __restrict__ mnew) {
    int idx = blockIdx.x * BLK + threadIdx.x;
    if (idx >= KD * CD) return;
    int k = idx / CD, c = idx % CD;
    float mean = esum[idx] / (counts[k] + 1e-6f);
    float pd = (mean - ss[c]) * (2.0f / ((float)KD * (float)(KD - 1)));
    mnew[idx] = m[idx] * 0.99f + (mean + pd) * 0.01f;
}

// out1[n][c] = sum_k score[n][k] * mnew[k][c]
__global__ __launch_bounds__(BLK) void av_k(const float* __restrict__ score,
                                            const float* __restrict__ mnew,
                                            float* __restrict__ out1) {
    int c = blockIdx.x * BLK + threadIdx.x;
    int n = blockIdx.y;
    if (c >= CD) return;
    const float* sp = score + (size_t)n * KD;
    float acc = 0.f;
    for (int k = 0; k < KD; ++k) acc += sp[k] * mnew[(size_t)k * CD + c];
    out1[(size_t)n * CD + c] = acc;
}

__global__ __launch_bounds__(BLK) void scale_k(const float* __restrict__ out1,
                                               const float* __restrict__ t1,
                                               const float* __restrict__ t2,
                                               float* __restrict__ memout) {
    int idx = blockIdx.x * BLK + threadIdx.x;
    if (idx >= BB * CD) return;
    int n = idx / CD;
    memout[idx] = out1[idx] * (t1[n] / t2[n]);
}

// logits[b][o] = cls_b[o] + sum_i (fea[b][i]-up[b][i]) * clsT[i][o]
__global__ __launch_bounds__(BLK) void cls_k(const float* __restrict__ fea,
                                             const float* __restrict__ up,
                                             const float* __restrict__ clsT,
                                             const float* __restrict__ clsb,
                                             float* __restrict__ out) {
    int t = blockIdx.x * BLK + threadIdx.x;
    if (t >= BB * 16) return;
    int o = t % 16, b = t / 16;
    const float* fp = fea + (size_t)b * CD;
    const float* up_ = up + (size_t)b * CD;
    float acc = clsb[o];
    for (int i = 0; i < CD; ++i) acc += (fp[i] - up_[i]) * clsT[i * 16 + o];
    out[t] = acc;
}

// ---------------- launch ----------------

static inline int cdiv(int a, int b) { return (a + b - 1) / b; }

extern "C" void kernel_launch(void* const* d_in, const int* in_sizes, int n_in,
                              void* d_out, int out_size, void* d_ws, size_t ws_size,
                              hipStream_t stream) {
    const float* x       = (const float*)d_in[0];
    const float* conv1_w = (const float*)d_in[1];
    const float* conv1_b = (const float*)d_in[2];
    const float* pool1_w = (const float*)d_in[3];
    const float* pool1_b = (const float*)d_in[4];
    const float* conv2_w = (const float*)d_in[5];
    const float* conv2_b = (const float*)d_in[6];
    const float* pool2_w = (const float*)d_in[7];
    const float* pool2_b = (const float*)d_in[8];
    const float* conv3_w = (const float*)d_in[9];
    const float* conv3_b = (const float*)d_in[10];
    const float* conv4_w = (const float*)d_in[11];
    const float* conv4_b = (const float*)d_in[12];
    const float* feat_w  = (const float*)d_in[13];
    const float* feat_b  = (const float*)d_in[14];
    const float* feat1_w = (const float*)d_in[15];
    const float* feat1_b = (const float*)d_in[16];
    const float* mem     = (const float*)d_in[17];
    const float* up_w    = (const float*)d_in[18];
    const float* up_b    = (const float*)d_in[19];
    const float* cls_w   = (const float*)d_in[20];
    const float* cls_b   = (const float*)d_in[21];
    float* outp = (float*)d_out;

    float* ws = (float*)d_ws;
    size_t off = 0;
    auto alloc = [&](size_t n) { float* p = ws + off; off += n; return p; };

    float* h1c   = alloc((size_t)CH * 20 * 198 * 9);
    float* h2c   = alloc((size_t)CH * 20 * 99 * 9);
    float* h3    = alloc((size_t)BB * 35 * 99);
    float* h4    = alloc((size_t)BB * 35 * 50);
    float* h5    = alloc((size_t)BB * 35 * 50);
    float* h6    = alloc((size_t)BB * 910);
    float* featT = alloc((size_t)910 * 400);
    float* f1T   = alloc((size_t)400 * 400);
    float* upT   = alloc((size_t)400 * 400);
    float* clsT  = alloc((size_t)400 * 16);
    float* fea   = alloc((size_t)BB * CD);
    float* xx    = alloc((size_t)BB * CD);
    float* xn    = alloc((size_t)BB * CD);
    float* mnT   = alloc((size_t)CD * KD);
    float* score = alloc((size_t)BB * KD);
    int*   ind   = (int*)alloc(BB);
    float* counts= alloc(KD);
    float* esum  = alloc((size_t)KD * CD);
    float* ssb   = alloc(CD);
    float* mnew  = alloc((size_t)KD * CD);
    float* mn2T  = alloc((size_t)CD * KD);
    float* out1  = alloc((size_t)BB * CD);
    float* t1    = alloc(BB);
    float* t2    = alloc(BB);
    float* memout= alloc((size_t)BB * CD);
    float* upb   = alloc((size_t)BB * CD);
    float* mnrm  = alloc(KD);

    // zero the accumulators (ws is poisoned before every call)
    hipMemsetAsync(counts, 0, KD * sizeof(float), stream);
    hipMemsetAsync(esum, 0, (size_t)KD * CD * sizeof(float), stream);

    // weight transposes
    transpose_k<<<cdiv(400 * 910, BLK), BLK, 0, stream>>>(feat_w, featT, 400, 910);
    transpose_k<<<cdiv(400 * 400, BLK), BLK, 0, stream>>>(feat1_w, f1T, 400, 400);
    transpose_k<<<cdiv(400 * 400, BLK), BLK, 0, stream>>>(up_w, upT, 400, 400);
    transpose_k<<<cdiv(16 * 400, BLK), BLK, 0, stream>>>(cls_w, clsT, 16, 400);

    // normalized codebook (transposed)
    rownorm_k<<<cdiv(KD, 4), BLK, 0, stream>>>(mem, mnrm, KD, CD);
    normT_k<<<cdiv(KD * CD, BLK), BLK, 0, stream>>>(mem, mnrm, mnT, KD, CD);

    // conv stack, chunked over batch
    for (int ch = 0; ch < NCH; ++ch) {
        int b0 = ch * CH;
        conv1_k<<<cdiv(CH * 20 * 198 * 9, BLK), BLK, 0, stream>>>(x, conv1_w, conv1_b, h1c, b0);
        pool1_k<<<cdiv(CH * 20 * 99 * 9, BLK), BLK, 0, stream>>>(h1c, pool1_w, pool1_b, h2c);
        conv2_k<<<cdiv(CH * 35 * 99, BLK), BLK, 0, stream>>>(h2c, conv2_w, conv2_b, h3, b0);
    }
    pool2_k<<<cdiv(BB * 35 * 50, BLK), BLK, 0, stream>>>(h3, pool2_w, pool2_b, h4);
    conv3_k<<<cdiv(BB * 35 * 50, BLK), BLK, 0, stream>>>(h4, conv3_w, conv3_b, h5);
    conv4_k<<<cdiv(BB * 35 * 26, BLK), BLK, 0, stream>>>(h5, conv4_w, conv4_b, h6);

    // linears
    {
        dim3 g(cdiv(400, BLK), BB);
        linear_k<<<g, BLK, 0, stream>>>(h6, featT, feat_b, fea, 910, 400);
        linear_k<<<g, BLK, 0, stream>>>(fea, f1T, feat1_b, xx, 400, 400);
    }

    // memory block
    rownorm_k<<<cdiv(BB, 4), BLK, 0, stream>>>(xx, t1, BB, CD);            // tend_1
    normrow_k<<<cdiv(BB * CD, BLK), BLK, 0, stream>>>(xx, t1, xn, BB, CD); // xn

    {
        dim3 g(KD / BLK, BB);
        score_k<<<g, BLK, 0, stream>>>(xn, mnT, score);
    }
    argmax_k<<<BB, BLK, 0, stream>>>(score, ind);
    scatter_k<<<cdiv(BB * CD, BLK), BLK, 0, stream>>>(xx, ind, esum, counts);
    ss_k<<<cdiv(CD, BLK), BLK, 0, stream>>>(esum, counts, ssb);
    mnew_k<<<cdiv(KD * CD, BLK), BLK, 0, stream>>>(mem, esum, counts, ssb, mnew);

    rownorm_k<<<cdiv(KD, 4), BLK, 0, stream>>>(mnew, mnrm, KD, CD);
    normT_k<<<cdiv(KD * CD, BLK), BLK, 0, stream>>>(mnew, mnrm, mn2T, KD, CD);
    {
        dim3 g(KD / BLK, BB);
        score_k<<<g, BLK, 0, stream>>>(xn, mn2T, score);
    }
    {
        dim3 g(cdiv(CD, BLK), BB);
        av_k<<<g, BLK, 0, stream>>>(score, mnew, out1);
    }
    rownorm_k<<<cdiv(BB, 4), BLK, 0, stream>>>(out1, t2, BB, CD);          // tend
    scale_k<<<cdiv(BB * CD, BLK), BLK, 0, stream>>>(out1, t1, t2, memout);

    {
        dim3 g(cdiv(400, BLK), BB);
        linear_k<<<g, BLK, 0, stream>>>(memout, upT, up_b, upb, 400, 400);
    }
    cls_k<<<cdiv(BB * 16, BLK), BLK, 0, stream>>>(fea, upb, clsT, cls_b, outp);
}

// Round 2
// 4549.749 us; speedup vs baseline: 1.1523x; 1.1523x over previous
//
#include <hip/hip_runtime.h>

#define BLK 256

constexpr int BB   = 2048;  // batch
constexpr int CH   = 256;   // batch chunk for conv1/pool1/conv2
constexpr int NCH  = BB / CH;
constexpr int KD   = 2048;  // codebook size
constexpr int CD   = 400;   // feature dim

// ---------------- conv stack ----------------

// x: [B][200][5][5] (1 in-chan), out chunk: [CH][20][198][3][3], relu
__global__ __launch_bounds__(BLK) void conv1_k(const float* __restrict__ x,
                                               const float* __restrict__ w,
                                               const float* __restrict__ bias,
                                               float* __restrict__ out, int b0) {
    int idx = blockIdx.x * BLK + threadIdx.x;
    const int total = CH * 20 * 198 * 9;
    if (idx >= total) return;
    int ow = idx % 3;
    int oh = (idx / 3) % 3;
    int od = (idx / 9) % 198;
    int oc = (idx / (9 * 198)) % 20;
    int b  = idx / (9 * 198 * 20);
    const float* xin = x + (size_t)(b0 + b) * 5000;
    const float* wp  = w + oc * 27;
    float acc = bias[oc];
#pragma unroll
    for (int kd = 0; kd < 3; ++kd)
#pragma unroll
        for (int kh = 0; kh < 3; ++kh)
#pragma unroll
            for (int kw = 0; kw < 3; ++kw)
                acc += xin[(od + kd) * 25 + (oh + kh) * 5 + (ow + kw)] * wp[kd * 9 + kh * 3 + kw];
    out[idx] = fmaxf(acc, 0.f);
}

// h1: [CH][20][198][9] -> out: [CH][20][99][9], stride2 pad1 in D, no relu
__global__ __launch_bounds__(BLK) void pool1_k(const float* __restrict__ h1,
                                               const float* __restrict__ w,
                                               const float* __restrict__ bias,
                                               float* __restrict__ out) {
    int idx = blockIdx.x * BLK + threadIdx.x;
    const int total = CH * 20 * 99 * 9;
    if (idx >= total) return;
    int hw = idx % 9;
    int od = (idx / 9) % 99;
    int oc = (idx / (9 * 99)) % 20;
    int b  = idx / (9 * 99 * 20);
    float acc = bias[oc];
#pragma unroll
    for (int kd = 0; kd < 3; ++kd) {
        int id = od * 2 - 1 + kd;
        if (id < 0 || id >= 198) continue;
        const float* hp = h1 + ((size_t)b * 20 * 198 + id) * 9 + hw;
        const float* wp = w + oc * 60 + kd;  // w[oc][ic][kd]
        for (int ic = 0; ic < 20; ++ic)
            acc += hp[(size_t)ic * 198 * 9] * wp[ic * 3];
    }
    out[idx] = acc;
}

// h2: [CH][20][99][9] -> h3 global: [B][35][99], pad1 D, relu
__global__ __launch_bounds__(BLK) void conv2_k(const float* __restrict__ h2,
                                               const float* __restrict__ w,
                                               const float* __restrict__ bias,
                                               float* __restrict__ out, int b0) {
    int idx = blockIdx.x * BLK + threadIdx.x;
    const int total = CH * 35 * 99;
    if (idx >= total) return;
    int od = idx % 99;
    int oc = (idx / 99) % 35;
    int b  = idx / (99 * 35);
    float acc = bias[oc];
    for (int ic = 0; ic < 20; ++ic) {
        const float* wp = w + ((size_t)(oc * 20 + ic) * 3) * 9;  // [3][9]
        const float* hp = h2 + ((size_t)(b * 20 + ic) * 99) * 9;
#pragma unroll
        for (int kd = 0; kd < 3; ++kd) {
            int id = od - 1 + kd;
            if (id < 0 || id >= 99) continue;
            const float* hpp = hp + (size_t)id * 9;
#pragma unroll
            for (int j = 0; j < 9; ++j) acc += hpp[j] * wp[kd * 9 + j];
        }
    }
    out[((size_t)(b0 + b) * 35 + oc) * 99 + od] = fmaxf(acc, 0.f);
}

// h3: [B][35][99] -> h4: [B][35][50], k3 s2 p1, no relu
__global__ __launch_bounds__(BLK) void pool2_k(const float* __restrict__ h3,
                                               const float* __restrict__ w,
                                               const float* __restrict__ bias,
                                               float* __restrict__ out) {
    int idx = blockIdx.x * BLK + threadIdx.x;
    const int total = BB * 35 * 50;
    if (idx >= total) return;
    int od = idx % 50;
    int oc = (idx / 50) % 35;
    int b  = idx / (50 * 35);
    float acc = bias[oc];
#pragma unroll
    for (int kd = 0; kd < 3; ++kd) {
        int id = od * 2 - 1 + kd;
        if (id < 0 || id >= 99) continue;
        for (int ic = 0; ic < 35; ++ic)
            acc += h3[((size_t)b * 35 + ic) * 99 + id] * w[(oc * 35 + ic) * 3 + kd];
    }
    out[idx] = acc;
}

// h4: [B][35][50] -> h5: [B][35][50], k3 s1 p1, relu
__global__ __launch_bounds__(BLK) void conv3_k(const float* __restrict__ h4,
                                               const float* __restrict__ w,
                                               const float* __restrict__ bias,
                                               float* __restrict__ out) {
    int idx = blockIdx.x * BLK + threadIdx.x;
    const int total = BB * 35 * 50;
    if (idx >= total) return;
    int od = idx % 50;
    int oc = (idx / 50) % 35;
    int b  = idx / (50 * 35);
    float acc = bias[oc];
#pragma unroll
    for (int kd = 0; kd < 3; ++kd) {
        int id = od - 1 + kd;
        if (id < 0 || id >= 50) continue;
        for (int ic = 0; ic < 35; ++ic)
            acc += h4[((size_t)b * 35 + ic) * 50 + id] * w[(oc * 35 + ic) * 3 + kd];
    }
    out[idx] = fmaxf(acc, 0.f);
}

// h5: [B][35][50] -> h6: [B][35][26] = [B][910], k2 s2 p1, relu
__global__ __launch_bounds__(BLK) void conv4_k(const float* __restrict__ h5,
                                               const float* __restrict__ w,
                                               const float* __restrict__ bias,
                                               float* __restrict__ out) {
    int idx = blockIdx.x * BLK + threadIdx.x;
    const int total = BB * 35 * 26;
    if (idx >= total) return;
    int od = idx % 26;
    int oc = (idx / 26) % 35;
    int b  = idx / (26 * 35);
    float acc = bias[oc];
#pragma unroll
    for (int kd = 0; kd < 2; ++kd) {
        int id = od * 2 - 1 + kd;
        if (id < 0 || id >= 50) continue;
        for (int ic = 0; ic < 35; ++ic)
            acc += h5[((size_t)b * 35 + ic) * 50 + id] * w[(oc * 35 + ic) * 2 + kd];
    }
    out[idx] = fmaxf(acc, 0.f);
}

// ---------------- tiled f32 GEMM ----------------
// C[M][N] = A[M][K] @ B[K][N] (+ bias[N] if non-null)
// BM=BN=64, BK=16, 256 threads, 4x4 per thread.
// GUARD=false requires M%64==0 && N%64==0 && K%16==0.
template <bool GUARD>
__global__ __launch_bounds__(256) void gemm_k(const float* __restrict__ A,
                                              const float* __restrict__ B,
                                              const float* __restrict__ bias,
                                              float* __restrict__ C,
                                              int M, int N, int K) {
    constexpr int BM = 64, BN = 64, BK = 16;
    __shared__ float As[BK][BM + 4];  // +4 pad: 2-way-max conflicts, keeps 16B alignment
    __shared__ float Bs[BK][BN + 4];
    int tid = threadIdx.x;
    int tx = tid % 16, ty = tid / 16;
    int row0 = blockIdx.y * BM;
    int col0 = blockIdx.x * BN;
    float acc[4][4] = {};
    for (int k0 = 0; k0 < K; k0 += BK) {
        {   // A tile 64x16 -> As[k][r]
            int r = tid / 16, kk = tid % 16;
            int gk = k0 + kk;
#pragma unroll
            for (int i = 0; i < 4; ++i) {
                int rr = r + 16 * i;
                int gr = row0 + rr;
                float v = 0.f;
                if (!GUARD || (gr < M && gk < K)) v = A[(size_t)gr * K + gk];
                As[kk][rr] = v;
            }
        }
        {   // B tile 16x64 -> Bs[k][c]
            int kk = tid / 64, c = tid % 64;
            int gc = col0 + c;
#pragma unroll
            for (int i = 0; i < 4; ++i) {
                int kr = kk + 4 * i;
                int gk = k0 + kr;
                float v = 0.f;
                if (!GUARD || (gk < K && gc < N)) v = B[(size_t)gk * N + gc];
                Bs[kr][c] = v;
            }
        }
        __syncthreads();
#pragma unroll
        for (int k = 0; k < BK; ++k) {
            float a[4], b[4];
#pragma unroll
            for (int i = 0; i < 4; ++i) a[i] = As[k][ty * 4 + i];
#pragma unroll
            for (int j = 0; j < 4; ++j) b[j] = Bs[k][tx * 4 + j];
#pragma unroll
            for (int i = 0; i < 4; ++i)
#pragma unroll
                for (int j = 0; j < 4; ++j) acc[i][j] += a[i] * b[j];
        }
        __syncthreads();
    }
#pragma unroll
    for (int i = 0; i < 4; ++i) {
        int gr = row0 + ty * 4 + i;
        if (GUARD && gr >= M) continue;
#pragma unroll
        for (int j = 0; j < 4; ++j) {
            int gc = col0 + tx * 4 + j;
            if (GUARD && gc >= N) continue;
            float v = acc[i][j];
            if (bias) v += bias[gc];
            C[(size_t)gr * N + gc] = v;
        }
    }
}

// ---------------- generic helpers ----------------

// w: [O][I] -> wT: [I][O]
__global__ __launch_bounds__(BLK) void transpose_k(const float* __restrict__ w,
                                                   float* __restrict__ wT, int O, int I) {
    int idx = blockIdx.x * BLK + threadIdx.x;
    if (idx >= O * I) return;
    int o = idx / I, i = idx % I;
    wT[(size_t)i * O + o] = w[idx];
}

// one wave per row: nrm[r] = ||in[r,:]||
__global__ __launch_bounds__(BLK) void rownorm_k(const float* __restrict__ in,
                                                 float* __restrict__ nrm, int rows, int cols) {
    int row  = blockIdx.x * (BLK / 64) + ((int)threadIdx.x / 64);
    int lane = threadIdx.x & 63;
    if (row >= rows) return;
    const float* p = in + (size_t)row * cols;
    float s = 0.f;
    for (int c = lane; c < cols; c += 64) { float v = p[c]; s += v * v; }
#pragma unroll
    for (int off = 32; off; off >>= 1) s += __shfl_down(s, off);
    if (lane == 0) nrm[row] = sqrtf(s);
}

// out[r][c] = in[r][c] / max(nrm[r], eps)
__global__ __launch_bounds__(BLK) void normrow_k(const float* __restrict__ in,
                                                 const float* __restrict__ nrm,
                                                 float* __restrict__ out, int rows, int cols) {
    int idx = blockIdx.x * BLK + threadIdx.x;
    if (idx >= rows * cols) return;
    int r = idx / cols;
    out[idx] = in[idx] / fmaxf(nrm[r], 1e-12f);
}

// outT[c][r] = in[r][c] / max(nrm[r], eps)   (rows x cols -> cols x rows)
__global__ __launch_bounds__(BLK) void normT_k(const float* __restrict__ in,
                                               const float* __restrict__ nrm,
                                               float* __restrict__ outT, int rows, int cols) {
    int idx = blockIdx.x * BLK + threadIdx.x;
    if (idx >= rows * cols) return;
    int r = idx / cols, c = idx % cols;
    outT[(size_t)c * rows + r] = in[idx] / fmaxf(nrm[r], 1e-12f);
}

__global__ __launch_bounds__(BLK) void argmax_k(const float* __restrict__ score,
                                                int* __restrict__ ind) {
    int n = blockIdx.x, tid = threadIdx.x;
    const float* sp = score + (size_t)n * KD;
    float best = -1e30f; int bi = 0;
    for (int k = tid; k < KD; k += BLK) {
        float v = sp[k];
        if (v > best) { best = v; bi = k; }
    }
    __shared__ float sv[BLK];
    __shared__ int   si[BLK];
    sv[tid] = best; si[tid] = bi;
    __syncthreads();
    for (int s = BLK / 2; s; s >>= 1) {
        if (tid < s) {
            if (sv[tid + s] > sv[tid] || (sv[tid + s] == sv[tid] && si[tid + s] < si[tid])) {
                sv[tid] = sv[tid + s]; si[tid] = si[tid + s];
            }
        }
        __syncthreads();
    }
    if (tid == 0) ind[n] = si[0];
}

__global__ __launch_bounds__(BLK) void scatter_k(const float* __restrict__ xx,
                                                 const int* __restrict__ ind,
                                                 float* __restrict__ esum,
                                                 float* __restrict__ counts) {
    int idx = blockIdx.x * BLK + threadIdx.x;
    if (idx >= BB * CD) return;
    int n = idx / CD, c = idx % CD;
    int k = ind[n];
    atomicAdd(&esum[(size_t)k * CD + c], xx[idx]);
    if (c == 0) atomicAdd(&counts[k], 1.0f);
}

// ss[c] = sum_k esum[k][c]/(counts[k]+1e-6)
__global__ __launch_bounds__(BLK) void ss_k(const float* __restrict__ esum,
                                            const float* __restrict__ counts,
                                            float* __restrict__ ss) {
    int c = blockIdx.x * BLK + threadIdx.x;
    if (c >= CD) return;
    float s = 0.f;
    for (int k = 0; k < KD; ++k) s += esum[(size_t)k * CD + c] / (counts[k] + 1e-6f);
    ss[c] = s;
}

__global__ __launch_bounds__(BLK) void mnew_k(const float* __restrict__ m,
                                              const float* __restrict__ esum,
                                              const float* __restrict__ counts,
                                              const float* __restrict__ ss,
                                              float* __restrict__ mnew) {
    int idx = blockIdx.x * BLK + threadIdx.x;
    if (idx >= KD * CD) return;
    int k = idx / CD, c = idx % CD;
    float mean = esum[idx] / (counts[k] + 1e-6f);
    float pd = (mean - ss[c]) * (2.0f / ((float)KD * (float)(KD - 1)));
    mnew[idx] = m[idx] * 0.99f + (mean + pd) * 0.01f;
}

__global__ __launch_bounds__(BLK) void scale_k(const float* __restrict__ out1,
                                               const float* __restrict__ t1,
                                               const float* __restrict__ t2,
                                               float* __restrict__ memout) {
    int idx = blockIdx.x * BLK + threadIdx.x;
    if (idx >= BB * CD) return;
    int n = idx / CD;
    memout[idx] = out1[idx] * (t1[n] / t2[n]);
}

// logits[b][o] = cls_b[o] + sum_i (fea[b][i]-up[b][i]) * clsT[i][o]
__global__ __launch_bounds__(BLK) void cls_k(const float* __restrict__ fea,
                                             const float* __restrict__ up,
                                             const float* __restrict__ clsT,
                                             const float* __restrict__ clsb,
                                             float* __restrict__ out) {
    int t = blockIdx.x * BLK + threadIdx.x;
    if (t >= BB * 16) return;
    int o = t % 16, b = t / 16;
    const float* fp = fea + (size_t)b * CD;
    const float* up_ = up + (size_t)b * CD;
    float acc = clsb[o];
    for (int i = 0; i < CD; ++i) acc += (fp[i] - up_[i]) * clsT[i * 16 + o];
    out[t] = acc;
}

// ---------------- launch ----------------

static inline int cdiv(int a, int b) { return (a + b - 1) / b; }

extern "C" void kernel_launch(void* const* d_in, const int* in_sizes, int n_in,
                              void* d_out, int out_size, void* d_ws, size_t ws_size,
                              hipStream_t stream) {
    const float* x       = (const float*)d_in[0];
    const float* conv1_w = (const float*)d_in[1];
    const float* conv1_b = (const float*)d_in[2];
    const float* pool1_w = (const float*)d_in[3];
    const float* pool1_b = (const float*)d_in[4];
    const float* conv2_w = (const float*)d_in[5];
    const float* conv2_b = (const float*)d_in[6];
    const float* pool2_w = (const float*)d_in[7];
    const float* pool2_b = (const float*)d_in[8];
    const float* conv3_w = (const float*)d_in[9];
    const float* conv3_b = (const float*)d_in[10];
    const float* conv4_w = (const float*)d_in[11];
    const float* conv4_b = (const float*)d_in[12];
    const float* feat_w  = (const float*)d_in[13];
    const float* feat_b  = (const float*)d_in[14];
    const float* feat1_w = (const float*)d_in[15];
    const float* feat1_b = (const float*)d_in[16];
    const float* mem     = (const float*)d_in[17];
    const float* up_w    = (const float*)d_in[18];
    const float* up_b    = (const float*)d_in[19];
    const float* cls_w   = (const float*)d_in[20];
    const float* cls_b   = (const float*)d_in[21];
    float* outp = (float*)d_out;

    float* ws = (float*)d_ws;
    size_t off = 0;
    auto alloc = [&](size_t n) { float* p = ws + off; off += n; return p; };

    float* h1c   = alloc((size_t)CH * 20 * 198 * 9);
    float* h2c   = alloc((size_t)CH * 20 * 99 * 9);
    float* h3    = alloc((size_t)BB * 35 * 99);
    float* h4    = alloc((size_t)BB * 35 * 50);
    float* h5    = alloc((size_t)BB * 35 * 50);
    float* h6    = alloc((size_t)BB * 910);
    float* featT = alloc((size_t)910 * 400);
    float* f1T   = alloc((size_t)400 * 400);
    float* upT   = alloc((size_t)400 * 400);
    float* clsT  = alloc((size_t)400 * 16);
    float* fea   = alloc((size_t)BB * CD);
    float* xx    = alloc((size_t)BB * CD);
    float* xn    = alloc((size_t)BB * CD);
    float* mnT   = alloc((size_t)CD * KD);
    float* score = alloc((size_t)BB * KD);
    int*   ind   = (int*)alloc(BB);
    float* counts= alloc(KD);
    float* esum  = alloc((size_t)KD * CD);
    float* ssb   = alloc(CD);
    float* mnew  = alloc((size_t)KD * CD);
    float* mn2T  = alloc((size_t)CD * KD);
    float* G     = alloc((size_t)CD * CD);
    float* out1  = alloc((size_t)BB * CD);
    float* t1    = alloc(BB);
    float* t2    = alloc(BB);
    float* memout= alloc((size_t)BB * CD);
    float* upb   = alloc((size_t)BB * CD);
    float* mnrm  = alloc(KD);

    // zero the accumulators (ws is poisoned before every call)
    hipMemsetAsync(counts, 0, KD * sizeof(float), stream);
    hipMemsetAsync(esum, 0, (size_t)KD * CD * sizeof(float), stream);

    // weight transposes
    transpose_k<<<cdiv(400 * 910, BLK), BLK, 0, stream>>>(feat_w, featT, 400, 910);
    transpose_k<<<cdiv(400 * 400, BLK), BLK, 0, stream>>>(feat1_w, f1T, 400, 400);
    transpose_k<<<cdiv(400 * 400, BLK), BLK, 0, stream>>>(up_w, upT, 400, 400);
    transpose_k<<<cdiv(16 * 400, BLK), BLK, 0, stream>>>(cls_w, clsT, 16, 400);

    // normalized codebook (transposed): mnT[c][k]
    rownorm_k<<<cdiv(KD, 4), BLK, 0, stream>>>(mem, mnrm, KD, CD);
    normT_k<<<cdiv(KD * CD, BLK), BLK, 0, stream>>>(mem, mnrm, mnT, KD, CD);

    // conv stack, chunked over batch
    for (int ch = 0; ch < NCH; ++ch) {
        int b0 = ch * CH;
        conv1_k<<<cdiv(CH * 20 * 198 * 9, BLK), BLK, 0, stream>>>(x, conv1_w, conv1_b, h1c, b0);
        pool1_k<<<cdiv(CH * 20 * 99 * 9, BLK), BLK, 0, stream>>>(h1c, pool1_w, pool1_b, h2c);
        conv2_k<<<cdiv(CH * 35 * 99, BLK), BLK, 0, stream>>>(h2c, conv2_w, conv2_b, h3, b0);
    }
    pool2_k<<<cdiv(BB * 35 * 50, BLK), BLK, 0, stream>>>(h3, pool2_w, pool2_b, h4);
    conv3_k<<<cdiv(BB * 35 * 50, BLK), BLK, 0, stream>>>(h4, conv3_w, conv3_b, h5);
    conv4_k<<<cdiv(BB * 35 * 26, BLK), BLK, 0, stream>>>(h5, conv4_w, conv4_b, h6);

    // linears: fea = h6 @ featT + feat_b ; xx = fea @ f1T + feat1_b
    {
        dim3 g(cdiv(400, 64), cdiv(BB, 64));
        gemm_k<true><<<g, 256, 0, stream>>>(h6, featT, feat_b, fea, BB, 400, 910);
        gemm_k<true><<<g, 256, 0, stream>>>(fea, f1T, feat1_b, xx, BB, 400, 400);
    }

    // memory block
    rownorm_k<<<cdiv(BB, 4), BLK, 0, stream>>>(xx, t1, BB, CD);            // tend_1
    normrow_k<<<cdiv(BB * CD, BLK), BLK, 0, stream>>>(xx, t1, xn, BB, CD); // xn

    // score1 = xn @ mnT  (2048 x 2048, K=400) — only needed for argmax
    {
        dim3 g(KD / 64, BB / 64);
        gemm_k<false><<<g, 256, 0, stream>>>(xn, mnT, nullptr, score, BB, KD, CD);
    }
    argmax_k<<<BB, BLK, 0, stream>>>(score, ind);
    scatter_k<<<cdiv(BB * CD, BLK), BLK, 0, stream>>>(xx, ind, esum, counts);
    ss_k<<<cdiv(CD, BLK), BLK, 0, stream>>>(esum, counts, ssb);
    mnew_k<<<cdiv(KD * CD, BLK), BLK, 0, stream>>>(mem, esum, counts, ssb, mnew);

    // mn2T[c][k] = l2norm(mnew) transposed
    rownorm_k<<<cdiv(KD, 4), BLK, 0, stream>>>(mnew, mnrm, KD, CD);
    normT_k<<<cdiv(KD * CD, BLK), BLK, 0, stream>>>(mnew, mnrm, mn2T, KD, CD);

    // G[c][d] = sum_k mn2[k][c]*mnew[k][d]  => G = mn2T @ mnew  (400x400, K=2048)
    {
        dim3 g(cdiv(CD, 64), cdiv(CD, 64));
        gemm_k<true><<<g, 256, 0, stream>>>(mn2T, mnew, nullptr, G, CD, CD, KD);
    }
    // out1 = xn @ G   (== (xn @ mn2^T) @ mnew, reassociated)
    {
        dim3 g(cdiv(CD, 64), cdiv(BB, 64));
        gemm_k<true><<<g, 256, 0, stream>>>(xn, G, nullptr, out1, BB, CD, CD);
    }
    rownorm_k<<<cdiv(BB, 4), BLK, 0, stream>>>(out1, t2, BB, CD);          // tend
    scale_k<<<cdiv(BB * CD, BLK), BLK, 0, stream>>>(out1, t1, t2, memout);

    // up = memout @ upT + up_b
    {
        dim3 g(cdiv(400, 64), cdiv(BB, 64));
        gemm_k<true><<<g, 256, 0, stream>>>(memout, upT, up_b, upb, BB, 400, 400);
    }
    cls_k<<<cdiv(BB * 16, BLK), BLK, 0, stream>>>(fea, upb, clsT, cls_b, outp);
}

// Round 3
// 1780.708 us; speedup vs baseline: 2.9442x; 2.5550x over previous
//
#include <hip/hip_runtime.h>

#define BLK 256

constexpr int BB   = 2048;  // batch
constexpr int CH2  = 512;   // batch chunk for conv1/pool1/conv2
constexpr int NCH2 = BB / CH2;
constexpr int KD   = 2048;  // codebook size
constexpr int CD   = 400;   // feature dim

// ---------------- fused conv1 + pool1 ----------------
// Per block: one batch elem, one od2-stripe of 33 (99 = 3 stripes).
// conv1 (k3, relu) computed into LDS, pool1 (k3 s2 p1, no relu) -> h2c global.
// LDS: c1[20][67][9] = 48.2KB + weights ~7KB.
__global__ __launch_bounds__(256) void fused12_k(const float* __restrict__ x,
                                                 const float* __restrict__ c1w,
                                                 const float* __restrict__ c1b,
                                                 const float* __restrict__ p1w,
                                                 const float* __restrict__ p1b,
                                                 float* __restrict__ h2c, int b0) {
    int bi = blockIdx.x;
    int o0 = blockIdx.y * 33;
    __shared__ float c1[20][67][9];
    __shared__ float w1s[540];
    __shared__ float wps[1200];
    __shared__ float b1s[20], bps[20];
    int tid = threadIdx.x;
    for (int i = tid; i < 540; i += 256) w1s[i] = c1w[i];
    for (int i = tid; i < 1200; i += 256) wps[i] = p1w[i];
    if (tid < 20) { b1s[tid] = c1b[tid]; bps[tid] = p1b[tid]; }
    __syncthreads();
    const float* xb = x + (size_t)(b0 + bi) * 5000;
    int r0 = 2 * o0 - 1;
    // phase 1: conv1 rows r0..r0+66 (zero-fill out-of-range rows)
    for (int it = tid; it < 20 * 67; it += 256) {
        int oc = it / 67, ri = it % 67;
        int r = r0 + ri;
        float acc[9];
        if (r >= 0 && r <= 197) {
#pragma unroll
            for (int j = 0; j < 9; ++j) acc[j] = b1s[oc];
            const float* wp1 = &w1s[oc * 27];
#pragma unroll
            for (int kd = 0; kd < 3; ++kd) {
                float xv[25];
                const float* xr = xb + (r + kd) * 25;
#pragma unroll
                for (int m = 0; m < 25; ++m) xv[m] = xr[m];
#pragma unroll
                for (int kh = 0; kh < 3; ++kh)
#pragma unroll
                    for (int kw = 0; kw < 3; ++kw) {
                        float w = wp1[kd * 9 + kh * 3 + kw];
#pragma unroll
                        for (int oh = 0; oh < 3; ++oh)
#pragma unroll
                            for (int ow = 0; ow < 3; ++ow)
                                acc[oh * 3 + ow] += xv[(oh + kh) * 5 + ow + kw] * w;
                    }
            }
#pragma unroll
            for (int j = 0; j < 9; ++j) acc[j] = fmaxf(acc[j], 0.f);
        } else {
#pragma unroll
            for (int j = 0; j < 9; ++j) acc[j] = 0.f;
        }
#pragma unroll
        for (int j = 0; j < 9; ++j) c1[oc][ri][j] = acc[j];
    }
    __syncthreads();
    // phase 2: pool1 for od2 in [o0, o0+32];  ri = 2*oi + kd
    for (int it = tid; it < 20 * 33; it += 256) {
        int oc = it / 33, oi = it % 33;
        float acc[9];
#pragma unroll
        for (int j = 0; j < 9; ++j) acc[j] = bps[oc];
        for (int ic = 0; ic < 20; ++ic) {
#pragma unroll
            for (int kd = 0; kd < 3; ++kd) {
                float w = wps[(oc * 20 + ic) * 3 + kd];
                int ri = 2 * oi + kd;
#pragma unroll
                for (int j = 0; j < 9; ++j) acc[j] += c1[ic][ri][j] * w;
            }
        }
        float* o = h2c + (((size_t)bi * 20 + oc) * 99 + (o0 + oi)) * 9;
#pragma unroll
        for (int j = 0; j < 9; ++j) o[j] = acc[j];
    }
}

// ---------------- conv2 (k3 s1 p1 over D, contracts hw) ----------------
// Block per batch elem; input staged in LDS in 2 ic-halves (10 ic each, od zero-padded);
// 245 threads each own (oc, 15-od run), acc[15] in registers; weights from global
// (near-uniform per wave -> L1 broadcast). relu.
__global__ __launch_bounds__(256) void conv2b_k(const float* __restrict__ h2c,
                                                const float* __restrict__ w,
                                                const float* __restrict__ bias,
                                                float* __restrict__ h3, int b0) {
    int bi = blockIdx.x;
    __shared__ float h2s[10][101][9];  // 36.4KB, od padded +1 both sides
    int tid = threadIdx.x;
    int oc = tid % 35, run = tid / 35;            // 7 runs of 15 od (overlapping, benign)
    int od_start = run * 14;
    if (od_start > 84) od_start = 84;
    bool active = tid < 245;
    float acc[15];
    float bv = active ? bias[oc] : 0.f;
#pragma unroll
    for (int i = 0; i < 15; ++i) acc[i] = bv;
    const float* src = h2c + (size_t)bi * 17820;
    for (int s = 0; s < 2; ++s) {
        // zero pads
        for (int i = tid; i < 10 * 9; i += 256) {
            int ic = i / 9, j = i % 9;
            h2s[ic][0][j] = 0.f; h2s[ic][100][j] = 0.f;
        }
        // load 10*99*9 = 8910 floats
        for (int i = tid; i < 8910; i += 256) {
            int ic = i / 891;
            ((float*)h2s)[i + ic * 18 + 9] = src[s * 8910 + i];
        }
        __syncthreads();
        if (active) {
            const float* wp = w + (size_t)oc * 540 + s * 270;  // w[oc][ic][kd][9]
            for (int ic = 0; ic < 10; ++ic) {
#pragma unroll
                for (int kd = 0; kd < 3; ++kd)
#pragma unroll
                    for (int j = 0; j < 9; ++j) {
                        float wv = wp[(ic * 3 + kd) * 9 + j];
#pragma unroll
                        for (int i = 0; i < 15; ++i)
                            acc[i] += h2s[ic][od_start + i + kd][j] * wv;
                    }
            }
        }
        __syncthreads();
    }
    if (active) {
        float* o = h3 + ((size_t)(b0 + bi) * 35 + oc) * 99 + od_start;
#pragma unroll
        for (int i = 0; i < 15; ++i) o[i] = fmaxf(acc[i], 0.f);
    }
}

// ---------------- fused pool2 + conv3 + conv4 ----------------
// Block per batch elem. h3[b] staged in LDS (padded), h4/h5 live only in LDS,
// weights reloaded per stage into a shared union buffer. Writes h6[b][910].
__global__ __launch_bounds__(256) void fused345_k(const float* __restrict__ h3,
                                                  const float* __restrict__ w2, const float* __restrict__ b2,
                                                  const float* __restrict__ w3, const float* __restrict__ b3,
                                                  const float* __restrict__ w4, const float* __restrict__ b4,
                                                  float* __restrict__ h6) {
    int b = blockIdx.x;
    __shared__ float h3s[35][101];
    __shared__ float h4s[35][52];
    __shared__ float h5s[35][52];
    __shared__ float wbuf[3675];
    __shared__ float bbuf[35];
    int tid = threadIdx.x;
    // load h3 (padded) + pool2 weights
    for (int i = tid; i < 35; i += 256) { h3s[i][0] = 0.f; h3s[i][100] = 0.f; }
    for (int i = tid; i < 35 * 99; i += 256) {
        int ic = i / 99, od = i % 99;
        h3s[ic][1 + od] = h3[((size_t)b * 35 + ic) * 99 + od];
    }
    for (int i = tid; i < 3675; i += 256) wbuf[i] = w2[i];
    if (tid < 35) bbuf[tid] = b2[tid];
    for (int i = tid; i < 35; i += 256) { h4s[i][0] = 0.f; h4s[i][51] = 0.f; }
    __syncthreads();
    // pool2: k3 s2 p1, no relu. id = 2od-1+kd -> padded p = 2od+kd
    for (int it = tid; it < 35 * 50; it += 256) {
        int oc = it / 50, od = it % 50;
        float acc = bbuf[oc];
        for (int ic = 0; ic < 35; ++ic) {
#pragma unroll
            for (int kd = 0; kd < 3; ++kd)
                acc += h3s[ic][2 * od + kd] * wbuf[(oc * 35 + ic) * 3 + kd];
        }
        h4s[oc][1 + od] = acc;
    }
    __syncthreads();
    for (int i = tid; i < 3675; i += 256) wbuf[i] = w3[i];
    if (tid < 35) bbuf[tid] = b3[tid];
    for (int i = tid; i < 35; i += 256) { h5s[i][0] = 0.f; h5s[i][51] = 0.f; }
    __syncthreads();
    // conv3: k3 s1 p1, relu. p = od+kd
    for (int it = tid; it < 35 * 50; it += 256) {
        int oc = it / 50, od = it % 50;
        float acc = bbuf[oc];
        for (int ic = 0; ic < 35; ++ic) {
#pragma unroll
            for (int kd = 0; kd < 3; ++kd)
                acc += h4s[ic][od + kd] * wbuf[(oc * 35 + ic) * 3 + kd];
        }
        h5s[oc][1 + od] = fmaxf(acc, 0.f);
    }
    __syncthreads();
    for (int i = tid; i < 2450; i += 256) wbuf[i] = w4[i];
    if (tid < 35) bbuf[tid] = b4[tid];
    __syncthreads();
    // conv4: k2 s2 p1, relu. id = 2od-1+kd -> p = 2od+kd, out D=26
    for (int it = tid; it < 35 * 26; it += 256) {
        int oc = it / 26, od = it % 26;
        float acc = bbuf[oc];
        for (int ic = 0; ic < 35; ++ic) {
#pragma unroll
            for (int kd = 0; kd < 2; ++kd)
                acc += h5s[ic][2 * od + kd] * wbuf[(oc * 35 + ic) * 2 + kd];
        }
        h6[(size_t)b * 910 + oc * 26 + od] = fmaxf(acc, 0.f);
    }
}

// ---------------- tiled f32 GEMM (optionally fused row-argmax) ----------------
// C[M][N] = A[M][K] @ B[K][N] (+ bias). BM=BN=64, BK=16, 256 thr, 4x4/thread.
// ARGMAX: skip C store; per-row packed-key atomicMax into keymax (init 0).
template <bool GUARD, bool ARGMAX>
__global__ __launch_bounds__(256) void gemm_k(const float* __restrict__ A,
                                              const float* __restrict__ B,
                                              const float* __restrict__ bias,
                                              float* __restrict__ C,
                                              unsigned long long* __restrict__ keymax,
                                              int M, int N, int K) {
    constexpr int BM = 64, BN = 64, BK = 16;
    __shared__ float As[BK][BM + 4];
    __shared__ float Bs[BK][BN + 4];
    int tid = threadIdx.x;
    int tx = tid % 16, ty = tid / 16;
    int row0 = blockIdx.y * BM;
    int col0 = blockIdx.x * BN;
    float acc[4][4] = {};
    for (int k0 = 0; k0 < K; k0 += BK) {
        {
            int r = tid / 16, kk = tid % 16;
            int gk = k0 + kk;
#pragma unroll
            for (int i = 0; i < 4; ++i) {
                int rr = r + 16 * i;
                int gr = row0 + rr;
                float v = 0.f;
                if (!GUARD || (gr < M && gk < K)) v = A[(size_t)gr * K + gk];
                As[kk][rr] = v;
            }
        }
        {
            int kk = tid / 64, c = tid % 64;
            int gc = col0 + c;
#pragma unroll
            for (int i = 0; i < 4; ++i) {
                int kr = kk + 4 * i;
                int gk = k0 + kr;
                float v = 0.f;
                if (!GUARD || (gk < K && gc < N)) v = B[(size_t)gk * N + gc];
                Bs[kr][c] = v;
            }
        }
        __syncthreads();
#pragma unroll
        for (int k = 0; k < BK; ++k) {
            float a[4], b[4];
#pragma unroll
            for (int i = 0; i < 4; ++i) a[i] = As[k][ty * 4 + i];
#pragma unroll
            for (int j = 0; j < 4; ++j) b[j] = Bs[k][tx * 4 + j];
#pragma unroll
            for (int i = 0; i < 4; ++i)
#pragma unroll
                for (int j = 0; j < 4; ++j) acc[i][j] += a[i] * b[j];
        }
        __syncthreads();
    }
    if constexpr (ARGMAX) {
        __shared__ unsigned long long red[64][16];
#pragma unroll
        for (int i = 0; i < 4; ++i) {
            unsigned long long best = 0;
#pragma unroll
            for (int j = 0; j < 4; ++j) {
                int gc = col0 + tx * 4 + j;
                unsigned u = __float_as_uint(acc[i][j]);
                unsigned ukey = (u & 0x80000000u) ? ~u : (u | 0x80000000u);
                unsigned long long key =
                    ((unsigned long long)ukey << 32) | (unsigned)(KD - 1 - gc);
                if (key > best) best = key;
            }
            red[ty * 4 + i][tx] = best;
        }
        __syncthreads();
        if (tid < 64) {
            unsigned long long best = 0;
#pragma unroll
            for (int q = 0; q < 16; ++q) {
                unsigned long long v = red[tid][q];
                if (v > best) best = v;
            }
            atomicMax(&keymax[row0 + tid], best);
        }
    } else {
#pragma unroll
        for (int i = 0; i < 4; ++i) {
            int gr = row0 + ty * 4 + i;
            if (GUARD && gr >= M) continue;
#pragma unroll
            for (int j = 0; j < 4; ++j) {
                int gc = col0 + tx * 4 + j;
                if (GUARD && gc >= N) continue;
                float v = acc[i][j];
                if (bias) v += bias[gc];
                C[(size_t)gr * N + gc] = v;
            }
        }
    }
}

// ---------------- generic helpers ----------------

__global__ __launch_bounds__(BLK) void transpose_k(const float* __restrict__ w,
                                                   float* __restrict__ wT, int O, int I) {
    int idx = blockIdx.x * BLK + threadIdx.x;
    if (idx >= O * I) return;
    int o = idx / I, i = idx % I;
    wT[(size_t)i * O + o] = w[idx];
}

__global__ __launch_bounds__(BLK) void rownorm_k(const float* __restrict__ in,
                                                 float* __restrict__ nrm, int rows, int cols) {
    int row  = blockIdx.x * (BLK / 64) + ((int)threadIdx.x / 64);
    int lane = threadIdx.x & 63;
    if (row >= rows) return;
    const float* p = in + (size_t)row * cols;
    float s = 0.f;
    for (int c = lane; c < cols; c += 64) { float v = p[c]; s += v * v; }
#pragma unroll
    for (int off = 32; off; off >>= 1) s += __shfl_down(s, off);
    if (lane == 0) nrm[row] = sqrtf(s);
}

__global__ __launch_bounds__(BLK) void normrow_k(const float* __restrict__ in,
                                                 const float* __restrict__ nrm,
                                                 float* __restrict__ out, int rows, int cols) {
    int idx = blockIdx.x * BLK + threadIdx.x;
    if (idx >= rows * cols) return;
    int r = idx / cols;
    out[idx] = in[idx] / fmaxf(nrm[r], 1e-12f);
}

__global__ __launch_bounds__(BLK) void normT_k(const float* __restrict__ in,
                                               const float* __restrict__ nrm,
                                               float* __restrict__ outT, int rows, int cols) {
    int idx = blockIdx.x * BLK + threadIdx.x;
    if (idx >= rows * cols) return;
    int r = idx / cols, c = idx % cols;
    outT[(size_t)c * rows + r] = in[idx] / fmaxf(nrm[r], 1e-12f);
}

__global__ __launch_bounds__(BLK) void ind_k(const unsigned long long* __restrict__ kb,
                                             int* __restrict__ ind) {
    int n = blockIdx.x * BLK + threadIdx.x;
    if (n < BB) ind[n] = (KD - 1) - (int)(unsigned)(kb[n] & 0xffffffffull);
}

__global__ __launch_bounds__(BLK) void scatter_k(const float* __restrict__ xx,
                                                 const int* __restrict__ ind,
                                                 float* __restrict__ esum,
                                                 float* __restrict__ counts) {
    int idx = blockIdx.x * BLK + threadIdx.x;
    if (idx >= BB * CD) return;
    int n = idx / CD, c = idx % CD;
    int k = ind[n];
    atomicAdd(&esum[(size_t)k * CD + c], xx[idx]);
    if (c == 0) atomicAdd(&counts[k], 1.0f);
}

// ss[c] += sum over 8 k-rows of esum[k][c]/(counts[k]+1e-6); ss pre-zeroed
__global__ __launch_bounds__(BLK) void ss2_k(const float* __restrict__ esum,
                                             const float* __restrict__ counts,
                                             float* __restrict__ ss) {
    int k0 = blockIdx.x * 8;
    int tid = threadIdx.x;
    float a0 = 0.f, a1 = 0.f;
    for (int r = 0; r < 8; ++r) {
        int k = k0 + r;
        float rc = 1.0f / (counts[k] + 1e-6f);
        a0 += esum[(size_t)k * CD + tid] * rc;
        if (tid < CD - BLK) a1 += esum[(size_t)k * CD + BLK + tid] * rc;
    }
    atomicAdd(&ss[tid], a0);
    if (tid < CD - BLK) atomicAdd(&ss[BLK + tid], a1);
}

__global__ __launch_bounds__(BLK) void mnew_k(const float* __restrict__ m,
                                              const float* __restrict__ esum,
                                              const float* __restrict__ counts,
                                              const float* __restrict__ ss,
                                              float* __restrict__ mnew) {
    int idx = blockIdx.x * BLK + threadIdx.x;
    if (idx >= KD * CD) return;
    int k = idx / CD, c = idx % CD;
    float mean = esum[idx] / (counts[k] + 1e-6f);
    float pd = (mean - ss[c]) * (2.0f / ((float)KD * (float)(KD - 1)));
    mnew[idx] = m[idx] * 0.99f + (mean + pd) * 0.01f;
}

__global__ __launch_bounds__(BLK) void scale_k(const float* __restrict__ out1,
                                               const float* __restrict__ t1,
                                               const float* __restrict__ t2,
                                               float* __restrict__ memout) {
    int idx = blockIdx.x * BLK + threadIdx.x;
    if (idx >= BB * CD) return;
    int n = idx / CD;
    memout[idx] = out1[idx] * (t1[n] / t2[n]);
}

__global__ __launch_bounds__(BLK) void cls_k(const float* __restrict__ fea,
                                             const float* __restrict__ up,
                                             const float* __restrict__ clsT,
                                             const float* __restrict__ clsb,
                                             float* __restrict__ out) {
    int t = blockIdx.x * BLK + threadIdx.x;
    if (t >= BB * 16) return;
    int o = t % 16, b = t / 16;
    const float* fp = fea + (size_t)b * CD;
    const float* up_ = up + (size_t)b * CD;
    float acc = clsb[o];
    for (int i = 0; i < CD; ++i) acc += (fp[i] - up_[i]) * clsT[i * 16 + o];
    out[t] = acc;
}

// ---------------- launch ----------------

static inline int cdiv(int a, int b) { return (a + b - 1) / b; }

extern "C" void kernel_launch(void* const* d_in, const int* in_sizes, int n_in,
                              void* d_out, int out_size, void* d_ws, size_t ws_size,
                              hipStream_t stream) {
    const float* x       = (const float*)d_in[0];
    const float* conv1_w = (const float*)d_in[1];
    const float* conv1_b = (const float*)d_in[2];
    const float* pool1_w = (const float*)d_in[3];
    const float* pool1_b = (const float*)d_in[4];
    const float* conv2_w = (const float*)d_in[5];
    const float* conv2_b = (const float*)d_in[6];
    const float* pool2_w = (const float*)d_in[7];
    const float* pool2_b = (const float*)d_in[8];
    const float* conv3_w = (const float*)d_in[9];
    const float* conv3_b = (const float*)d_in[10];
    const float* conv4_w = (const float*)d_in[11];
    const float* conv4_b = (const float*)d_in[12];
    const float* feat_w  = (const float*)d_in[13];
    const float* feat_b  = (const float*)d_in[14];
    const float* feat1_w = (const float*)d_in[15];
    const float* feat1_b = (const float*)d_in[16];
    const float* mem     = (const float*)d_in[17];
    const float* up_w    = (const float*)d_in[18];
    const float* up_b    = (const float*)d_in[19];
    const float* cls_w   = (const float*)d_in[20];
    const float* cls_b   = (const float*)d_in[21];
    float* outp = (float*)d_out;

    float* ws = (float*)d_ws;
    size_t off = 0;
    auto alloc = [&](size_t n) { float* p = ws + off; off += n; return p; };

    unsigned long long* keybuf = (unsigned long long*)alloc(2 * BB);  // 8B aligned (off=0)
    float* h2c   = alloc((size_t)CH2 * 17820);
    float* h3    = alloc((size_t)BB * 35 * 99);
    float* h6    = alloc((size_t)BB * 910);
    float* featT = alloc((size_t)910 * 400);
    float* f1T   = alloc((size_t)400 * 400);
    float* upT   = alloc((size_t)400 * 400);
    float* clsT  = alloc((size_t)400 * 16);
    float* fea   = alloc((size_t)BB * CD);
    float* xx    = alloc((size_t)BB * CD);
    float* xn    = alloc((size_t)BB * CD);
    float* mnT   = alloc((size_t)CD * KD);
    int*   ind   = (int*)alloc(BB);
    float* counts= alloc(KD);
    float* esum  = alloc((size_t)KD * CD);
    float* ssb   = alloc(CD);
    float* mnew  = alloc((size_t)KD * CD);
    float* mn2T  = alloc((size_t)CD * KD);
    float* G     = alloc((size_t)CD * CD);
    float* out1  = alloc((size_t)BB * CD);
    float* t1    = alloc(BB);
    float* t2    = alloc(BB);
    float* memout= alloc((size_t)BB * CD);
    float* upb   = alloc((size_t)BB * CD);
    float* mnrm  = alloc(KD);

    hipMemsetAsync(counts, 0, KD * sizeof(float), stream);
    hipMemsetAsync(esum, 0, (size_t)KD * CD * sizeof(float), stream);
    hipMemsetAsync(ssb, 0, CD * sizeof(float), stream);
    hipMemsetAsync(keybuf, 0, BB * sizeof(unsigned long long), stream);

    transpose_k<<<cdiv(400 * 910, BLK), BLK, 0, stream>>>(feat_w, featT, 400, 910);
    transpose_k<<<cdiv(400 * 400, BLK), BLK, 0, stream>>>(feat1_w, f1T, 400, 400);
    transpose_k<<<cdiv(400 * 400, BLK), BLK, 0, stream>>>(up_w, upT, 400, 400);
    transpose_k<<<cdiv(16 * 400, BLK), BLK, 0, stream>>>(cls_w, clsT, 16, 400);

    rownorm_k<<<cdiv(KD, 4), BLK, 0, stream>>>(mem, mnrm, KD, CD);
    normT_k<<<cdiv(KD * CD, BLK), BLK, 0, stream>>>(mem, mnrm, mnT, KD, CD);

    // conv stack
    for (int ch = 0; ch < NCH2; ++ch) {
        int b0 = ch * CH2;
        dim3 g12(CH2, 3);
        fused12_k<<<g12, 256, 0, stream>>>(x, conv1_w, conv1_b, pool1_w, pool1_b, h2c, b0);
        conv2b_k<<<CH2, 256, 0, stream>>>(h2c, conv2_w, conv2_b, h3, b0);
    }
    fused345_k<<<BB, 256, 0, stream>>>(h3, pool2_w, pool2_b, conv3_w, conv3_b,
                                       conv4_w, conv4_b, h6);

    // linears
    {
        dim3 g(cdiv(400, 64), cdiv(BB, 64));
        gemm_k<true, false><<<g, 256, 0, stream>>>(h6, featT, feat_b, fea, nullptr, BB, 400, 910);
        gemm_k<true, false><<<g, 256, 0, stream>>>(fea, f1T, feat1_b, xx, nullptr, BB, 400, 400);
    }

    // memory block
    rownorm_k<<<cdiv(BB, 4), BLK, 0, stream>>>(xx, t1, BB, CD);
    normrow_k<<<cdiv(BB * CD, BLK), BLK, 0, stream>>>(xx, t1, xn, BB, CD);

    // fused score1 + row-argmax (score matrix never materialized)
    {
        dim3 g(KD / 64, BB / 64);
        gemm_k<false, true><<<g, 256, 0, stream>>>(xn, mnT, nullptr, nullptr, keybuf, BB, KD, CD);
    }
    ind_k<<<cdiv(BB, BLK), BLK, 0, stream>>>(keybuf, ind);
    scatter_k<<<cdiv(BB * CD, BLK), BLK, 0, stream>>>(xx, ind, esum, counts);
    ss2_k<<<KD / 8, BLK, 0, stream>>>(esum, counts, ssb);
    mnew_k<<<cdiv(KD * CD, BLK), BLK, 0, stream>>>(mem, esum, counts, ssb, mnew);

    rownorm_k<<<cdiv(KD, 4), BLK, 0, stream>>>(mnew, mnrm, KD, CD);
    normT_k<<<cdiv(KD * CD, BLK), BLK, 0, stream>>>(mnew, mnrm, mn2T, KD, CD);

    // G = mn2T @ mnew (400x400, K=2048); out1 = xn @ G
    {
        dim3 g(cdiv(CD, 64), cdiv(CD, 64));
        gemm_k<true, false><<<g, 256, 0, stream>>>(mn2T, mnew, nullptr, G, nullptr, CD, CD, KD);
    }
    {
        dim3 g(cdiv(CD, 64), cdiv(BB, 64));
        gemm_k<true, false><<<g, 256, 0, stream>>>(xn, G, nullptr, out1, nullptr, BB, CD, CD);
    }
    rownorm_k<<<cdiv(BB, 4), BLK, 0, stream>>>(out1, t2, BB, CD);
    scale_k<<<cdiv(BB * CD, BLK), BLK, 0, stream>>>(out1, t1, t2, memout);

    {
        dim3 g(cdiv(400, 64), cdiv(BB, 64));
        gemm_k<true, false><<<g, 256, 0, stream>>>(memout, upT, up_b, upb, nullptr, BB, 400, 400);
    }
    cls_k<<<cdiv(BB * 16, BLK), BLK, 0, stream>>>(fea, upb, clsT, cls_b, outp);
}

// Round 4
// 1777.714 us; speedup vs baseline: 2.9492x; 1.0017x over previous
//
#include <hip/hip_runtime.h>

#define BLK 256

constexpr int BB   = 2048;  // batch
constexpr int CH2  = 512;   // batch chunk for conv1/pool1/conv2
constexpr int NCH2 = BB / CH2;
constexpr int KD   = 2048;  // codebook size
constexpr int CD   = 400;   // feature dim

// ---------------- fused conv1 + pool1 ----------------
// Per block: one batch elem, one od2-stripe of 33 (99 = 3 stripes).
// x rows staged in LDS (coalesced) -> conv1 (k3, relu) into LDS -> pool1 -> h2c.
// LDS: xs 6.9KB + c1[20][67][9] 48.2KB + weights ~7KB = ~62.3KB.
__global__ __launch_bounds__(256) void fused12_k(const float* __restrict__ x,
                                                 const float* __restrict__ c1w,
                                                 const float* __restrict__ c1b,
                                                 const float* __restrict__ p1w,
                                                 const float* __restrict__ p1b,
                                                 float* __restrict__ h2c, int b0) {
    int bi = blockIdx.x;
    int o0 = blockIdx.y * 33;
    __shared__ float xs[69 * 25];
    __shared__ float c1[20][67][9];
    __shared__ float w1s[540];
    __shared__ float wps[1200];
    __shared__ float b1s[20], bps[20];
    int tid = threadIdx.x;
    for (int i = tid; i < 540; i += 256) w1s[i] = c1w[i];
    for (int i = tid; i < 1200; i += 256) wps[i] = p1w[i];
    if (tid < 20) { b1s[tid] = c1b[tid]; bps[tid] = p1b[tid]; }
    const float* xb = x + (size_t)(b0 + bi) * 5000;
    int r0 = 2 * o0 - 1;
    // phase 0: stage x rows r0..r0+68 (zero-fill OOB)
    for (int i = tid; i < 69 * 25; i += 256) {
        int r = r0 + i / 25;
        xs[i] = (r >= 0 && r < 200) ? xb[r * 25 + (i % 25)] : 0.f;
    }
    __syncthreads();
    // phase 1: conv1 rows r0..r0+66 (zero-fill out-of-range rows)
    for (int it = tid; it < 20 * 67; it += 256) {
        int oc = it / 67, ri = it % 67;
        int r = r0 + ri;
        float acc[9];
        if (r >= 0 && r <= 197) {
#pragma unroll
            for (int j = 0; j < 9; ++j) acc[j] = b1s[oc];
            const float* wp1 = &w1s[oc * 27];
#pragma unroll
            for (int kd = 0; kd < 3; ++kd) {
                float xv[25];
                const float* xr = &xs[(ri + kd) * 25];
#pragma unroll
                for (int m = 0; m < 25; ++m) xv[m] = xr[m];
#pragma unroll
                for (int kh = 0; kh < 3; ++kh)
#pragma unroll
                    for (int kw = 0; kw < 3; ++kw) {
                        float w = wp1[kd * 9 + kh * 3 + kw];
#pragma unroll
                        for (int oh = 0; oh < 3; ++oh)
#pragma unroll
                            for (int ow = 0; ow < 3; ++ow)
                                acc[oh * 3 + ow] += xv[(oh + kh) * 5 + ow + kw] * w;
                    }
            }
#pragma unroll
            for (int j = 0; j < 9; ++j) acc[j] = fmaxf(acc[j], 0.f);
        } else {
#pragma unroll
            for (int j = 0; j < 9; ++j) acc[j] = 0.f;
        }
#pragma unroll
        for (int j = 0; j < 9; ++j) c1[oc][ri][j] = acc[j];
    }
    __syncthreads();
    // phase 2: pool1 for od2 in [o0, o0+32];  ri = 2*oi + kd
    for (int it = tid; it < 20 * 33; it += 256) {
        int oc = it / 33, oi = it % 33;
        float acc[9];
#pragma unroll
        for (int j = 0; j < 9; ++j) acc[j] = bps[oc];
        for (int ic = 0; ic < 20; ++ic) {
#pragma unroll
            for (int kd = 0; kd < 3; ++kd) {
                float w = wps[(oc * 20 + ic) * 3 + kd];
                int ri = 2 * oi + kd;
#pragma unroll
                for (int j = 0; j < 9; ++j) acc[j] += c1[ic][ri][j] * w;
            }
        }
        float* o = h2c + (((size_t)bi * 20 + oc) * 99 + (o0 + oi)) * 9;
#pragma unroll
        for (int j = 0; j < 9; ++j) o[j] = acc[j];
    }
}

// ---------------- conv2 (k3 s1 p1 over D, contracts hw) ----------------
// Block per batch elem; input staged in LDS in 2 ic-halves; weights for the
// current half staged in LDS (ws[35][271], odd pad -> conflict-free).
// 245 threads each own (oc, 15-od run); sliding window win[17] per (ic,j)
// feeds all 3 kd taps. relu.
__global__ __launch_bounds__(256) void conv2b_k(const float* __restrict__ h2c,
                                                const float* __restrict__ w,
                                                const float* __restrict__ bias,
                                                float* __restrict__ h3, int b0) {
    int bi = blockIdx.x;
    __shared__ float h2s[10][101][9];   // 36.4KB, od padded +1 both sides
    __shared__ float ws[35 * 271];      // 37.9KB, current ic-half of weights
    int tid = threadIdx.x;
    int oc = tid % 35, run = tid / 35;  // 7 runs of 15 od (1-col overlap, benign)
    int od_start = run * 14;
    if (od_start > 84) od_start = 84;
    bool active = tid < 245;
    float acc[15];
    float bv = active ? bias[oc] : 0.f;
#pragma unroll
    for (int i = 0; i < 15; ++i) acc[i] = bv;
    const float* src = h2c + (size_t)bi * 17820;
    for (int s = 0; s < 2; ++s) {
        // zero pads
        for (int i = tid; i < 10 * 9; i += 256) {
            int ic = i / 9, j = i % 9;
            h2s[ic][0][j] = 0.f; h2s[ic][100][j] = 0.f;
        }
        // load 10*99*9 = 8910 floats (coalesced)
        for (int i = tid; i < 8910; i += 256) {
            int ic = i / 891;
            ((float*)h2s)[i + ic * 18 + 9] = src[s * 8910 + i];
        }
        // load weight half: w[oc][540], this half = 270 floats per oc
        for (int i = tid; i < 35 * 270; i += 256) {
            int o = i / 270, t = i % 270;
            ws[o * 271 + t] = w[(size_t)o * 540 + s * 270 + t];
        }
        __syncthreads();
        if (active) {
            const float* wp = &ws[oc * 271];  // [(ic*3+kd)*9 + j]
            for (int ic = 0; ic < 10; ++ic) {
#pragma unroll
                for (int j = 0; j < 9; ++j) {
                    float win[17];
#pragma unroll
                    for (int t = 0; t < 17; ++t) win[t] = h2s[ic][od_start + t][j];
#pragma unroll
                    for (int kd = 0; kd < 3; ++kd) {
                        float wv = wp[(ic * 3 + kd) * 9 + j];
#pragma unroll
                        for (int i = 0; i < 15; ++i) acc[i] += win[i + kd] * wv;
                    }
                }
            }
        }
        __syncthreads();
    }
    if (active) {
        float* o = h3 + ((size_t)(b0 + bi) * 35 + oc) * 99 + od_start;
#pragma unroll
        for (int i = 0; i < 15; ++i) o[i] = fmaxf(acc[i], 0.f);
    }
}

// ---------------- fused pool2 + conv3 + conv4 ----------------
__global__ __launch_bounds__(256) void fused345_k(const float* __restrict__ h3,
                                                  const float* __restrict__ w2, const float* __restrict__ b2,
                                                  const float* __restrict__ w3, const float* __restrict__ b3,
                                                  const float* __restrict__ w4, const float* __restrict__ b4,
                                                  float* __restrict__ h6) {
    int b = blockIdx.x;
    __shared__ float h3s[35][101];
    __shared__ float h4s[35][52];
    __shared__ float h5s[35][52];
    __shared__ float wbuf[3675];
    __shared__ float bbuf[35];
    int tid = threadIdx.x;
    for (int i = tid; i < 35; i += 256) { h3s[i][0] = 0.f; h3s[i][100] = 0.f; }
    for (int i = tid; i < 35 * 99; i += 256) {
        int ic = i / 99, od = i % 99;
        h3s[ic][1 + od] = h3[((size_t)b * 35 + ic) * 99 + od];
    }
    for (int i = tid; i < 3675; i += 256) wbuf[i] = w2[i];
    if (tid < 35) bbuf[tid] = b2[tid];
    for (int i = tid; i < 35; i += 256) { h4s[i][0] = 0.f; h4s[i][51] = 0.f; }
    __syncthreads();
    for (int it = tid; it < 35 * 50; it += 256) {
        int oc = it / 50, od = it % 50;
        float acc = bbuf[oc];
        for (int ic = 0; ic < 35; ++ic) {
#pragma unroll
            for (int kd = 0; kd < 3; ++kd)
                acc += h3s[ic][2 * od + kd] * wbuf[(oc * 35 + ic) * 3 + kd];
        }
        h4s[oc][1 + od] = acc;
    }
    __syncthreads();
    for (int i = tid; i < 3675; i += 256) wbuf[i] = w3[i];
    if (tid < 35) bbuf[tid] = b3[tid];
    for (int i = tid; i < 35; i += 256) { h5s[i][0] = 0.f; h5s[i][51] = 0.f; }
    __syncthreads();
    for (int it = tid; it < 35 * 50; it += 256) {
        int oc = it / 50, od = it % 50;
        float acc = bbuf[oc];
        for (int ic = 0; ic < 35; ++ic) {
#pragma unroll
            for (int kd = 0; kd < 3; ++kd)
                acc += h4s[ic][od + kd] * wbuf[(oc * 35 + ic) * 3 + kd];
        }
        h5s[oc][1 + od] = fmaxf(acc, 0.f);
    }
    __syncthreads();
    for (int i = tid; i < 2450; i += 256) wbuf[i] = w4[i];
    if (tid < 35) bbuf[tid] = b4[tid];
    __syncthreads();
    for (int it = tid; it < 35 * 26; it += 256) {
        int oc = it / 26, od = it % 26;
        float acc = bbuf[oc];
        for (int ic = 0; ic < 35; ++ic) {
#pragma unroll
            for (int kd = 0; kd < 2; ++kd)
                acc += h5s[ic][2 * od + kd] * wbuf[(oc * 35 + ic) * 2 + kd];
        }
        h6[(size_t)b * 910 + oc * 26 + od] = fmaxf(acc, 0.f);
    }
}

// ---------------- tiled f32 GEMM (optionally fused row-argmax) ----------------
template <bool GUARD, bool ARGMAX>
__global__ __launch_bounds__(256) void gemm_k(const float* __restrict__ A,
                                              const float* __restrict__ B,
                                              const float* __restrict__ bias,
                                              float* __restrict__ C,
                                              unsigned long long* __restrict__ keymax,
                                              int M, int N, int K) {
    constexpr int BM = 64, BN = 64, BK = 16;
    __shared__ float As[BK][BM + 4];
    __shared__ float Bs[BK][BN + 4];
    int tid = threadIdx.x;
    int tx = tid % 16, ty = tid / 16;
    int row0 = blockIdx.y * BM;
    int col0 = blockIdx.x * BN;
    float acc[4][4] = {};
    for (int k0 = 0; k0 < K; k0 += BK) {
        {
            int r = tid / 16, kk = tid % 16;
            int gk = k0 + kk;
#pragma unroll
            for (int i = 0; i < 4; ++i) {
                int rr = r + 16 * i;
                int gr = row0 + rr;
                float v = 0.f;
                if (!GUARD || (gr < M && gk < K)) v = A[(size_t)gr * K + gk];
                As[kk][rr] = v;
            }
        }
        {
            int kk = tid / 64, c = tid % 64;
            int gc = col0 + c;
#pragma unroll
            for (int i = 0; i < 4; ++i) {
                int kr = kk + 4 * i;
                int gk = k0 + kr;
                float v = 0.f;
                if (!GUARD || (gk < K && gc < N)) v = B[(size_t)gk * N + gc];
                Bs[kr][c] = v;
            }
        }
        __syncthreads();
#pragma unroll
        for (int k = 0; k < BK; ++k) {
            float a[4], b[4];
#pragma unroll
            for (int i = 0; i < 4; ++i) a[i] = As[k][ty * 4 + i];
#pragma unroll
            for (int j = 0; j < 4; ++j) b[j] = Bs[k][tx * 4 + j];
#pragma unroll
            for (int i = 0; i < 4; ++i)
#pragma unroll
                for (int j = 0; j < 4; ++j) acc[i][j] += a[i] * b[j];
        }
        __syncthreads();
    }
    if constexpr (ARGMAX) {
        __shared__ unsigned long long red[64][16];
#pragma unroll
        for (int i = 0; i < 4; ++i) {
            unsigned long long best = 0;
#pragma unroll
            for (int j = 0; j < 4; ++j) {
                int gc = col0 + tx * 4 + j;
                unsigned u = __float_as_uint(acc[i][j]);
                unsigned ukey = (u & 0x80000000u) ? ~u : (u | 0x80000000u);
                unsigned long long key =
                    ((unsigned long long)ukey << 32) | (unsigned)(KD - 1 - gc);
                if (key > best) best = key;
            }
            red[ty * 4 + i][tx] = best;
        }
        __syncthreads();
        if (tid < 64) {
            unsigned long long best = 0;
#pragma unroll
            for (int q = 0; q < 16; ++q) {
                unsigned long long v = red[tid][q];
                if (v > best) best = v;
            }
            atomicMax(&keymax[row0 + tid], best);
        }
    } else {
#pragma unroll
        for (int i = 0; i < 4; ++i) {
            int gr = row0 + ty * 4 + i;
            if (GUARD && gr >= M) continue;
#pragma unroll
            for (int j = 0; j < 4; ++j) {
                int gc = col0 + tx * 4 + j;
                if (GUARD && gc >= N) continue;
                float v = acc[i][j];
                if (bias) v += bias[gc];
                C[(size_t)gr * N + gc] = v;
            }
        }
    }
}

// ---------------- generic helpers ----------------

__global__ __launch_bounds__(BLK) void transpose_k(const float* __restrict__ w,
                                                   float* __restrict__ wT, int O, int I) {
    int idx = blockIdx.x * BLK + threadIdx.x;
    if (idx >= O * I) return;
    int o = idx / I, i = idx % I;
    wT[(size_t)i * O + o] = w[idx];
}

__global__ __launch_bounds__(BLK) void rownorm_k(const float* __restrict__ in,
                                                 float* __restrict__ nrm, int rows, int cols) {
    int row  = blockIdx.x * (BLK / 64) + ((int)threadIdx.x / 64);
    int lane = threadIdx.x & 63;
    if (row >= rows) return;
    const float* p = in + (size_t)row * cols;
    float s = 0.f;
    for (int c = lane; c < cols; c += 64) { float v = p[c]; s += v * v; }
#pragma unroll
    for (int off = 32; off; off >>= 1) s += __shfl_down(s, off);
    if (lane == 0) nrm[row] = sqrtf(s);
}

__global__ __launch_bounds__(BLK) void normrow_k(const float* __restrict__ in,
                                                 const float* __restrict__ nrm,
                                                 float* __restrict__ out, int rows, int cols) {
    int idx = blockIdx.x * BLK + threadIdx.x;
    if (idx >= rows * cols) return;
    int r = idx / cols;
    out[idx] = in[idx] / fmaxf(nrm[r], 1e-12f);
}

__global__ __launch_bounds__(BLK) void normT_k(const float* __restrict__ in,
                                               const float* __restrict__ nrm,
                                               float* __restrict__ outT, int rows, int cols) {
    int idx = blockIdx.x * BLK + threadIdx.x;
    if (idx >= rows * cols) return;
    int r = idx / cols, c = idx % cols;
    outT[(size_t)c * rows + r] = in[idx] / fmaxf(nrm[r], 1e-12f);
}

__global__ __launch_bounds__(BLK) void ind_k(const unsigned long long* __restrict__ kb,
                                             int* __restrict__ ind) {
    int n = blockIdx.x * BLK + threadIdx.x;
    if (n < BB) ind[n] = (KD - 1) - (int)(unsigned)(kb[n] & 0xffffffffull);
}

__global__ __launch_bounds__(BLK) void scatter_k(const float* __restrict__ xx,
                                                 const int* __restrict__ ind,
                                                 float* __restrict__ esum,
                                                 float* __restrict__ counts) {
    int idx = blockIdx.x * BLK + threadIdx.x;
    if (idx >= BB * CD) return;
    int n = idx / CD, c = idx % CD;
    int k = ind[n];
    atomicAdd(&esum[(size_t)k * CD + c], xx[idx]);
    if (c == 0) atomicAdd(&counts[k], 1.0f);
}

// ss[c] += sum over 8 k-rows of esum[k][c]/(counts[k]+1e-6); ss pre-zeroed
__global__ __launch_bounds__(BLK) void ss2_k(const float* __restrict__ esum,
                                             const float* __restrict__ counts,
                                             float* __restrict__ ss) {
    int k0 = blockIdx.x * 8;
    int tid = threadIdx.x;
    float a0 = 0.f, a1 = 0.f;
    for (int r = 0; r < 8; ++r) {
        int k = k0 + r;
        float rc = 1.0f / (counts[k] + 1e-6f);
        a0 += esum[(size_t)k * CD + tid] * rc;
        if (tid < CD - BLK) a1 += esum[(size_t)k * CD + BLK + tid] * rc;
    }
    atomicAdd(&ss[tid], a0);
    if (tid < CD - BLK) atomicAdd(&ss[BLK + tid], a1);
}

__global__ __launch_bounds__(BLK) void mnew_k(const float* __restrict__ m,
                                              const float* __restrict__ esum,
                                              const float* __restrict__ counts,
                                              const float* __restrict__ ss,
                                              float* __restrict__ mnew) {
    int idx = blockIdx.x * BLK + threadIdx.x;
    if (idx >= KD * CD) return;
    int k = idx / CD, c = idx % CD;
    float mean = esum[idx] / (counts[k] + 1e-6f);
    float pd = (mean - ss[c]) * (2.0f / ((float)KD * (float)(KD - 1)));
    mnew[idx] = m[idx] * 0.99f + (mean + pd) * 0.01f;
}

__global__ __launch_bounds__(BLK) void scale_k(const float* __restrict__ out1,
                                               const float* __restrict__ t1,
                                               const float* __restrict__ t2,
                                               float* __restrict__ memout) {
    int idx = blockIdx.x * BLK + threadIdx.x;
    if (idx >= BB * CD) return;
    int n = idx / CD;
    memout[idx] = out1[idx] * (t1[n] / t2[n]);
}

__global__ __launch_bounds__(BLK) void cls_k(const float* __restrict__ fea,
                                             const float* __restrict__ up,
                                             const float* __restrict__ clsT,
                                             const float* __restrict__ clsb,
                                             float* __restrict__ out) {
    int t = blockIdx.x * BLK + threadIdx.x;
    if (t >= BB * 16) return;
    int o = t % 16, b = t / 16;
    const float* fp = fea + (size_t)b * CD;
    const float* up_ = up + (size_t)b * CD;
    float acc = clsb[o];
    for (int i = 0; i < CD; ++i) acc += (fp[i] - up_[i]) * clsT[i * 16 + o];
    out[t] = acc;
}

// ---------------- launch ----------------

static inline int cdiv(int a, int b) { return (a + b - 1) / b; }

extern "C" void kernel_launch(void* const* d_in, const int* in_sizes, int n_in,
                              void* d_out, int out_size, void* d_ws, size_t ws_size,
                              hipStream_t stream) {
    const float* x       = (const float*)d_in[0];
    const float* conv1_w = (const float*)d_in[1];
    const float* conv1_b = (const float*)d_in[2];
    const float* pool1_w = (const float*)d_in[3];
    const float* pool1_b = (const float*)d_in[4];
    const float* conv2_w = (const float*)d_in[5];
    const float* conv2_b = (const float*)d_in[6];
    const float* pool2_w = (const float*)d_in[7];
    const float* pool2_b = (const float*)d_in[8];
    const float* conv3_w = (const float*)d_in[9];
    const float* conv3_b = (const float*)d_in[10];
    const float* conv4_w = (const float*)d_in[11];
    const float* conv4_b = (const float*)d_in[12];
    const float* feat_w  = (const float*)d_in[13];
    const float* feat_b  = (const float*)d_in[14];
    const float* feat1_w = (const float*)d_in[15];
    const float* feat1_b = (const float*)d_in[16];
    const float* mem     = (const float*)d_in[17];
    const float* up_w    = (const float*)d_in[18];
    const float* up_b    = (const float*)d_in[19];
    const float* cls_w   = (const float*)d_in[20];
    const float* cls_b   = (const float*)d_in[21];
    float* outp = (float*)d_out;

    float* ws = (float*)d_ws;
    size_t off = 0;
    auto alloc = [&](size_t n) { float* p = ws + off; off += n; return p; };

    unsigned long long* keybuf = (unsigned long long*)alloc(2 * BB);  // 8B aligned (off=0)
    float* h2c   = alloc((size_t)CH2 * 17820);
    float* h3    = alloc((size_t)BB * 35 * 99);
    float* h6    = alloc((size_t)BB * 910);
    float* featT = alloc((size_t)910 * 400);
    float* f1T   = alloc((size_t)400 * 400);
    float* upT   = alloc((size_t)400 * 400);
    float* clsT  = alloc((size_t)400 * 16);
    float* fea   = alloc((size_t)BB * CD);
    float* xx    = alloc((size_t)BB * CD);
    float* xn    = alloc((size_t)BB * CD);
    float* mnT   = alloc((size_t)CD * KD);
    int*   ind   = (int*)alloc(BB);
    float* counts= alloc(KD);
    float* esum  = alloc((size_t)KD * CD);
    float* ssb   = alloc(CD);
    float* mnew  = alloc((size_t)KD * CD);
    float* mn2T  = alloc((size_t)CD * KD);
    float* G     = alloc((size_t)CD * CD);
    float* out1  = alloc((size_t)BB * CD);
    float* t1    = alloc(BB);
    float* t2    = alloc(BB);
    float* memout= alloc((size_t)BB * CD);
    float* upb   = alloc((size_t)BB * CD);
    float* mnrm  = alloc(KD);

    hipMemsetAsync(counts, 0, KD * sizeof(float), stream);
    hipMemsetAsync(esum, 0, (size_t)KD * CD * sizeof(float), stream);
    hipMemsetAsync(ssb, 0, CD * sizeof(float), stream);
    hipMemsetAsync(keybuf, 0, BB * sizeof(unsigned long long), stream);

    transpose_k<<<cdiv(400 * 910, BLK), BLK, 0, stream>>>(feat_w, featT, 400, 910);
    transpose_k<<<cdiv(400 * 400, BLK), BLK, 0, stream>>>(feat1_w, f1T, 400, 400);
    transpose_k<<<cdiv(400 * 400, BLK), BLK, 0, stream>>>(up_w, upT, 400, 400);
    transpose_k<<<cdiv(16 * 400, BLK), BLK, 0, stream>>>(cls_w, clsT, 16, 400);

    rownorm_k<<<cdiv(KD, 4), BLK, 0, stream>>>(mem, mnrm, KD, CD);
    normT_k<<<cdiv(KD * CD, BLK), BLK, 0, stream>>>(mem, mnrm, mnT, KD, CD);

    // conv stack
    for (int ch = 0; ch < NCH2; ++ch) {
        int b0 = ch * CH2;
        dim3 g12(CH2, 3);
        fused12_k<<<g12, 256, 0, stream>>>(x, conv1_w, conv1_b, pool1_w, pool1_b, h2c, b0);
        conv2b_k<<<CH2, 256, 0, stream>>>(h2c, conv2_w, conv2_b, h3, b0);
    }
    fused345_k<<<BB, 256, 0, stream>>>(h3, pool2_w, pool2_b, conv3_w, conv3_b,
                                       conv4_w, conv4_b, h6);

    // linears
    {
        dim3 g(cdiv(400, 64), cdiv(BB, 64));
        gemm_k<true, false><<<g, 256, 0, stream>>>(h6, featT, feat_b, fea, nullptr, BB, 400, 910);
        gemm_k<true, false><<<g, 256, 0, stream>>>(fea, f1T, feat1_b, xx, nullptr, BB, 400, 400);
    }

    // memory block
    rownorm_k<<<cdiv(BB, 4), BLK, 0, stream>>>(xx, t1, BB, CD);
    normrow_k<<<cdiv(BB * CD, BLK), BLK, 0, stream>>>(xx, t1, xn, BB, CD);

    // fused score1 + row-argmax (score matrix never materialized)
    {
        dim3 g(KD / 64, BB / 64);
        gemm_k<false, true><<<g, 256, 0, stream>>>(xn, mnT, nullptr, nullptr, keybuf, BB, KD, CD);
    }
    ind_k<<<cdiv(BB, BLK), BLK, 0, stream>>>(keybuf, ind);
    scatter_k<<<cdiv(BB * CD, BLK), BLK, 0, stream>>>(xx, ind, esum, counts);
    ss2_k<<<KD / 8, BLK, 0, stream>>>(esum, counts, ssb);
    mnew_k<<<cdiv(KD * CD, BLK), BLK, 0, stream>>>(mem, esum, counts, ssb, mnew);

    rownorm_k<<<cdiv(KD, 4), BLK, 0, stream>>>(mnew, mnrm, KD, CD);
    normT_k<<<cdiv(KD * CD, BLK), BLK, 0, stream>>>(mnew, mnrm, mn2T, KD, CD);

    // G = mn2T @ mnew (400x400, K=2048); out1 = xn @ G
    {
        dim3 g(cdiv(CD, 64), cdiv(CD, 64));
        gemm_k<true, false><<<g, 256, 0, stream>>>(mn2T, mnew, nullptr, G, nullptr, CD, CD, KD);
    }
    {
        dim3 g(cdiv(CD, 64), cdiv(BB, 64));
        gemm_k<true, false><<<g, 256, 0, stream>>>(xn, G, nullptr, out1, nullptr, BB, CD, CD);
    }
    rownorm_k<<<cdiv(BB, 4), BLK, 0, stream>>>(out1, t2, BB, CD);
    scale_k<<<cdiv(BB * CD, BLK), BLK, 0, stream>>>(out1, t1, t2, memout);

    {
        dim3 g(cdiv(400, 64), cdiv(BB, 64));
        gemm_k<true, false><<<g, 256, 0, stream>>>(memout, upT, up_b, upb, nullptr, BB, 400, 400);
    }
    cls_k<<<cdiv(BB * 16, BLK), BLK, 0, stream>>>(fea, upb, clsT, cls_b, outp);
}

// Round 5
// 1472.910 us; speedup vs baseline: 3.5595x; 1.2069x over previous
//
#include <hip/hip_runtime.h>

#define BLK 256

constexpr int BB   = 2048;  // batch
constexpr int CH2  = 512;   // batch chunk for conv1/pool1/conv2
constexpr int NCH2 = BB / CH2;
constexpr int KD   = 2048;  // codebook size
constexpr int CD   = 400;   // feature dim

// ---------------- fused conv1 + pool1 ----------------
__global__ __launch_bounds__(256) void fused12_k(const float* __restrict__ x,
                                                 const float* __restrict__ c1w,
                                                 const float* __restrict__ c1b,
                                                 const float* __restrict__ p1w,
                                                 const float* __restrict__ p1b,
                                                 float* __restrict__ h2c, int b0) {
    int bi = blockIdx.x;
    int o0 = blockIdx.y * 33;
    __shared__ float xs[69 * 25];
    __shared__ float c1[20][67][9];
    __shared__ float w1s[540];
    __shared__ float wps[1200];
    __shared__ float b1s[20], bps[20];
    int tid = threadIdx.x;
    for (int i = tid; i < 540; i += 256) w1s[i] = c1w[i];
    for (int i = tid; i < 1200; i += 256) wps[i] = p1w[i];
    if (tid < 20) { b1s[tid] = c1b[tid]; bps[tid] = p1b[tid]; }
    const float* xb = x + (size_t)(b0 + bi) * 5000;
    int r0 = 2 * o0 - 1;
    for (int i = tid; i < 69 * 25; i += 256) {
        int r = r0 + i / 25;
        xs[i] = (r >= 0 && r < 200) ? xb[r * 25 + (i % 25)] : 0.f;
    }
    __syncthreads();
    for (int it = tid; it < 20 * 67; it += 256) {
        int oc = it / 67, ri = it % 67;
        int r = r0 + ri;
        float acc[9];
        if (r >= 0 && r <= 197) {
#pragma unroll
            for (int j = 0; j < 9; ++j) acc[j] = b1s[oc];
            const float* wp1 = &w1s[oc * 27];
#pragma unroll
            for (int kd = 0; kd < 3; ++kd) {
                float xv[25];
                const float* xr = &xs[(ri + kd) * 25];
#pragma unroll
                for (int m = 0; m < 25; ++m) xv[m] = xr[m];
#pragma unroll
                for (int kh = 0; kh < 3; ++kh)
#pragma unroll
                    for (int kw = 0; kw < 3; ++kw) {
                        float w = wp1[kd * 9 + kh * 3 + kw];
#pragma unroll
                        for (int oh = 0; oh < 3; ++oh)
#pragma unroll
                            for (int ow = 0; ow < 3; ++ow)
                                acc[oh * 3 + ow] += xv[(oh + kh) * 5 + ow + kw] * w;
                    }
            }
#pragma unroll
            for (int j = 0; j < 9; ++j) acc[j] = fmaxf(acc[j], 0.f);
        } else {
#pragma unroll
            for (int j = 0; j < 9; ++j) acc[j] = 0.f;
        }
#pragma unroll
        for (int j = 0; j < 9; ++j) c1[oc][ri][j] = acc[j];
    }
    __syncthreads();
    for (int it = tid; it < 20 * 33; it += 256) {
        int oc = it / 33, oi = it % 33;
        float acc[9];
#pragma unroll
        for (int j = 0; j < 9; ++j) acc[j] = bps[oc];
        for (int ic = 0; ic < 20; ++ic) {
#pragma unroll
            for (int kd = 0; kd < 3; ++kd) {
                float w = wps[(oc * 20 + ic) * 3 + kd];
                int ri = 2 * oi + kd;
#pragma unroll
                for (int j = 0; j < 9; ++j) acc[j] += c1[ic][ri][j] * w;
            }
        }
        float* o = h2c + (((size_t)bi * 20 + oc) * 99 + (o0 + oi)) * 9;
#pragma unroll
        for (int j = 0; j < 9; ++j) o[j] = acc[j];
    }
}

// ---------------- conv2 ----------------
__global__ __launch_bounds__(256) void conv2b_k(const float* __restrict__ h2c,
                                                const float* __restrict__ w,
                                                const float* __restrict__ bias,
                                                float* __restrict__ h3, int b0) {
    int bi = blockIdx.x;
    __shared__ float h2s[10][101][9];
    __shared__ float ws[35 * 271];
    int tid = threadIdx.x;
    int oc = tid % 35, run = tid / 35;
    int od_start = run * 14;
    if (od_start > 84) od_start = 84;
    bool active = tid < 245;
    float acc[15];
    float bv = active ? bias[oc] : 0.f;
#pragma unroll
    for (int i = 0; i < 15; ++i) acc[i] = bv;
    const float* src = h2c + (size_t)bi * 17820;
    for (int s = 0; s < 2; ++s) {
        for (int i = tid; i < 10 * 9; i += 256) {
            int ic = i / 9, j = i % 9;
            h2s[ic][0][j] = 0.f; h2s[ic][100][j] = 0.f;
        }
        for (int i = tid; i < 8910; i += 256) {
            int ic = i / 891;
            ((float*)h2s)[i + ic * 18 + 9] = src[s * 8910 + i];
        }
        for (int i = tid; i < 35 * 270; i += 256) {
            int o = i / 270, t = i % 270;
            ws[o * 271 + t] = w[(size_t)o * 540 + s * 270 + t];
        }
        __syncthreads();
        if (active) {
            const float* wp = &ws[oc * 271];
            for (int ic = 0; ic < 10; ++ic) {
#pragma unroll
                for (int j = 0; j < 9; ++j) {
                    float win[17];
#pragma unroll
                    for (int t = 0; t < 17; ++t) win[t] = h2s[ic][od_start + t][j];
#pragma unroll
                    for (int kd = 0; kd < 3; ++kd) {
                        float wv = wp[(ic * 3 + kd) * 9 + j];
#pragma unroll
                        for (int i = 0; i < 15; ++i) acc[i] += win[i + kd] * wv;
                    }
                }
            }
        }
        __syncthreads();
    }
    if (active) {
        float* o = h3 + ((size_t)(b0 + bi) * 35 + oc) * 99 + od_start;
#pragma unroll
        for (int i = 0; i < 15; ++i) o[i] = fmaxf(acc[i], 0.f);
    }
}

// ---------------- fused pool2 + conv3 + conv4 ----------------
__global__ __launch_bounds__(256) void fused345_k(const float* __restrict__ h3,
                                                  const float* __restrict__ w2, const float* __restrict__ b2,
                                                  const float* __restrict__ w3, const float* __restrict__ b3,
                                                  const float* __restrict__ w4, const float* __restrict__ b4,
                                                  float* __restrict__ h6) {
    int b = blockIdx.x;
    __shared__ float h3s[35][101];
    __shared__ float h4s[35][52];
    __shared__ float h5s[35][52];
    __shared__ float wbuf[3675];
    __shared__ float bbuf[35];
    int tid = threadIdx.x;
    for (int i = tid; i < 35; i += 256) { h3s[i][0] = 0.f; h3s[i][100] = 0.f; }
    for (int i = tid; i < 35 * 99; i += 256) {
        int ic = i / 99, od = i % 99;
        h3s[ic][1 + od] = h3[((size_t)b * 35 + ic) * 99 + od];
    }
    for (int i = tid; i < 3675; i += 256) wbuf[i] = w2[i];
    if (tid < 35) bbuf[tid] = b2[tid];
    for (int i = tid; i < 35; i += 256) { h4s[i][0] = 0.f; h4s[i][51] = 0.f; }
    __syncthreads();
    for (int it = tid; it < 35 * 50; it += 256) {
        int oc = it / 50, od = it % 50;
        float acc = bbuf[oc];
        for (int ic = 0; ic < 35; ++ic) {
#pragma unroll
            for (int kd = 0; kd < 3; ++kd)
                acc += h3s[ic][2 * od + kd] * wbuf[(oc * 35 + ic) * 3 + kd];
        }
        h4s[oc][1 + od] = acc;
    }
    __syncthreads();
    for (int i = tid; i < 3675; i += 256) wbuf[i] = w3[i];
    if (tid < 35) bbuf[tid] = b3[tid];
    for (int i = tid; i < 35; i += 256) { h5s[i][0] = 0.f; h5s[i][51] = 0.f; }
    __syncthreads();
    for (int it = tid; it < 35 * 50; it += 256) {
        int oc = it / 50, od = it % 50;
        float acc = bbuf[oc];
        for (int ic = 0; ic < 35; ++ic) {
#pragma unroll
            for (int kd = 0; kd < 3; ++kd)
                acc += h4s[ic][od + kd] * wbuf[(oc * 35 + ic) * 3 + kd];
        }
        h5s[oc][1 + od] = fmaxf(acc, 0.f);
    }
    __syncthreads();
    for (int i = tid; i < 2450; i += 256) wbuf[i] = w4[i];
    if (tid < 35) bbuf[tid] = b4[tid];
    __syncthreads();
    for (int it = tid; it < 35 * 26; it += 256) {
        int oc = it / 26, od = it % 26;
        float acc = bbuf[oc];
        for (int ic = 0; ic < 35; ++ic) {
#pragma unroll
            for (int kd = 0; kd < 2; ++kd)
                acc += h5s[ic][2 * od + kd] * wbuf[(oc * 35 + ic) * 2 + kd];
        }
        h6[(size_t)b * 910 + oc * 26 + od] = fmaxf(acc, 0.f);
    }
}

// ---------------- NT-form tiled f32 GEMM ----------------
// C[M][N] = A[M][K] @ B[N][K]^T (+bias). B is torch-Linear layout (out,in).
// BM x BN tile, TM x TN micro, 256 threads. BK=16, k-major LDS (2-way max).
// ARGMAX: no C store; key = monotone(acc*colscale[gc]) packed with (N-1-gc),
// per-row atomicMax into keymax.
template <int BM, int BN, int TM, int TN, bool GUARD, bool ARGMAX>
__global__ __launch_bounds__(256) void gemm_nt(const float* __restrict__ A,
                                               const float* __restrict__ B,
                                               const float* __restrict__ bias,
                                               float* __restrict__ C,
                                               const float* __restrict__ colscale,
                                               unsigned long long* __restrict__ keymax,
                                               int M, int N, int K) {
    constexpr int BK = 16;
    __shared__ float As[BK][BM + 4];
    __shared__ float Bs[BK][BN + 4];
    int tid = threadIdx.x;
    int tx = tid % (BN / TN), ty = tid / (BN / TN);   // both 16-wide
    int row0 = blockIdx.y * BM;
    int col0 = blockIdx.x * BN;
    int kk = tid % 16, ld = tid / 16;
    float acc[TM][TN] = {};
    for (int k0 = 0; k0 < K; k0 += BK) {
        int gk = k0 + kk;
#pragma unroll
        for (int i = 0; i < BM / 16; ++i) {
            int rr = ld + 16 * i, gr = row0 + rr;
            float v = 0.f;
            if (!GUARD || (gr < M && gk < K)) v = A[(size_t)gr * K + gk];
            As[kk][rr] = v;
        }
#pragma unroll
        for (int i = 0; i < BN / 16; ++i) {
            int nn = ld + 16 * i, gn = col0 + nn;
            float v = 0.f;
            if (!GUARD || (gn < N && gk < K)) v = B[(size_t)gn * K + gk];
            Bs[kk][nn] = v;
        }
        __syncthreads();
#pragma unroll
        for (int k = 0; k < BK; ++k) {
            float a[TM], b[TN];
#pragma unroll
            for (int i = 0; i < TM; ++i) a[i] = As[k][ty * TM + i];
#pragma unroll
            for (int j = 0; j < TN; ++j) b[j] = Bs[k][tx * TN + j];
#pragma unroll
            for (int i = 0; i < TM; ++i)
#pragma unroll
                for (int j = 0; j < TN; ++j) acc[i][j] += a[i] * b[j];
        }
        __syncthreads();
    }
    if constexpr (ARGMAX) {
        __shared__ unsigned long long red[BM][17];
#pragma unroll
        for (int i = 0; i < TM; ++i) {
            unsigned long long best = 0;
#pragma unroll
            for (int j = 0; j < TN; ++j) {
                int gc = col0 + tx * TN + j;
                float v = acc[i][j] * colscale[gc];
                unsigned u = __float_as_uint(v);
                unsigned ukey = (u & 0x80000000u) ? ~u : (u | 0x80000000u);
                unsigned long long key =
                    ((unsigned long long)ukey << 32) | (unsigned)(N - 1 - gc);
                if (key > best) best = key;
            }
            red[ty * TM + i][tx] = best;
        }
        __syncthreads();
        if (tid < BM) {
            unsigned long long best = 0;
#pragma unroll
            for (int q = 0; q < 16; ++q) {
                unsigned long long v = red[tid][q];
                if (v > best) best = v;
            }
            atomicMax(&keymax[row0 + tid], best);
        }
    } else {
#pragma unroll
        for (int i = 0; i < TM; ++i) {
            int gr = row0 + ty * TM + i;
            if (GUARD && gr >= M) continue;
#pragma unroll
            for (int j = 0; j < TN; ++j) {
                int gc = col0 + tx * TN + j;
                if (GUARD && gc >= N) continue;
                float v = acc[i][j];
                if (bias) v += bias[gc];
                C[(size_t)gr * N + gc] = v;
            }
        }
    }
}

// ---------------- G = mnew^T diag(1/||mnew_k||) mnew, split-K ----------------
// grid (7,7,SPLIT); 64x64 tile, 4x4 micro; atomicAdd into pre-zeroed G[CD][CD].
__global__ __launch_bounds__(256) void gemm_tn_g(const float* __restrict__ mnew,
                                                 const float* __restrict__ nrm2,
                                                 float* __restrict__ G, int kchunk) {
    constexpr int BK = 16;
    __shared__ float As[BK][64];
    __shared__ float Bs[BK][64];
    int tid = threadIdx.x;
    int tx = tid % 16, ty = tid / 16;
    int c0 = blockIdx.y * 64, d0 = blockIdx.x * 64;
    int kbase = blockIdx.z * kchunk;
    int cl = tid % 64, kk0 = tid / 64;
    float acc[4][4] = {};
    for (int k0 = kbase; k0 < kbase + kchunk; k0 += BK) {
#pragma unroll
        for (int i = 0; i < 4; ++i) {
            int kk = kk0 + 4 * i, gk = k0 + kk;
            float s = 1.0f / fmaxf(nrm2[gk], 1e-12f);
            int gc = c0 + cl, gd = d0 + cl;
            As[kk][cl] = (gc < CD) ? mnew[(size_t)gk * CD + gc] * s : 0.f;
            Bs[kk][cl] = (gd < CD) ? mnew[(size_t)gk * CD + gd] : 0.f;
        }
        __syncthreads();
#pragma unroll
        for (int k = 0; k < BK; ++k) {
            float a[4], b[4];
#pragma unroll
            for (int i = 0; i < 4; ++i) a[i] = As[k][ty * 4 + i];
#pragma unroll
            for (int j = 0; j < 4; ++j) b[j] = Bs[k][tx * 4 + j];
#pragma unroll
            for (int i = 0; i < 4; ++i)
#pragma unroll
                for (int j = 0; j < 4; ++j) acc[i][j] += a[i] * b[j];
        }
        __syncthreads();
    }
#pragma unroll
    for (int i = 0; i < 4; ++i) {
        int gc = c0 + ty * 4 + i;
        if (gc >= CD) continue;
#pragma unroll
        for (int j = 0; j < 4; ++j) {
            int gd = d0 + tx * 4 + j;
            if (gd >= CD) continue;
            atomicAdd(&G[(size_t)gc * CD + gd], acc[i][j]);
        }
    }
}

// ---------------- helpers ----------------

__global__ __launch_bounds__(BLK) void rownorm_k(const float* __restrict__ in,
                                                 float* __restrict__ nrm, int rows, int cols) {
    int row  = blockIdx.x * (BLK / 64) + ((int)threadIdx.x / 64);
    int lane = threadIdx.x & 63;
    if (row >= rows) return;
    const float* p = in + (size_t)row * cols;
    float s = 0.f;
    for (int c = lane; c < cols; c += 64) { float v = p[c]; s += v * v; }
#pragma unroll
    for (int off = 32; off; off >>= 1) s += __shfl_down(s, off);
    if (lane == 0) nrm[row] = sqrtf(s);
}

__global__ __launch_bounds__(BLK) void ind_k(const unsigned long long* __restrict__ kb,
                                             int* __restrict__ ind) {
    int n = blockIdx.x * BLK + threadIdx.x;
    if (n < BB) ind[n] = (KD - 1) - (int)(unsigned)(kb[n] & 0xffffffffull);
}

__global__ __launch_bounds__(BLK) void scatter_k(const float* __restrict__ xx,
                                                 const int* __restrict__ ind,
                                                 float* __restrict__ esum,
                                                 float* __restrict__ counts) {
    int idx = blockIdx.x * BLK + threadIdx.x;
    if (idx >= BB * CD) return;
    int n = idx / CD, c = idx % CD;
    int k = ind[n];
    atomicAdd(&esum[(size_t)k * CD + c], xx[idx]);
    if (c == 0) atomicAdd(&counts[k], 1.0f);
}

__global__ __launch_bounds__(BLK) void ss2_k(const float* __restrict__ esum,
                                             const float* __restrict__ counts,
                                             float* __restrict__ ss) {
    int k0 = blockIdx.x * 8;
    int tid = threadIdx.x;
    float a0 = 0.f, a1 = 0.f;
    for (int r = 0; r < 8; ++r) {
        int k = k0 + r;
        float rc = 1.0f / (counts[k] + 1e-6f);
        a0 += esum[(size_t)k * CD + tid] * rc;
        if (tid < CD - BLK) a1 += esum[(size_t)k * CD + BLK + tid] * rc;
    }
    atomicAdd(&ss[tid], a0);
    if (tid < CD - BLK) atomicAdd(&ss[BLK + tid], a1);
}

__global__ __launch_bounds__(BLK) void mnew_k(const float* __restrict__ m,
                                              const float* __restrict__ esum,
                                              const float* __restrict__ counts,
                                              const float* __restrict__ ss,
                                              float* __restrict__ mnew) {
    int idx = blockIdx.x * BLK + threadIdx.x;
    if (idx >= KD * CD) return;
    int k = idx / CD, c = idx % CD;
    float mean = esum[idx] / (counts[k] + 1e-6f);
    float pd = (mean - ss[c]) * (2.0f / ((float)KD * (float)(KD - 1)));
    mnew[idx] = m[idx] * 0.99f + (mean + pd) * 0.01f;
}

// Q[o][c] = sum_i cls_w[o][i] * up_w[i][c]
__global__ __launch_bounds__(BLK) void q_k(const float* __restrict__ cls_w,
                                           const float* __restrict__ up_w,
                                           float* __restrict__ Q) {
    int idx = blockIdx.x * BLK + threadIdx.x;
    if (idx >= 16 * CD) return;
    int o = idx / CD, c = idx % CD;
    float s = 0.f;
    for (int i = 0; i < CD; ++i) s += cls_w[o * CD + i] * up_w[(size_t)i * CD + c];
    Q[idx] = s;
}

// bias2[o] = cls_b[o] - sum_i up_b[i]*cls_w[o][i]
__global__ __launch_bounds__(64) void bias2_k(const float* __restrict__ cls_w,
                                              const float* __restrict__ up_b,
                                              const float* __restrict__ cls_b,
                                              float* __restrict__ bias2) {
    int o = threadIdx.x;
    if (o >= 16) return;
    float s = 0.f;
    for (int i = 0; i < CD; ++i) s += up_b[i] * cls_w[o * CD + i];
    bias2[o] = cls_b[o] - s;
}

// logits[b][o] = bias2[o] + fea[b].cls_w[o] - (t1[b]/u[b]) * Y[b].Q[o]
__global__ __launch_bounds__(BLK) void cls2_k(const float* __restrict__ fea,
                                              const float* __restrict__ Y,
                                              const float* __restrict__ t1,
                                              const float* __restrict__ u,
                                              const float* __restrict__ cls_w,
                                              const float* __restrict__ Q,
                                              const float* __restrict__ bias2,
                                              float* __restrict__ out) {
    int t = blockIdx.x * BLK + threadIdx.x;
    if (t >= BB * 16) return;
    int o = t % 16, b = t / 16;
    float rs = t1[b] / u[b];
    const float* fp = fea + (size_t)b * CD;
    const float* yp = Y + (size_t)b * CD;
    const float* cw = cls_w + o * CD;
    const float* qp = Q + o * CD;
    float a1 = 0.f, a2 = 0.f;
    for (int i = 0; i < CD; ++i) { a1 += fp[i] * cw[i]; a2 += yp[i] * qp[i]; }
    out[t] = bias2[o] + a1 - rs * a2;
}

// ---------------- launch ----------------

static inline int cdiv(int a, int b) { return (a + b - 1) / b; }

extern "C" void kernel_launch(void* const* d_in, const int* in_sizes, int n_in,
                              void* d_out, int out_size, void* d_ws, size_t ws_size,
                              hipStream_t stream) {
    const float* x       = (const float*)d_in[0];
    const float* conv1_w = (const float*)d_in[1];
    const float* conv1_b = (const float*)d_in[2];
    const float* pool1_w = (const float*)d_in[3];
    const float* pool1_b = (const float*)d_in[4];
    const float* conv2_w = (const float*)d_in[5];
    const float* conv2_b = (const float*)d_in[6];
    const float* pool2_w = (const float*)d_in[7];
    const float* pool2_b = (const float*)d_in[8];
    const float* conv3_w = (const float*)d_in[9];
    const float* conv3_b = (const float*)d_in[10];
    const float* conv4_w = (const float*)d_in[11];
    const float* conv4_b = (const float*)d_in[12];
    const float* feat_w  = (const float*)d_in[13];
    const float* feat_b  = (const float*)d_in[14];
    const float* feat1_w = (const float*)d_in[15];
    const float* feat1_b = (const float*)d_in[16];
    const float* mem     = (const float*)d_in[17];
    const float* up_w    = (const float*)d_in[18];
    const float* up_b    = (const float*)d_in[19];
    const float* cls_w   = (const float*)d_in[20];
    const float* cls_b   = (const float*)d_in[21];
    float* outp = (float*)d_out;

    float* ws = (float*)d_ws;
    size_t off = 0;
    auto alloc = [&](size_t n) { float* p = ws + off; off += n; return p; };

    unsigned long long* keybuf = (unsigned long long*)alloc(2 * BB);  // 8B aligned (off=0)
    float* h2c   = alloc((size_t)CH2 * 17820);
    float* h3    = alloc((size_t)BB * 35 * 99);
    float* h6    = alloc((size_t)BB * 910);
    float* fea   = alloc((size_t)BB * CD);
    float* xx    = alloc((size_t)BB * CD);
    float* Y     = alloc((size_t)BB * CD);
    int*   ind   = (int*)alloc(BB);
    float* counts= alloc(KD);
    float* esum  = alloc((size_t)KD * CD);
    float* ssb   = alloc(CD);
    float* mnewb = alloc((size_t)KD * CD);
    float* G     = alloc((size_t)CD * CD);
    float* t1    = alloc(BB);
    float* u     = alloc(BB);
    float* Q     = alloc((size_t)16 * CD);
    float* bias2 = alloc(16);
    float* mnrm  = alloc(KD);
    float* nrm2  = alloc(KD);

    hipMemsetAsync(counts, 0, KD * sizeof(float), stream);
    hipMemsetAsync(esum, 0, (size_t)KD * CD * sizeof(float), stream);
    hipMemsetAsync(ssb, 0, CD * sizeof(float), stream);
    hipMemsetAsync(keybuf, 0, BB * sizeof(unsigned long long), stream);
    hipMemsetAsync(G, 0, (size_t)CD * CD * sizeof(float), stream);

    // weight-only precomputes (independent of activations)
    q_k<<<cdiv(16 * CD, BLK), BLK, 0, stream>>>(cls_w, up_w, Q);
    bias2_k<<<1, 64, 0, stream>>>(cls_w, up_b, cls_b, bias2);
    rownorm_k<<<cdiv(KD, 4), BLK, 0, stream>>>(mem, mnrm, KD, CD);

    // conv stack
    for (int ch = 0; ch < NCH2; ++ch) {
        int b0 = ch * CH2;
        dim3 g12(CH2, 3);
        fused12_k<<<g12, 256, 0, stream>>>(x, conv1_w, conv1_b, pool1_w, pool1_b, h2c, b0);
        conv2b_k<<<CH2, 256, 0, stream>>>(h2c, conv2_w, conv2_b, h3, b0);
    }
    fused345_k<<<BB, 256, 0, stream>>>(h3, pool2_w, pool2_b, conv3_w, conv3_b,
                                       conv4_w, conv4_b, h6);

    // fea = h6 @ feat_w^T + feat_b ; xx = fea @ feat1_w^T + feat1_b   (NT form)
    {
        dim3 g(cdiv(CD, 64), BB / 64);
        gemm_nt<64, 64, 4, 4, true, false><<<g, 256, 0, stream>>>(
            h6, feat_w, feat_b, fea, nullptr, nullptr, BB, CD, 910);
        gemm_nt<64, 64, 4, 4, true, false><<<g, 256, 0, stream>>>(
            fea, feat1_w, feat1_b, xx, nullptr, nullptr, BB, CD, CD);
    }

    rownorm_k<<<cdiv(BB, 4), BLK, 0, stream>>>(xx, t1, BB, CD);  // tend_1

    // fused score1 + argmax: raw = xx @ mem^T, key scaled by 1/||mem_k||
    {
        dim3 g(KD / 128, BB / 128);
        gemm_nt<128, 128, 8, 8, false, true><<<g, 256, 0, stream>>>(
            xx, mem, nullptr, nullptr, mnrm, keybuf, BB, KD, CD);
    }
    ind_k<<<cdiv(BB, BLK), BLK, 0, stream>>>(keybuf, ind);
    scatter_k<<<cdiv(BB * CD, BLK), BLK, 0, stream>>>(xx, ind, esum, counts);
    ss2_k<<<KD / 8, BLK, 0, stream>>>(esum, counts, ssb);
    mnew_k<<<cdiv(KD * CD, BLK), BLK, 0, stream>>>(mem, esum, counts, ssb, mnewb);

    rownorm_k<<<cdiv(KD, 4), BLK, 0, stream>>>(mnewb, nrm2, KD, CD);

    // G = mnew^T diag(1/||mnew_k||) mnew  (symmetric), split-K over 8 chunks
    {
        dim3 g(cdiv(CD, 64), cdiv(CD, 64), 8);
        gemm_tn_g<<<g, 256, 0, stream>>>(mnewb, nrm2, G, KD / 8);
    }
    // Y = xx @ G  (G symmetric -> NT form valid)
    {
        dim3 g(cdiv(CD, 64), BB / 64);
        gemm_nt<64, 64, 4, 4, true, false><<<g, 256, 0, stream>>>(
            xx, G, nullptr, Y, nullptr, nullptr, BB, CD, CD);
    }
    rownorm_k<<<cdiv(BB, 4), BLK, 0, stream>>>(Y, u, BB, CD);    // tend * t1g

    // logits = bias2 + fea@cls_w^T - (t1/u) * Y@Q^T
    cls2_k<<<cdiv(BB * 16, BLK), BLK, 0, stream>>>(fea, Y, t1, u, cls_w, Q, bias2, outp);
}

// Round 6
// 1279.820 us; speedup vs baseline: 4.0965x; 1.1509x over previous
//
#include <hip/hip_runtime.h>

#define BLK 256

constexpr int BB   = 2048;  // batch
constexpr int CH2  = 512;   // batch chunk for conv1/pool1/conv2
constexpr int NCH2 = BB / CH2;
constexpr int KD   = 2048;  // codebook size
constexpr int CD   = 400;   // feature dim

// ---------------- fused conv1 + pool1 ----------------
__global__ __launch_bounds__(256) void fused12_k(const float* __restrict__ x,
                                                 const float* __restrict__ c1w,
                                                 const float* __restrict__ c1b,
                                                 const float* __restrict__ p1w,
                                                 const float* __restrict__ p1b,
                                                 float* __restrict__ h2c, int b0) {
    int bi = blockIdx.x;
    int o0 = blockIdx.y * 33;
    __shared__ float xs[69 * 25];
    __shared__ float c1[20][67][9];
    __shared__ float w1s[540];
    __shared__ float wps[1200];
    __shared__ float b1s[20], bps[20];
    int tid = threadIdx.x;
    for (int i = tid; i < 540; i += 256) w1s[i] = c1w[i];
    for (int i = tid; i < 1200; i += 256) wps[i] = p1w[i];
    if (tid < 20) { b1s[tid] = c1b[tid]; bps[tid] = p1b[tid]; }
    const float* xb = x + (size_t)(b0 + bi) * 5000;
    int r0 = 2 * o0 - 1;
    for (int i = tid; i < 69 * 25; i += 256) {
        int r = r0 + i / 25;
        xs[i] = (r >= 0 && r < 200) ? xb[r * 25 + (i % 25)] : 0.f;
    }
    __syncthreads();
    for (int it = tid; it < 20 * 67; it += 256) {
        int oc = it / 67, ri = it % 67;
        int r = r0 + ri;
        float acc[9];
        if (r >= 0 && r <= 197) {
#pragma unroll
            for (int j = 0; j < 9; ++j) acc[j] = b1s[oc];
            const float* wp1 = &w1s[oc * 27];
#pragma unroll
            for (int kd = 0; kd < 3; ++kd) {
                float xv[25];
                const float* xr = &xs[(ri + kd) * 25];
#pragma unroll
                for (int m = 0; m < 25; ++m) xv[m] = xr[m];
#pragma unroll
                for (int kh = 0; kh < 3; ++kh)
#pragma unroll
                    for (int kw = 0; kw < 3; ++kw) {
                        float w = wp1[kd * 9 + kh * 3 + kw];
#pragma unroll
                        for (int oh = 0; oh < 3; ++oh)
#pragma unroll
                            for (int ow = 0; ow < 3; ++ow)
                                acc[oh * 3 + ow] += xv[(oh + kh) * 5 + ow + kw] * w;
                    }
            }
#pragma unroll
            for (int j = 0; j < 9; ++j) acc[j] = fmaxf(acc[j], 0.f);
        } else {
#pragma unroll
            for (int j = 0; j < 9; ++j) acc[j] = 0.f;
        }
#pragma unroll
        for (int j = 0; j < 9; ++j) c1[oc][ri][j] = acc[j];
    }
    __syncthreads();
    for (int it = tid; it < 20 * 33; it += 256) {
        int oc = it / 33, oi = it % 33;
        float acc[9];
#pragma unroll
        for (int j = 0; j < 9; ++j) acc[j] = bps[oc];
        for (int ic = 0; ic < 20; ++ic) {
#pragma unroll
            for (int kd = 0; kd < 3; ++kd) {
                float w = wps[(oc * 20 + ic) * 3 + kd];
                int ri = 2 * oi + kd;
#pragma unroll
                for (int j = 0; j < 9; ++j) acc[j] += c1[ic][ri][j] * w;
            }
        }
        float* o = h2c + (((size_t)bi * 20 + oc) * 99 + (o0 + oi)) * 9;
#pragma unroll
        for (int j = 0; j < 9; ++j) o[j] = acc[j];
    }
}

// ---------------- conv2 ----------------
__global__ __launch_bounds__(256) void conv2b_k(const float* __restrict__ h2c,
                                                const float* __restrict__ w,
                                                const float* __restrict__ bias,
                                                float* __restrict__ h3, int b0) {
    int bi = blockIdx.x;
    __shared__ float h2s[10][101][9];
    __shared__ float ws[35 * 271];
    int tid = threadIdx.x;
    int oc = tid % 35, run = tid / 35;
    int od_start = run * 14;
    if (od_start > 84) od_start = 84;
    bool active = tid < 245;
    float acc[15];
    float bv = active ? bias[oc] : 0.f;
#pragma unroll
    for (int i = 0; i < 15; ++i) acc[i] = bv;
    const float* src = h2c + (size_t)bi * 17820;
    for (int s = 0; s < 2; ++s) {
        for (int i = tid; i < 10 * 9; i += 256) {
            int ic = i / 9, j = i % 9;
            h2s[ic][0][j] = 0.f; h2s[ic][100][j] = 0.f;
        }
        for (int i = tid; i < 8910; i += 256) {
            int ic = i / 891;
            ((float*)h2s)[i + ic * 18 + 9] = src[s * 8910 + i];
        }
        for (int i = tid; i < 35 * 270; i += 256) {
            int o = i / 270, t = i % 270;
            ws[o * 271 + t] = w[(size_t)o * 540 + s * 270 + t];
        }
        __syncthreads();
        if (active) {
            const float* wp = &ws[oc * 271];
            for (int ic = 0; ic < 10; ++ic) {
#pragma unroll
                for (int j = 0; j < 9; ++j) {
                    float win[17];
#pragma unroll
                    for (int t = 0; t < 17; ++t) win[t] = h2s[ic][od_start + t][j];
#pragma unroll
                    for (int kd = 0; kd < 3; ++kd) {
                        float wv = wp[(ic * 3 + kd) * 9 + j];
#pragma unroll
                        for (int i = 0; i < 15; ++i) acc[i] += win[i + kd] * wv;
                    }
                }
            }
        }
        __syncthreads();
    }
    if (active) {
        float* o = h3 + ((size_t)(b0 + bi) * 35 + oc) * 99 + od_start;
#pragma unroll
        for (int i = 0; i < 15; ++i) o[i] = fmaxf(acc[i], 0.f);
    }
}

// ---------------- fused pool2 + conv3 + conv4 ----------------
__global__ __launch_bounds__(256) void fused345_k(const float* __restrict__ h3,
                                                  const float* __restrict__ w2, const float* __restrict__ b2,
                                                  const float* __restrict__ w3, const float* __restrict__ b3,
                                                  const float* __restrict__ w4, const float* __restrict__ b4,
                                                  float* __restrict__ h6) {
    int b = blockIdx.x;
    __shared__ float h3s[35][101];
    __shared__ float h4s[35][52];
    __shared__ float h5s[35][52];
    __shared__ float wbuf[3675];
    __shared__ float bbuf[35];
    int tid = threadIdx.x;
    for (int i = tid; i < 35; i += 256) { h3s[i][0] = 0.f; h3s[i][100] = 0.f; }
    for (int i = tid; i < 35 * 99; i += 256) {
        int ic = i / 99, od = i % 99;
        h3s[ic][1 + od] = h3[((size_t)b * 35 + ic) * 99 + od];
    }
    for (int i = tid; i < 3675; i += 256) wbuf[i] = w2[i];
    if (tid < 35) bbuf[tid] = b2[tid];
    for (int i = tid; i < 35; i += 256) { h4s[i][0] = 0.f; h4s[i][51] = 0.f; }
    __syncthreads();
    for (int it = tid; it < 35 * 50; it += 256) {
        int oc = it / 50, od = it % 50;
        float acc = bbuf[oc];
        for (int ic = 0; ic < 35; ++ic) {
#pragma unroll
            for (int kd = 0; kd < 3; ++kd)
                acc += h3s[ic][2 * od + kd] * wbuf[(oc * 35 + ic) * 3 + kd];
        }
        h4s[oc][1 + od] = acc;
    }
    __syncthreads();
    for (int i = tid; i < 3675; i += 256) wbuf[i] = w3[i];
    if (tid < 35) bbuf[tid] = b3[tid];
    for (int i = tid; i < 35; i += 256) { h5s[i][0] = 0.f; h5s[i][51] = 0.f; }
    __syncthreads();
    for (int it = tid; it < 35 * 50; it += 256) {
        int oc = it / 50, od = it % 50;
        float acc = bbuf[oc];
        for (int ic = 0; ic < 35; ++ic) {
#pragma unroll
            for (int kd = 0; kd < 3; ++kd)
                acc += h4s[ic][od + kd] * wbuf[(oc * 35 + ic) * 3 + kd];
        }
        h5s[oc][1 + od] = fmaxf(acc, 0.f);
    }
    __syncthreads();
    for (int i = tid; i < 2450; i += 256) wbuf[i] = w4[i];
    if (tid < 35) bbuf[tid] = b4[tid];
    __syncthreads();
    for (int it = tid; it < 35 * 26; it += 256) {
        int oc = it / 26, od = it % 26;
        float acc = bbuf[oc];
        for (int ic = 0; ic < 35; ++ic) {
#pragma unroll
            for (int kd = 0; kd < 2; ++kd)
                acc += h5s[ic][2 * od + kd] * wbuf[(oc * 35 + ic) * 2 + kd];
        }
        h6[(size_t)b * 910 + oc * 26 + od] = fmaxf(acc, 0.f);
    }
}

// ---------------- NT-form tiled f32 GEMM, reg-prefetch + float4 LDS ----------------
// C[M][N] = A[M][K] @ B[N][K]^T (+bias). B in torch-Linear layout (out,in).
// 256 threads, BMxBN tile, TMxTN micro (TM,TN in {4,8}), BK=16.
// SPLITK: gridDim.z chunks over K; atomicAdd into pre-zeroed C; bias from z==0.
// ARGMAX: no C store; key = monotone(acc*colscale[gc]) | (N-1-gc); atomicMax/row.
template <int BM, int BN, int TM, int TN, bool GUARD, bool ARGMAX, bool SPLITK>
__global__ __launch_bounds__(256) void gemm_nt(const float* __restrict__ A,
                                               const float* __restrict__ B,
                                               const float* __restrict__ bias,
                                               float* __restrict__ C,
                                               const float* __restrict__ colscale,
                                               unsigned long long* __restrict__ keymax,
                                               int M, int N, int K) {
    constexpr int BK = 16;
    constexpr int AI = BM / 16, BI = BN / 16;
    __shared__ float As[BK][BM + 4];
    __shared__ float Bs[BK][BN + 4];
    int tid = threadIdx.x;
    int tx = tid % (BN / TN), ty = tid / (BN / TN);
    int row0 = blockIdx.y * BM;
    int col0 = blockIdx.x * BN;
    int kbase = 0, kend = K;
    if constexpr (SPLITK) {
        int nz = gridDim.z;
        int kchunk = (((K + nz - 1) / nz) + BK - 1) / BK * BK;
        kbase = blockIdx.z * kchunk;
        kend = kbase + kchunk;
        if (kend > K) kend = K;
    }
    int kk = tid % 16, ld = tid / 16;
    float ra[AI], rb[BI];
    auto loadA = [&](int k0, float* r) {
        int gk = k0 + kk;
#pragma unroll
        for (int i = 0; i < AI; ++i) {
            int gr = row0 + ld + 16 * i;
            float v = 0.f;
            if ((!GUARD && !SPLITK) || (gr < M && gk < kend)) v = A[(size_t)gr * K + gk];
            r[i] = v;
        }
    };
    auto loadB = [&](int k0, float* r) {
        int gk = k0 + kk;
#pragma unroll
        for (int i = 0; i < BI; ++i) {
            int gn = col0 + ld + 16 * i;
            float v = 0.f;
            if ((!GUARD && !SPLITK) || (gn < N && gk < kend)) v = B[(size_t)gn * K + gk];
            r[i] = v;
        }
    };
    auto stash = [&]() {
#pragma unroll
        for (int i = 0; i < AI; ++i) As[kk][ld + 16 * i] = ra[i];
#pragma unroll
        for (int i = 0; i < BI; ++i) Bs[kk][ld + 16 * i] = rb[i];
    };
    float acc[TM][TN] = {};
    int nt = (kend - kbase + BK - 1) / BK;
    loadA(kbase, ra); loadB(kbase, rb);
    stash();
    __syncthreads();
    for (int t = 0; t < nt; ++t) {
        bool more = (t + 1 < nt);
        if (more) { loadA(kbase + (t + 1) * BK, ra); loadB(kbase + (t + 1) * BK, rb); }
#pragma unroll
        for (int k = 0; k < BK; ++k) {
            float a[TM], b[TN];
            *(float4*)&a[0] = *(const float4*)&As[k][ty * TM];
            if constexpr (TM == 8) *(float4*)&a[4] = *(const float4*)&As[k][ty * TM + 4];
            *(float4*)&b[0] = *(const float4*)&Bs[k][tx * TN];
            if constexpr (TN == 8) *(float4*)&b[4] = *(const float4*)&Bs[k][tx * TN + 4];
#pragma unroll
            for (int i = 0; i < TM; ++i)
#pragma unroll
                for (int j = 0; j < TN; ++j) acc[i][j] += a[i] * b[j];
        }
        if (more) {
            __syncthreads();
            stash();
            __syncthreads();
        }
    }
    if constexpr (ARGMAX) {
        __shared__ unsigned long long red[BM][17];
#pragma unroll
        for (int i = 0; i < TM; ++i) {
            unsigned long long best = 0;
#pragma unroll
            for (int j = 0; j < TN; ++j) {
                int gc = col0 + tx * TN + j;
                float v = acc[i][j] * colscale[gc];
                unsigned u = __float_as_uint(v);
                unsigned ukey = (u & 0x80000000u) ? ~u : (u | 0x80000000u);
                unsigned long long key =
                    ((unsigned long long)ukey << 32) | (unsigned)(N - 1 - gc);
                if (key > best) best = key;
            }
            red[ty * TM + i][tx] = best;
        }
        __syncthreads();
        if (tid < BM) {
            unsigned long long best = 0;
#pragma unroll
            for (int q = 0; q < 16; ++q) {
                unsigned long long v = red[tid][q];
                if (v > best) best = v;
            }
            atomicMax(&keymax[row0 + tid], best);
        }
    } else {
#pragma unroll
        for (int i = 0; i < TM; ++i) {
            int gr = row0 + ty * TM + i;
            if (GUARD && gr >= M) continue;
#pragma unroll
            for (int j = 0; j < TN; ++j) {
                int gc = col0 + tx * TN + j;
                if (GUARD && gc >= N) continue;
                float v = acc[i][j];
                if constexpr (SPLITK) {
                    if (bias && blockIdx.z == 0) v += bias[gc];
                    atomicAdd(&C[(size_t)gr * N + gc], v);
                } else {
                    if (bias) v += bias[gc];
                    C[(size_t)gr * N + gc] = v;
                }
            }
        }
    }
}

// ---------------- G = mnew^T diag(1/||mnew_k||) mnew, split-K ----------------
__global__ __launch_bounds__(256) void gemm_tn_g(const float* __restrict__ mnew,
                                                 const float* __restrict__ nrm2,
                                                 float* __restrict__ G, int kchunk) {
    constexpr int BK = 16;
    __shared__ float As[BK][64];
    __shared__ float Bs[BK][64];
    int tid = threadIdx.x;
    int tx = tid % 16, ty = tid / 16;
    int c0 = blockIdx.y * 64, d0 = blockIdx.x * 64;
    int kbase = blockIdx.z * kchunk;
    int cl = tid % 64, kk0 = tid / 64;
    float acc[4][4] = {};
    for (int k0 = kbase; k0 < kbase + kchunk; k0 += BK) {
#pragma unroll
        for (int i = 0; i < 4; ++i) {
            int kk = kk0 + 4 * i, gk = k0 + kk;
            float s = 1.0f / fmaxf(nrm2[gk], 1e-12f);
            int gc = c0 + cl, gd = d0 + cl;
            As[kk][cl] = (gc < CD) ? mnew[(size_t)gk * CD + gc] * s : 0.f;
            Bs[kk][cl] = (gd < CD) ? mnew[(size_t)gk * CD + gd] : 0.f;
        }
        __syncthreads();
#pragma unroll
        for (int k = 0; k < BK; ++k) {
            float a[4], b[4];
            *(float4*)&a[0] = *(const float4*)&As[k][ty * 4];
            *(float4*)&b[0] = *(const float4*)&Bs[k][tx * 4];
#pragma unroll
            for (int i = 0; i < 4; ++i)
#pragma unroll
                for (int j = 0; j < 4; ++j) acc[i][j] += a[i] * b[j];
        }
        __syncthreads();
    }
#pragma unroll
    for (int i = 0; i < 4; ++i) {
        int gc = c0 + ty * 4 + i;
        if (gc >= CD) continue;
#pragma unroll
        for (int j = 0; j < 4; ++j) {
            int gd = d0 + tx * 4 + j;
            if (gd >= CD) continue;
            atomicAdd(&G[(size_t)gc * CD + gd], acc[i][j]);
        }
    }
}

// ---------------- helpers ----------------

__global__ __launch_bounds__(BLK) void rownorm_k(const float* __restrict__ in,
                                                 float* __restrict__ nrm, int rows, int cols) {
    int row  = blockIdx.x * (BLK / 64) + ((int)threadIdx.x / 64);
    int lane = threadIdx.x & 63;
    if (row >= rows) return;
    const float* p = in + (size_t)row * cols;
    float s = 0.f;
    for (int c = lane; c < cols; c += 64) { float v = p[c]; s += v * v; }
#pragma unroll
    for (int off = 32; off; off >>= 1) s += __shfl_down(s, off);
    if (lane == 0) nrm[row] = sqrtf(s);
}

__global__ __launch_bounds__(BLK) void ind_k(const unsigned long long* __restrict__ kb,
                                             int* __restrict__ ind) {
    int n = blockIdx.x * BLK + threadIdx.x;
    if (n < BB) ind[n] = (KD - 1) - (int)(unsigned)(kb[n] & 0xffffffffull);
}

__global__ __launch_bounds__(BLK) void scatter_k(const float* __restrict__ xx,
                                                 const int* __restrict__ ind,
                                                 float* __restrict__ esum,
                                                 float* __restrict__ counts) {
    int idx = blockIdx.x * BLK + threadIdx.x;
    if (idx >= BB * CD) return;
    int n = idx / CD, c = idx % CD;
    int k = ind[n];
    atomicAdd(&esum[(size_t)k * CD + c], xx[idx]);
    if (c == 0) atomicAdd(&counts[k], 1.0f);
}

__global__ __launch_bounds__(BLK) void ss2_k(const float* __restrict__ esum,
                                             const float* __restrict__ counts,
                                             float* __restrict__ ss) {
    int k0 = blockIdx.x * 8;
    int tid = threadIdx.x;
    float a0 = 0.f, a1 = 0.f;
    for (int r = 0; r < 8; ++r) {
        int k = k0 + r;
        float rc = 1.0f / (counts[k] + 1e-6f);
        a0 += esum[(size_t)k * CD + tid] * rc;
        if (tid < CD - BLK) a1 += esum[(size_t)k * CD + BLK + tid] * rc;
    }
    atomicAdd(&ss[tid], a0);
    if (tid < CD - BLK) atomicAdd(&ss[BLK + tid], a1);
}

__global__ __launch_bounds__(BLK) void mnew_k(const float* __restrict__ m,
                                              const float* __restrict__ esum,
                                              const float* __restrict__ counts,
                                              const float* __restrict__ ss,
                                              float* __restrict__ mnew) {
    int idx = blockIdx.x * BLK + threadIdx.x;
    if (idx >= KD * CD) return;
    int k = idx / CD, c = idx % CD;
    float mean = esum[idx] / (counts[k] + 1e-6f);
    float pd = (mean - ss[c]) * (2.0f / ((float)KD * (float)(KD - 1)));
    mnew[idx] = m[idx] * 0.99f + (mean + pd) * 0.01f;
}

// Q[o][c] = sum_i cls_w[o][i] * up_w[i][c]
__global__ __launch_bounds__(BLK) void q_k(const float* __restrict__ cls_w,
                                           const float* __restrict__ up_w,
                                           float* __restrict__ Q) {
    int idx = blockIdx.x * BLK + threadIdx.x;
    if (idx >= 16 * CD) return;
    int o = idx / CD, c = idx % CD;
    float s = 0.f;
    for (int i = 0; i < CD; ++i) s += cls_w[o * CD + i] * up_w[(size_t)i * CD + c];
    Q[idx] = s;
}

// bias2[o] = cls_b[o] - sum_i up_b[i]*cls_w[o][i]
__global__ __launch_bounds__(64) void bias2_k(const float* __restrict__ cls_w,
                                              const float* __restrict__ up_b,
                                              const float* __restrict__ cls_b,
                                              float* __restrict__ bias2) {
    int o = threadIdx.x;
    if (o >= 16) return;
    float s = 0.f;
    for (int i = 0; i < CD; ++i) s += up_b[i] * cls_w[o * CD + i];
    bias2[o] = cls_b[o] - s;
}

// logits[b][o] = bias2[o] + fea[b].cls_w[o] - (t1[b]/u[b]) * Y[b].Q[o]
__global__ __launch_bounds__(BLK) void cls2_k(const float* __restrict__ fea,
                                              const float* __restrict__ Y,
                                              const float* __restrict__ t1,
                                              const float* __restrict__ u,
                                              const float* __restrict__ cls_w,
                                              const float* __restrict__ Q,
                                              const float* __restrict__ bias2,
                                              float* __restrict__ out) {
    int t = blockIdx.x * BLK + threadIdx.x;
    if (t >= BB * 16) return;
    int o = t % 16, b = t / 16;
    float rs = t1[b] / u[b];
    const float* fp = fea + (size_t)b * CD;
    const float* yp = Y + (size_t)b * CD;
    const float* cw = cls_w + o * CD;
    const float* qp = Q + o * CD;
    float a1 = 0.f, a2 = 0.f;
    for (int i = 0; i < CD; ++i) { a1 += fp[i] * cw[i]; a2 += yp[i] * qp[i]; }
    out[t] = bias2[o] + a1 - rs * a2;
}

// ---------------- launch ----------------

static inline int cdiv(int a, int b) { return (a + b - 1) / b; }

extern "C" void kernel_launch(void* const* d_in, const int* in_sizes, int n_in,
                              void* d_out, int out_size, void* d_ws, size_t ws_size,
                              hipStream_t stream) {
    const float* x       = (const float*)d_in[0];
    const float* conv1_w = (const float*)d_in[1];
    const float* conv1_b = (const float*)d_in[2];
    const float* pool1_w = (const float*)d_in[3];
    const float* pool1_b = (const float*)d_in[4];
    const float* conv2_w = (const float*)d_in[5];
    const float* conv2_b = (const float*)d_in[6];
    const float* pool2_w = (const float*)d_in[7];
    const float* pool2_b = (const float*)d_in[8];
    const float* conv3_w = (const float*)d_in[9];
    const float* conv3_b = (const float*)d_in[10];
    const float* conv4_w = (const float*)d_in[11];
    const float* conv4_b = (const float*)d_in[12];
    const float* feat_w  = (const float*)d_in[13];
    const float* feat_b  = (const float*)d_in[14];
    const float* feat1_w = (const float*)d_in[15];
    const float* feat1_b = (const float*)d_in[16];
    const float* mem     = (const float*)d_in[17];
    const float* up_w    = (const float*)d_in[18];
    const float* up_b    = (const float*)d_in[19];
    const float* cls_w   = (const float*)d_in[20];
    const float* cls_b   = (const float*)d_in[21];
    float* outp = (float*)d_out;

    float* ws = (float*)d_ws;
    size_t off = 0;
    auto alloc = [&](size_t n) { float* p = ws + off; off += n; return p; };

    unsigned long long* keybuf = (unsigned long long*)alloc(2 * BB);  // 8B aligned (off=0)
    float* h2c   = alloc((size_t)CH2 * 17820);
    float* h3    = alloc((size_t)BB * 35 * 99);
    float* h6    = alloc((size_t)BB * 910);
    float* fea   = alloc((size_t)BB * CD);
    float* xx    = alloc((size_t)BB * CD);
    float* Y     = alloc((size_t)BB * CD);
    int*   ind   = (int*)alloc(BB);
    float* counts= alloc(KD);
    float* esum  = alloc((size_t)KD * CD);
    float* ssb   = alloc(CD);
    float* mnewb = alloc((size_t)KD * CD);
    float* G     = alloc((size_t)CD * CD);
    float* t1    = alloc(BB);
    float* u     = alloc(BB);
    float* Q     = alloc((size_t)16 * CD);
    float* bias2 = alloc(16);
    float* mnrm  = alloc(KD);
    float* nrm2  = alloc(KD);

    hipMemsetAsync(counts, 0, KD * sizeof(float), stream);
    hipMemsetAsync(esum, 0, (size_t)KD * CD * sizeof(float), stream);
    hipMemsetAsync(ssb, 0, CD * sizeof(float), stream);
    hipMemsetAsync(keybuf, 0, BB * sizeof(unsigned long long), stream);
    hipMemsetAsync(G, 0, (size_t)CD * CD * sizeof(float), stream);
    hipMemsetAsync(fea, 0, (size_t)BB * CD * sizeof(float), stream);
    hipMemsetAsync(xx, 0, (size_t)BB * CD * sizeof(float), stream);
    hipMemsetAsync(Y, 0, (size_t)BB * CD * sizeof(float), stream);

    // weight-only precomputes
    q_k<<<cdiv(16 * CD, BLK), BLK, 0, stream>>>(cls_w, up_w, Q);
    bias2_k<<<1, 64, 0, stream>>>(cls_w, up_b, cls_b, bias2);
    rownorm_k<<<cdiv(KD, 4), BLK, 0, stream>>>(mem, mnrm, KD, CD);

    // conv stack
    for (int ch = 0; ch < NCH2; ++ch) {
        int b0 = ch * CH2;
        dim3 g12(CH2, 3);
        fused12_k<<<g12, 256, 0, stream>>>(x, conv1_w, conv1_b, pool1_w, pool1_b, h2c, b0);
        conv2b_k<<<CH2, 256, 0, stream>>>(h2c, conv2_w, conv2_b, h3, b0);
    }
    fused345_k<<<BB, 256, 0, stream>>>(h3, pool2_w, pool2_b, conv3_w, conv3_b,
                                       conv4_w, conv4_b, h6);

    // fea = h6 @ feat_w^T + feat_b ; xx = fea @ feat1_w^T + feat1_b (split-K=2)
    {
        dim3 g(cdiv(CD, 64), BB / 64, 2);
        gemm_nt<64, 64, 4, 4, true, false, true><<<g, 256, 0, stream>>>(
            h6, feat_w, feat_b, fea, nullptr, nullptr, BB, CD, 910);
        gemm_nt<64, 64, 4, 4, true, false, true><<<g, 256, 0, stream>>>(
            fea, feat1_w, feat1_b, xx, nullptr, nullptr, BB, CD, CD);
    }

    rownorm_k<<<cdiv(BB, 4), BLK, 0, stream>>>(xx, t1, BB, CD);  // tend_1

    // fused score1 + argmax: raw = xx @ mem^T, key scaled by 1/||mem_k||
    {
        dim3 g(KD / 128, BB / 128);
        gemm_nt<128, 128, 8, 8, false, true, false><<<g, 256, 0, stream>>>(
            xx, mem, nullptr, nullptr, mnrm, keybuf, BB, KD, CD);
    }
    ind_k<<<cdiv(BB, BLK), BLK, 0, stream>>>(keybuf, ind);
    scatter_k<<<cdiv(BB * CD, BLK), BLK, 0, stream>>>(xx, ind, esum, counts);
    ss2_k<<<KD / 8, BLK, 0, stream>>>(esum, counts, ssb);
    mnew_k<<<cdiv(KD * CD, BLK), BLK, 0, stream>>>(mem, esum, counts, ssb, mnewb);

    rownorm_k<<<cdiv(KD, 4), BLK, 0, stream>>>(mnewb, nrm2, KD, CD);

    // G = mnew^T diag(1/||mnew_k||) mnew (symmetric), split-K over 8 chunks
    {
        dim3 g(cdiv(CD, 64), cdiv(CD, 64), 8);
        gemm_tn_g<<<g, 256, 0, stream>>>(mnewb, nrm2, G, KD / 8);
    }
    // Y = xx @ G (G symmetric -> NT form valid), split-K=2
    {
        dim3 g(cdiv(CD, 64), BB / 64, 2);
        gemm_nt<64, 64, 4, 4, true, false, true><<<g, 256, 0, stream>>>(
            xx, G, nullptr, Y, nullptr, nullptr, BB, CD, CD);
    }
    rownorm_k<<<cdiv(BB, 4), BLK, 0, stream>>>(Y, u, BB, CD);    // tend * t1g

    // logits = bias2 + fea@cls_w^T - (t1/u) * Y@Q^T
    cls2_k<<<cdiv(BB * 16, BLK), BLK, 0, stream>>>(fea, Y, t1, u, cls_w, Q, bias2, outp);
}

// Round 7
// 1175.601 us; speedup vs baseline: 4.4597x; 1.0887x over previous
//
#include <hip/hip_runtime.h>

#define BLK 256

constexpr int BB   = 2048;  // batch
constexpr int CH2  = 512;   // batch chunk for conv1/pool1/conv2
constexpr int NCH2 = BB / CH2;
constexpr int KD   = 2048;  // codebook size
constexpr int CD   = 400;   // feature dim

// ---------------- fused conv1 + pool1 ----------------
__global__ __launch_bounds__(256) void fused12_k(const float* __restrict__ x,
                                                 const float* __restrict__ c1w,
                                                 const float* __restrict__ c1b,
                                                 const float* __restrict__ p1w,
                                                 const float* __restrict__ p1b,
                                                 float* __restrict__ h2c, int b0) {
    int bi = blockIdx.x;
    int o0 = blockIdx.y * 33;
    __shared__ float xs[69 * 25];
    __shared__ float c1[20][67][9];
    __shared__ float w1s[540];
    __shared__ float wps[1200];
    __shared__ float b1s[20], bps[20];
    int tid = threadIdx.x;
    for (int i = tid; i < 540; i += 256) w1s[i] = c1w[i];
    for (int i = tid; i < 1200; i += 256) wps[i] = p1w[i];
    if (tid < 20) { b1s[tid] = c1b[tid]; bps[tid] = p1b[tid]; }
    const float* xb = x + (size_t)(b0 + bi) * 5000;
    int r0 = 2 * o0 - 1;
    for (int i = tid; i < 69 * 25; i += 256) {
        int r = r0 + i / 25;
        xs[i] = (r >= 0 && r < 200) ? xb[r * 25 + (i % 25)] : 0.f;
    }
    __syncthreads();
    for (int it = tid; it < 20 * 67; it += 256) {
        int oc = it / 67, ri = it % 67;
        int r = r0 + ri;
        float acc[9];
        if (r >= 0 && r <= 197) {
#pragma unroll
            for (int j = 0; j < 9; ++j) acc[j] = b1s[oc];
            const float* wp1 = &w1s[oc * 27];
#pragma unroll
            for (int kd = 0; kd < 3; ++kd) {
                float xv[25];
                const float* xr = &xs[(ri + kd) * 25];
#pragma unroll
                for (int m = 0; m < 25; ++m) xv[m] = xr[m];
#pragma unroll
                for (int kh = 0; kh < 3; ++kh)
#pragma unroll
                    for (int kw = 0; kw < 3; ++kw) {
                        float w = wp1[kd * 9 + kh * 3 + kw];
#pragma unroll
                        for (int oh = 0; oh < 3; ++oh)
#pragma unroll
                            for (int ow = 0; ow < 3; ++ow)
                                acc[oh * 3 + ow] += xv[(oh + kh) * 5 + ow + kw] * w;
                    }
            }
#pragma unroll
            for (int j = 0; j < 9; ++j) acc[j] = fmaxf(acc[j], 0.f);
        } else {
#pragma unroll
            for (int j = 0; j < 9; ++j) acc[j] = 0.f;
        }
#pragma unroll
        for (int j = 0; j < 9; ++j) c1[oc][ri][j] = acc[j];
    }
    __syncthreads();
    for (int it = tid; it < 20 * 33; it += 256) {
        int oc = it / 33, oi = it % 33;
        float acc[9];
#pragma unroll
        for (int j = 0; j < 9; ++j) acc[j] = bps[oc];
        for (int ic = 0; ic < 20; ++ic) {
#pragma unroll
            for (int kd = 0; kd < 3; ++kd) {
                float w = wps[(oc * 20 + ic) * 3 + kd];
                int ri = 2 * oi + kd;
#pragma unroll
                for (int j = 0; j < 9; ++j) acc[j] += c1[ic][ri][j] * w;
            }
        }
        float* o = h2c + (((size_t)bi * 20 + oc) * 99 + (o0 + oi)) * 9;
#pragma unroll
        for (int j = 0; j < 9; ++j) o[j] = acc[j];
    }
}

// ---------------- conv2 ----------------
__global__ __launch_bounds__(256) void conv2b_k(const float* __restrict__ h2c,
                                                const float* __restrict__ w,
                                                const float* __restrict__ bias,
                                                float* __restrict__ h3, int b0) {
    int bi = blockIdx.x;
    __shared__ float h2s[10][101][9];
    __shared__ float ws[35 * 271];
    int tid = threadIdx.x;
    int oc = tid % 35, run = tid / 35;
    int od_start = run * 14;
    if (od_start > 84) od_start = 84;
    bool active = tid < 245;
    float acc[15];
    float bv = active ? bias[oc] : 0.f;
#pragma unroll
    for (int i = 0; i < 15; ++i) acc[i] = bv;
    const float* src = h2c + (size_t)bi * 17820;
    for (int s = 0; s < 2; ++s) {
        for (int i = tid; i < 10 * 9; i += 256) {
            int ic = i / 9, j = i % 9;
            h2s[ic][0][j] = 0.f; h2s[ic][100][j] = 0.f;
        }
        for (int i = tid; i < 8910; i += 256) {
            int ic = i / 891;
            ((float*)h2s)[i + ic * 18 + 9] = src[s * 8910 + i];
        }
        for (int i = tid; i < 35 * 270; i += 256) {
            int o = i / 270, t = i % 270;
            ws[o * 271 + t] = w[(size_t)o * 540 + s * 270 + t];
        }
        __syncthreads();
        if (active) {
            const float* wp = &ws[oc * 271];
            for (int ic = 0; ic < 10; ++ic) {
#pragma unroll
                for (int j = 0; j < 9; ++j) {
                    float win[17];
#pragma unroll
                    for (int t = 0; t < 17; ++t) win[t] = h2s[ic][od_start + t][j];
#pragma unroll
                    for (int kd = 0; kd < 3; ++kd) {
                        float wv = wp[(ic * 3 + kd) * 9 + j];
#pragma unroll
                        for (int i = 0; i < 15; ++i) acc[i] += win[i + kd] * wv;
                    }
                }
            }
        }
        __syncthreads();
    }
    if (active) {
        float* o = h3 + ((size_t)(b0 + bi) * 35 + oc) * 99 + od_start;
#pragma unroll
        for (int i = 0; i < 15; ++i) o[i] = fmaxf(acc[i], 0.f);
    }
}

// ---------------- fused pool2 + conv3 + conv4 (register-window version) ----------------
// Thread = (oc, run). Per ic the input window is loaded once into registers;
// all lanes of a run read the SAME LDS address (broadcast, conflict-free).
// h4s/h5s rows padded to 53 (odd) -> conflict-free cross-oc access.
__global__ __launch_bounds__(256) void fused345_k(const float* __restrict__ h3,
                                                  const float* __restrict__ w2, const float* __restrict__ b2,
                                                  const float* __restrict__ w3, const float* __restrict__ b3,
                                                  const float* __restrict__ w4, const float* __restrict__ b4,
                                                  float* __restrict__ h6) {
    int b = blockIdx.x;
    __shared__ float h3s[35][101];  // [ic][1+id], id in [-1..99]
    __shared__ float h4s[35][53];   // [ic][1+id], id in [-1..50]; data 1..50, pads 0,51
    __shared__ float h5s[35][53];
    __shared__ float wbuf[3675];
    __shared__ float bbuf[35];
    int tid = threadIdx.x;
    int oc = tid % 35, run = tid / 35;   // 7 runs for tid < 245
    bool act = tid < 245;
    for (int i = tid; i < 35; i += 256) {
        h3s[i][0] = 0.f; h3s[i][100] = 0.f;
        h4s[i][0] = 0.f; h4s[i][51] = 0.f;
        h5s[i][0] = 0.f; h5s[i][51] = 0.f;
    }
    for (int i = tid; i < 35 * 99; i += 256) h3s[i / 99][1 + i % 99] = h3[(size_t)b * 3465 + i];
    for (int i = tid; i < 3675; i += 256) wbuf[i] = w2[i];
    if (tid < 35) bbuf[tid] = b2[tid];
    __syncthreads();
    // pool2: k3 s2 p1, no relu. padded in-idx p = 2*od+kd. 8 outputs per thread.
    if (act) {
        int od0 = run * 7;          // 0..42, 8 outputs -> covers 0..49 (1-od overlap, same value)
        float acc[8];
        float bv = bbuf[oc];
#pragma unroll
        for (int i = 0; i < 8; ++i) acc[i] = bv;
        const float* wrow = &wbuf[oc * 105];
        for (int ic = 0; ic < 35; ++ic) {
            float w0 = wrow[ic * 3], w1 = wrow[ic * 3 + 1], w2v = wrow[ic * 3 + 2];
            float win[17];
#pragma unroll
            for (int t = 0; t < 17; ++t) win[t] = h3s[ic][2 * od0 + t];  // broadcast
#pragma unroll
            for (int i = 0; i < 8; ++i)
                acc[i] += win[2 * i] * w0 + win[2 * i + 1] * w1 + win[2 * i + 2] * w2v;
        }
#pragma unroll
        for (int i = 0; i < 8; ++i) h4s[oc][1 + od0 + i] = acc[i];
    }
    __syncthreads();
    for (int i = tid; i < 3675; i += 256) wbuf[i] = w3[i];
    if (tid < 35) bbuf[tid] = b3[tid];
    __syncthreads();
    // conv3: k3 s1 p1, relu. padded in-idx p = od+kd.
    if (act) {
        int od0 = run * 7;
        float acc[8];
        float bv = bbuf[oc];
#pragma unroll
        for (int i = 0; i < 8; ++i) acc[i] = bv;
        const float* wrow = &wbuf[oc * 105];
        for (int ic = 0; ic < 35; ++ic) {
            float w0 = wrow[ic * 3], w1 = wrow[ic * 3 + 1], w2v = wrow[ic * 3 + 2];
            float win[10];
#pragma unroll
            for (int t = 0; t < 10; ++t) win[t] = h4s[ic][od0 + t];  // broadcast
#pragma unroll
            for (int i = 0; i < 8; ++i)
                acc[i] += win[i] * w0 + win[i + 1] * w1 + win[i + 2] * w2v;
        }
#pragma unroll
        for (int i = 0; i < 8; ++i) h5s[oc][1 + od0 + i] = fmaxf(acc[i], 0.f);
    }
    __syncthreads();
    for (int i = tid; i < 2450; i += 256) wbuf[i] = w4[i];
    if (tid < 35) bbuf[tid] = b4[tid];
    __syncthreads();
    // conv4: k2 s2 p1, relu, out D=26. padded in-idx p = 2*od+kd.
    if (act) {
        int od0 = run * 4; if (od0 > 22) od0 = 22;   // covers 0..25, overlap benign
        float acc[4];
        float bv = bbuf[oc];
#pragma unroll
        for (int i = 0; i < 4; ++i) acc[i] = bv;
        const float* wrow = &wbuf[oc * 70];
        for (int ic = 0; ic < 35; ++ic) {
            float w0 = wrow[ic * 2], w1 = wrow[ic * 2 + 1];
            float win[8];
#pragma unroll
            for (int t = 0; t < 8; ++t) win[t] = h5s[ic][2 * od0 + t];  // broadcast
#pragma unroll
            for (int i = 0; i < 4; ++i)
                acc[i] += win[2 * i] * w0 + win[2 * i + 1] * w1;
        }
#pragma unroll
        for (int i = 0; i < 4; ++i) {
            int od = od0 + i;
            if (od < 26) h6[(size_t)b * 910 + oc * 26 + od] = fmaxf(acc[i], 0.f);
        }
    }
}

// ---------------- NT-form tiled f32 GEMM, reg-prefetch + float4 LDS ----------------
template <int BM, int BN, int TM, int TN, bool GUARD, bool ARGMAX, bool SPLITK>
__global__ __launch_bounds__(256) void gemm_nt(const float* __restrict__ A,
                                               const float* __restrict__ B,
                                               const float* __restrict__ bias,
                                               float* __restrict__ C,
                                               const float* __restrict__ colscale,
                                               unsigned long long* __restrict__ keymax,
                                               int M, int N, int K) {
    constexpr int BK = 16;
    constexpr int AI = BM / 16, BI = BN / 16;
    __shared__ float As[BK][BM + 4];
    __shared__ float Bs[BK][BN + 4];
    int tid = threadIdx.x;
    int tx = tid % (BN / TN), ty = tid / (BN / TN);
    int row0 = blockIdx.y * BM;
    int col0 = blockIdx.x * BN;
    int kbase = 0, kend = K;
    if constexpr (SPLITK) {
        int nz = gridDim.z;
        int kchunk = (((K + nz - 1) / nz) + BK - 1) / BK * BK;
        kbase = blockIdx.z * kchunk;
        kend = kbase + kchunk;
        if (kend > K) kend = K;
    }
    int kk = tid % 16, ld = tid / 16;
    float ra[AI], rb[BI];
    auto loadA = [&](int k0, float* r) {
        int gk = k0 + kk;
#pragma unroll
        for (int i = 0; i < AI; ++i) {
            int gr = row0 + ld + 16 * i;
            float v = 0.f;
            if ((!GUARD && !SPLITK) || (gr < M && gk < kend)) v = A[(size_t)gr * K + gk];
            r[i] = v;
        }
    };
    auto loadB = [&](int k0, float* r) {
        int gk = k0 + kk;
#pragma unroll
        for (int i = 0; i < BI; ++i) {
            int gn = col0 + ld + 16 * i;
            float v = 0.f;
            if ((!GUARD && !SPLITK) || (gn < N && gk < kend)) v = B[(size_t)gn * K + gk];
            r[i] = v;
        }
    };
    auto stash = [&]() {
#pragma unroll
        for (int i = 0; i < AI; ++i) As[kk][ld + 16 * i] = ra[i];
#pragma unroll
        for (int i = 0; i < BI; ++i) Bs[kk][ld + 16 * i] = rb[i];
    };
    float acc[TM][TN] = {};
    int nt = (kend - kbase + BK - 1) / BK;
    loadA(kbase, ra); loadB(kbase, rb);
    stash();
    __syncthreads();
    for (int t = 0; t < nt; ++t) {
        bool more = (t + 1 < nt);
        if (more) { loadA(kbase + (t + 1) * BK, ra); loadB(kbase + (t + 1) * BK, rb); }
#pragma unroll
        for (int k = 0; k < BK; ++k) {
            float a[TM], b[TN];
            *(float4*)&a[0] = *(const float4*)&As[k][ty * TM];
            if constexpr (TM == 8) *(float4*)&a[4] = *(const float4*)&As[k][ty * TM + 4];
            *(float4*)&b[0] = *(const float4*)&Bs[k][tx * TN];
            if constexpr (TN == 8) *(float4*)&b[4] = *(const float4*)&Bs[k][tx * TN + 4];
#pragma unroll
            for (int i = 0; i < TM; ++i)
#pragma unroll
                for (int j = 0; j < TN; ++j) acc[i][j] += a[i] * b[j];
        }
        if (more) {
            __syncthreads();
            stash();
            __syncthreads();
        }
    }
    if constexpr (ARGMAX) {
        __shared__ unsigned long long red[BM][17];
#pragma unroll
        for (int i = 0; i < TM; ++i) {
            unsigned long long best = 0;
#pragma unroll
            for (int j = 0; j < TN; ++j) {
                int gc = col0 + tx * TN + j;
                float v = acc[i][j] * colscale[gc];
                unsigned u = __float_as_uint(v);
                unsigned ukey = (u & 0x80000000u) ? ~u : (u | 0x80000000u);
                unsigned long long key =
                    ((unsigned long long)ukey << 32) | (unsigned)(N - 1 - gc);
                if (key > best) best = key;
            }
            red[ty * TM + i][tx] = best;
        }
        __syncthreads();
        if (tid < BM) {
            unsigned long long best = 0;
#pragma unroll
            for (int q = 0; q < 16; ++q) {
                unsigned long long v = red[tid][q];
                if (v > best) best = v;
            }
            atomicMax(&keymax[row0 + tid], best);
        }
    } else {
#pragma unroll
        for (int i = 0; i < TM; ++i) {
            int gr = row0 + ty * TM + i;
            if (GUARD && gr >= M) continue;
#pragma unroll
            for (int j = 0; j < TN; ++j) {
                int gc = col0 + tx * TN + j;
                if (GUARD && gc >= N) continue;
                float v = acc[i][j];
                if constexpr (SPLITK) {
                    if (bias && blockIdx.z == 0) v += bias[gc];
                    atomicAdd(&C[(size_t)gr * N + gc], v);
                } else {
                    if (bias) v += bias[gc];
                    C[(size_t)gr * N + gc] = v;
                }
            }
        }
    }
}

// ---------------- G = mnew^T diag(1/||mnew_k||) mnew, split-K, reg-prefetch ----------------
__global__ __launch_bounds__(256) void gemm_tn_g(const float* __restrict__ mnew,
                                                 const float* __restrict__ nrm2,
                                                 float* __restrict__ G, int kchunk) {
    constexpr int BK = 16;
    __shared__ float As[BK][64];
    __shared__ float Bs[BK][64];
    int tid = threadIdx.x;
    int tx = tid % 16, ty = tid / 16;
    int c0 = blockIdx.y * 64, d0 = blockIdx.x * 64;
    int kbase = blockIdx.z * kchunk;
    int cl = tid % 64, kk0 = tid / 64;
    int gc0 = c0 + cl, gd0 = d0 + cl;
    bool cok = gc0 < CD, dok = gd0 < CD;
    float pa[4], pb[4];
    auto ld = [&](int k0) {
#pragma unroll
        for (int i = 0; i < 4; ++i) {
            int gk = k0 + kk0 + 4 * i;
            float s = 1.0f / fmaxf(nrm2[gk], 1e-12f);
            pa[i] = cok ? mnew[(size_t)gk * CD + gc0] * s : 0.f;
            pb[i] = dok ? mnew[(size_t)gk * CD + gd0] : 0.f;
        }
    };
    auto stash = [&]() {
#pragma unroll
        for (int i = 0; i < 4; ++i) {
            As[kk0 + 4 * i][cl] = pa[i];
            Bs[kk0 + 4 * i][cl] = pb[i];
        }
    };
    float acc[4][4] = {};
    int nt = kchunk / BK;
    ld(kbase); stash(); __syncthreads();
    for (int t = 0; t < nt; ++t) {
        bool more = (t + 1 < nt);
        if (more) ld(kbase + (t + 1) * BK);
#pragma unroll
        for (int k = 0; k < BK; ++k) {
            float a[4], b[4];
            *(float4*)&a[0] = *(const float4*)&As[k][ty * 4];
            *(float4*)&b[0] = *(const float4*)&Bs[k][tx * 4];
#pragma unroll
            for (int i = 0; i < 4; ++i)
#pragma unroll
                for (int j = 0; j < 4; ++j) acc[i][j] += a[i] * b[j];
        }
        if (more) { __syncthreads(); stash(); __syncthreads(); }
    }
#pragma unroll
    for (int i = 0; i < 4; ++i) {
        int gc = c0 + ty * 4 + i;
        if (gc >= CD) continue;
#pragma unroll
        for (int j = 0; j < 4; ++j) {
            int gd = d0 + tx * 4 + j;
            if (gd >= CD) continue;
            atomicAdd(&G[(size_t)gc * CD + gd], acc[i][j]);
        }
    }
}

// ---------------- helpers ----------------

__global__ __launch_bounds__(BLK) void rownorm_k(const float* __restrict__ in,
                                                 float* __restrict__ nrm, int rows, int cols) {
    int row  = blockIdx.x * (BLK / 64) + ((int)threadIdx.x / 64);
    int lane = threadIdx.x & 63;
    if (row >= rows) return;
    const float* p = in + (size_t)row * cols;
    float s = 0.f;
    for (int c = lane; c < cols; c += 64) { float v = p[c]; s += v * v; }
#pragma unroll
    for (int off = 32; off; off >>= 1) s += __shfl_down(s, off);
    if (lane == 0) nrm[row] = sqrtf(s);
}

__global__ __launch_bounds__(BLK) void scatter_k(const float* __restrict__ xx,
                                                 const unsigned long long* __restrict__ kb,
                                                 float* __restrict__ esum,
                                                 float* __restrict__ counts) {
    int idx = blockIdx.x * BLK + threadIdx.x;
    if (idx >= BB * CD) return;
    int n = idx / CD, c = idx % CD;
    int k = (KD - 1) - (int)(unsigned)(kb[n] & 0xffffffffull);
    atomicAdd(&esum[(size_t)k * CD + c], xx[idx]);
    if (c == 0) atomicAdd(&counts[k], 1.0f);
}

__global__ __launch_bounds__(BLK) void ss2_k(const float* __restrict__ esum,
                                             const float* __restrict__ counts,
                                             float* __restrict__ ss) {
    int k0 = blockIdx.x * 8;
    int tid = threadIdx.x;
    float a0 = 0.f, a1 = 0.f;
    for (int r = 0; r < 8; ++r) {
        int k = k0 + r;
        float rc = 1.0f / (counts[k] + 1e-6f);
        a0 += esum[(size_t)k * CD + tid] * rc;
        if (tid < CD - BLK) a1 += esum[(size_t)k * CD + BLK + tid] * rc;
    }
    atomicAdd(&ss[tid], a0);
    if (tid < CD - BLK) atomicAdd(&ss[BLK + tid], a1);
}

__global__ __launch_bounds__(BLK) void mnew_k(const float* __restrict__ m,
                                              const float* __restrict__ esum,
                                              const float* __restrict__ counts,
                                              const float* __restrict__ ss,
                                              float* __restrict__ mnew) {
    int idx = blockIdx.x * BLK + threadIdx.x;
    if (idx >= KD * CD) return;
    int k = idx / CD, c = idx % CD;
    float mean = esum[idx] / (counts[k] + 1e-6f);
    float pd = (mean - ss[c]) * (2.0f / ((float)KD * (float)(KD - 1)));
    mnew[idx] = m[idx] * 0.99f + (mean + pd) * 0.01f;
}

// Q[o][c] = sum_i cls_w[o][i] * up_w[i][c]
__global__ __launch_bounds__(BLK) void q_k(const float* __restrict__ cls_w,
                                           const float* __restrict__ up_w,
                                           float* __restrict__ Q) {
    int idx = blockIdx.x * BLK + threadIdx.x;
    if (idx >= 16 * CD) return;
    int o = idx / CD, c = idx % CD;
    float s = 0.f;
    for (int i = 0; i < CD; ++i) s += cls_w[o * CD + i] * up_w[(size_t)i * CD + c];
    Q[idx] = s;
}

// bias2[o] = cls_b[o] - sum_i up_b[i]*cls_w[o][i]
__global__ __launch_bounds__(64) void bias2_k(const float* __restrict__ cls_w,
                                              const float* __restrict__ up_b,
                                              const float* __restrict__ cls_b,
                                              float* __restrict__ bias2) {
    int o = threadIdx.x;
    if (o >= 16) return;
    float s = 0.f;
    for (int i = 0; i < CD; ++i) s += up_b[i] * cls_w[o * CD + i];
    bias2[o] = cls_b[o] - s;
}

// logits[b][o] = bias2[o] + fea[b].cls_w[o] - (t1[b]/u[b]) * Y[b].Q[o]
__global__ __launch_bounds__(BLK) void cls2_k(const float* __restrict__ fea,
                                              const float* __restrict__ Y,
                                              const float* __restrict__ t1,
                                              const float* __restrict__ u,
                                              const float* __restrict__ cls_w,
                                              const float* __restrict__ Q,
                                              const float* __restrict__ bias2,
                                              float* __restrict__ out) {
    int t = blockIdx.x * BLK + threadIdx.x;
    if (t >= BB * 16) return;
    int o = t % 16, b = t / 16;
    float rs = t1[b] / u[b];
    const float* fp = fea + (size_t)b * CD;
    const float* yp = Y + (size_t)b * CD;
    const float* cw = cls_w + o * CD;
    const float* qp = Q + o * CD;
    float a1 = 0.f, a2 = 0.f;
    for (int i = 0; i < CD; ++i) { a1 += fp[i] * cw[i]; a2 += yp[i] * qp[i]; }
    out[t] = bias2[o] + a1 - rs * a2;
}

// ---------------- launch ----------------

static inline int cdiv(int a, int b) { return (a + b - 1) / b; }

extern "C" void kernel_launch(void* const* d_in, const int* in_sizes, int n_in,
                              void* d_out, int out_size, void* d_ws, size_t ws_size,
                              hipStream_t stream) {
    const float* x       = (const float*)d_in[0];
    const float* conv1_w = (const float*)d_in[1];
    const float* conv1_b = (const float*)d_in[2];
    const float* pool1_w = (const float*)d_in[3];
    const float* pool1_b = (const float*)d_in[4];
    const float* conv2_w = (const float*)d_in[5];
    const float* conv2_b = (const float*)d_in[6];
    const float* pool2_w = (const float*)d_in[7];
    const float* pool2_b = (const float*)d_in[8];
    const float* conv3_w = (const float*)d_in[9];
    const float* conv3_b = (const float*)d_in[10];
    const float* conv4_w = (const float*)d_in[11];
    const float* conv4_b = (const float*)d_in[12];
    const float* feat_w  = (const float*)d_in[13];
    const float* feat_b  = (const float*)d_in[14];
    const float* feat1_w = (const float*)d_in[15];
    const float* feat1_b = (const float*)d_in[16];
    const float* mem     = (const float*)d_in[17];
    const float* up_w    = (const float*)d_in[18];
    const float* up_b    = (const float*)d_in[19];
    const float* cls_w   = (const float*)d_in[20];
    const float* cls_b   = (const float*)d_in[21];
    float* outp = (float*)d_out;

    float* ws = (float*)d_ws;
    size_t off = 0;
    auto alloc = [&](size_t n) { float* p = ws + off; off += n; return p; };

    unsigned long long* keybuf = (unsigned long long*)alloc(2 * BB);  // 8B aligned (off=0)
    float* h2c   = alloc((size_t)CH2 * 17820);
    float* h3    = alloc((size_t)BB * 35 * 99);
    float* h6    = alloc((size_t)BB * 910);
    float* fea   = alloc((size_t)BB * CD);   // fea,xx,Y contiguous -> one memset
    float* xx    = alloc((size_t)BB * CD);
    float* Y     = alloc((size_t)BB * CD);
    float* counts= alloc(KD);                // counts,esum,ssb contiguous -> one memset
    float* esum  = alloc((size_t)KD * CD);
    float* ssb   = alloc(CD);
    float* mnewb = alloc((size_t)KD * CD);
    float* G     = alloc((size_t)CD * CD);
    float* t1    = alloc(BB);
    float* u     = alloc(BB);
    float* Q     = alloc((size_t)16 * CD);
    float* bias2 = alloc(16);
    float* mnrm  = alloc(KD);
    float* nrm2  = alloc(KD);

    hipMemsetAsync(keybuf, 0, BB * sizeof(unsigned long long), stream);
    hipMemsetAsync(counts, 0, (KD + (size_t)KD * CD + CD) * sizeof(float), stream);
    hipMemsetAsync(fea, 0, (size_t)3 * BB * CD * sizeof(float), stream);
    hipMemsetAsync(G, 0, (size_t)CD * CD * sizeof(float), stream);

    // weight-only precomputes
    q_k<<<cdiv(16 * CD, BLK), BLK, 0, stream>>>(cls_w, up_w, Q);
    bias2_k<<<1, 64, 0, stream>>>(cls_w, up_b, cls_b, bias2);
    rownorm_k<<<cdiv(KD, 4), BLK, 0, stream>>>(mem, mnrm, KD, CD);

    // conv stack
    for (int ch = 0; ch < NCH2; ++ch) {
        int b0 = ch * CH2;
        dim3 g12(CH2, 3);
        fused12_k<<<g12, 256, 0, stream>>>(x, conv1_w, conv1_b, pool1_w, pool1_b, h2c, b0);
        conv2b_k<<<CH2, 256, 0, stream>>>(h2c, conv2_w, conv2_b, h3, b0);
    }
    fused345_k<<<BB, 256, 0, stream>>>(h3, pool2_w, pool2_b, conv3_w, conv3_b,
                                       conv4_w, conv4_b, h6);

    // fea = h6 @ feat_w^T + feat_b ; xx = fea @ feat1_w^T + feat1_b (split-K=2)
    {
        dim3 g(cdiv(CD, 64), BB / 64, 2);
        gemm_nt<64, 64, 4, 4, true, false, true><<<g, 256, 0, stream>>>(
            h6, feat_w, feat_b, fea, nullptr, nullptr, BB, CD, 910);
        gemm_nt<64, 64, 4, 4, true, false, true><<<g, 256, 0, stream>>>(
            fea, feat1_w, feat1_b, xx, nullptr, nullptr, BB, CD, CD);
    }

    rownorm_k<<<cdiv(BB, 4), BLK, 0, stream>>>(xx, t1, BB, CD);  // tend_1

    // fused score1 + argmax: raw = xx @ mem^T, key scaled by 1/||mem_k||
    {
        dim3 g(KD / 128, BB / 128);
        gemm_nt<128, 128, 8, 8, false, true, false><<<g, 256, 0, stream>>>(
            xx, mem, nullptr, nullptr, mnrm, keybuf, BB, KD, CD);
    }
    scatter_k<<<cdiv(BB * CD, BLK), BLK, 0, stream>>>(xx, keybuf, esum, counts);
    ss2_k<<<KD / 8, BLK, 0, stream>>>(esum, counts, ssb);
    mnew_k<<<cdiv(KD * CD, BLK), BLK, 0, stream>>>(mem, esum, counts, ssb, mnewb);

    rownorm_k<<<cdiv(KD, 4), BLK, 0, stream>>>(mnewb, nrm2, KD, CD);

    // G = mnew^T diag(1/||mnew_k||) mnew (symmetric), split-K over 8 chunks
    {
        dim3 g(cdiv(CD, 64), cdiv(CD, 64), 8);
        gemm_tn_g<<<g, 256, 0, stream>>>(mnewb, nrm2, G, KD / 8);
    }
    // Y = xx @ G (G symmetric -> NT form valid), split-K=2
    {
        dim3 g(cdiv(CD, 64), BB / 64, 2);
        gemm_nt<64, 64, 4, 4, true, false, true><<<g, 256, 0, stream>>>(
            xx, G, nullptr, Y, nullptr, nullptr, BB, CD, CD);
    }
    rownorm_k<<<cdiv(BB, 4), BLK, 0, stream>>>(Y, u, BB, CD);    // tend * t1g

    // logits = bias2 + fea@cls_w^T - (t1/u) * Y@Q^T
    cls2_k<<<cdiv(BB * 16, BLK), BLK, 0, stream>>>(fea, Y, t1, u, cls_w, Q, bias2, outp);
}

// Round 8
// 1002.673 us; speedup vs baseline: 5.2288x; 1.1725x over previous
//
#include <hip/hip_runtime.h>

#define BLK 256

constexpr int BB   = 2048;  // batch
constexpr int CH2  = 512;   // batch chunk for conv1/pool1/conv2
constexpr int NCH2 = BB / CH2;
constexpr int KD   = 2048;  // codebook size
constexpr int CD   = 400;   // feature dim

// ---------------- fused conv1 + pool1 (oc-grouped, broadcast-ordered) ----------------
// Per block: one batch elem, one od2-stripe of 33 (99 = 3 stripes).
// Phase 1: thread=(ri, 4-oc group): x-window regs feed 4 oc -> 1:5 read:FMA.
// Phase 2: thread=(oi, 4-oc group): c1-window regs broadcast across group,
// distinct-oi lanes hit distinct banks (stride 18) -> conflict-free.
__global__ __launch_bounds__(256) void fused12_k(const float* __restrict__ x,
                                                 const float* __restrict__ c1w,
                                                 const float* __restrict__ c1b,
                                                 const float* __restrict__ p1w,
                                                 const float* __restrict__ p1b,
                                                 float* __restrict__ h2c, int b0) {
    int bi = blockIdx.x;
    int o0 = blockIdx.y * 33;
    __shared__ float xs[69 * 25];
    __shared__ float c1[20][67][9];
    __shared__ float w1s[540];
    __shared__ float wps[1200];
    __shared__ float b1s[20], bps[20];
    int tid = threadIdx.x;
    for (int i = tid; i < 540; i += 256) w1s[i] = c1w[i];
    for (int i = tid; i < 1200; i += 256) wps[i] = p1w[i];
    if (tid < 20) { b1s[tid] = c1b[tid]; bps[tid] = p1b[tid]; }
    const float* xb = x + (size_t)(b0 + bi) * 5000;
    int r0 = 2 * o0 - 1;
    for (int i = tid; i < 69 * 25; i += 256) {
        int r = r0 + i / 25;
        xs[i] = (r >= 0 && r < 200) ? xb[r * 25 + (i % 25)] : 0.f;
    }
    __syncthreads();
    // phase 1: conv1, items = 67 ri x 5 groups (4 oc each)
    for (int it = tid; it < 67 * 5; it += 256) {
        int ri = it / 5, g = it % 5;
        int oc0 = g * 4;
        int r = r0 + ri;
        float acc[4][9];
        if (r >= 0 && r <= 197) {
#pragma unroll
            for (int o = 0; o < 4; ++o)
#pragma unroll
                for (int j = 0; j < 9; ++j) acc[o][j] = b1s[oc0 + o];
#pragma unroll
            for (int kd = 0; kd < 3; ++kd) {
                float xv[25];
                const float* xr = &xs[(ri + kd) * 25];
#pragma unroll
                for (int m = 0; m < 25; ++m) xv[m] = xr[m];
#pragma unroll
                for (int o = 0; o < 4; ++o) {
                    const float* wp1 = &w1s[(oc0 + o) * 27 + kd * 9];
#pragma unroll
                    for (int kh = 0; kh < 3; ++kh)
#pragma unroll
                        for (int kw = 0; kw < 3; ++kw) {
                            float w = wp1[kh * 3 + kw];
#pragma unroll
                            for (int oh = 0; oh < 3; ++oh)
#pragma unroll
                                for (int ow = 0; ow < 3; ++ow)
                                    acc[o][oh * 3 + ow] += xv[(oh + kh) * 5 + ow + kw] * w;
                        }
                }
            }
#pragma unroll
            for (int o = 0; o < 4; ++o)
#pragma unroll
                for (int j = 0; j < 9; ++j) c1[oc0 + o][ri][j] = fmaxf(acc[o][j], 0.f);
        } else {
#pragma unroll
            for (int o = 0; o < 4; ++o)
#pragma unroll
                for (int j = 0; j < 9; ++j) c1[oc0 + o][ri][j] = 0.f;
        }
    }
    __syncthreads();
    // phase 2: pool1, items = 33 oi x 5 groups (4 oc each); ri = 2*oi + kd
    for (int it = tid; it < 33 * 5; it += 256) {
        int oi = it / 5, g = it % 5;
        int oc0 = g * 4;
        float acc[4][9];
#pragma unroll
        for (int o = 0; o < 4; ++o)
#pragma unroll
            for (int j = 0; j < 9; ++j) acc[o][j] = bps[oc0 + o];
        for (int ic = 0; ic < 20; ++ic) {
            float win[3][9];
#pragma unroll
            for (int kd = 0; kd < 3; ++kd)
#pragma unroll
                for (int j = 0; j < 9; ++j) win[kd][j] = c1[ic][2 * oi + kd][j];
#pragma unroll
            for (int o = 0; o < 4; ++o) {
                const float* wp = &wps[((oc0 + o) * 20 + ic) * 3];
#pragma unroll
                for (int kd = 0; kd < 3; ++kd) {
                    float w = wp[kd];
#pragma unroll
                    for (int j = 0; j < 9; ++j) acc[o][j] += win[kd][j] * w;
                }
            }
        }
#pragma unroll
        for (int o = 0; o < 4; ++o) {
            float* ou = h2c + (((size_t)bi * 20 + (oc0 + o)) * 99 + (o0 + oi)) * 9;
#pragma unroll
            for (int j = 0; j < 9; ++j) ou[j] = acc[o][j];
        }
    }
}

// ---------------- conv2 ----------------
__global__ __launch_bounds__(256) void conv2b_k(const float* __restrict__ h2c,
                                                const float* __restrict__ w,
                                                const float* __restrict__ bias,
                                                float* __restrict__ h3, int b0) {
    int bi = blockIdx.x;
    __shared__ float h2s[10][101][9];
    __shared__ float ws[35 * 271];
    int tid = threadIdx.x;
    int oc = tid % 35, run = tid / 35;
    int od_start = run * 14;
    if (od_start > 84) od_start = 84;
    bool active = tid < 245;
    float acc[15];
    float bv = active ? bias[oc] : 0.f;
#pragma unroll
    for (int i = 0; i < 15; ++i) acc[i] = bv;
    const float* src = h2c + (size_t)bi * 17820;
    for (int s = 0; s < 2; ++s) {
        for (int i = tid; i < 10 * 9; i += 256) {
            int ic = i / 9, j = i % 9;
            h2s[ic][0][j] = 0.f; h2s[ic][100][j] = 0.f;
        }
        for (int i = tid; i < 8910; i += 256) {
            int ic = i / 891;
            ((float*)h2s)[i + ic * 18 + 9] = src[s * 8910 + i];
        }
        for (int i = tid; i < 35 * 270; i += 256) {
            int o = i / 270, t = i % 270;
            ws[o * 271 + t] = w[(size_t)o * 540 + s * 270 + t];
        }
        __syncthreads();
        if (active) {
            const float* wp = &ws[oc * 271];
            for (int ic = 0; ic < 10; ++ic) {
#pragma unroll
                for (int j = 0; j < 9; ++j) {
                    float win[17];
#pragma unroll
                    for (int t = 0; t < 17; ++t) win[t] = h2s[ic][od_start + t][j];
#pragma unroll
                    for (int kd = 0; kd < 3; ++kd) {
                        float wv = wp[(ic * 3 + kd) * 9 + j];
#pragma unroll
                        for (int i = 0; i < 15; ++i) acc[i] += win[i + kd] * wv;
                    }
                }
            }
        }
        __syncthreads();
    }
    if (active) {
        float* o = h3 + ((size_t)(b0 + bi) * 35 + oc) * 99 + od_start;
#pragma unroll
        for (int i = 0; i < 15; ++i) o[i] = fmaxf(acc[i], 0.f);
    }
}

// ---------------- fused pool2 + conv3 + conv4 (register-window version) ----------------
__global__ __launch_bounds__(256) void fused345_k(const float* __restrict__ h3,
                                                  const float* __restrict__ w2, const float* __restrict__ b2,
                                                  const float* __restrict__ w3, const float* __restrict__ b3,
                                                  const float* __restrict__ w4, const float* __restrict__ b4,
                                                  float* __restrict__ h6) {
    int b = blockIdx.x;
    __shared__ float h3s[35][101];
    __shared__ float h4s[35][53];
    __shared__ float h5s[35][53];
    __shared__ float wbuf[3675];
    __shared__ float bbuf[35];
    int tid = threadIdx.x;
    int oc = tid % 35, run = tid / 35;
    bool act = tid < 245;
    for (int i = tid; i < 35; i += 256) {
        h3s[i][0] = 0.f; h3s[i][100] = 0.f;
        h4s[i][0] = 0.f; h4s[i][51] = 0.f;
        h5s[i][0] = 0.f; h5s[i][51] = 0.f;
    }
    for (int i = tid; i < 35 * 99; i += 256) h3s[i / 99][1 + i % 99] = h3[(size_t)b * 3465 + i];
    for (int i = tid; i < 3675; i += 256) wbuf[i] = w2[i];
    if (tid < 35) bbuf[tid] = b2[tid];
    __syncthreads();
    if (act) {
        int od0 = run * 7;
        float acc[8];
        float bv = bbuf[oc];
#pragma unroll
        for (int i = 0; i < 8; ++i) acc[i] = bv;
        const float* wrow = &wbuf[oc * 105];
        for (int ic = 0; ic < 35; ++ic) {
            float w0 = wrow[ic * 3], w1 = wrow[ic * 3 + 1], w2v = wrow[ic * 3 + 2];
            float win[17];
#pragma unroll
            for (int t = 0; t < 17; ++t) win[t] = h3s[ic][2 * od0 + t];
#pragma unroll
            for (int i = 0; i < 8; ++i)
                acc[i] += win[2 * i] * w0 + win[2 * i + 1] * w1 + win[2 * i + 2] * w2v;
        }
#pragma unroll
        for (int i = 0; i < 8; ++i) h4s[oc][1 + od0 + i] = acc[i];
    }
    __syncthreads();
    for (int i = tid; i < 3675; i += 256) wbuf[i] = w3[i];
    if (tid < 35) bbuf[tid] = b3[tid];
    __syncthreads();
    if (act) {
        int od0 = run * 7;
        float acc[8];
        float bv = bbuf[oc];
#pragma unroll
        for (int i = 0; i < 8; ++i) acc[i] = bv;
        const float* wrow = &wbuf[oc * 105];
        for (int ic = 0; ic < 35; ++ic) {
            float w0 = wrow[ic * 3], w1 = wrow[ic * 3 + 1], w2v = wrow[ic * 3 + 2];
            float win[10];
#pragma unroll
            for (int t = 0; t < 10; ++t) win[t] = h4s[ic][od0 + t];
#pragma unroll
            for (int i = 0; i < 8; ++i)
                acc[i] += win[i] * w0 + win[i + 1] * w1 + win[i + 2] * w2v;
        }
#pragma unroll
        for (int i = 0; i < 8; ++i) h5s[oc][1 + od0 + i] = fmaxf(acc[i], 0.f);
    }
    __syncthreads();
    for (int i = tid; i < 2450; i += 256) wbuf[i] = w4[i];
    if (tid < 35) bbuf[tid] = b4[tid];
    __syncthreads();
    if (act) {
        int od0 = run * 4; if (od0 > 22) od0 = 22;
        float acc[4];
        float bv = bbuf[oc];
#pragma unroll
        for (int i = 0; i < 4; ++i) acc[i] = bv;
        const float* wrow = &wbuf[oc * 70];
        for (int ic = 0; ic < 35; ++ic) {
            float w0 = wrow[ic * 2], w1 = wrow[ic * 2 + 1];
            float win[8];
#pragma unroll
            for (int t = 0; t < 8; ++t) win[t] = h5s[ic][2 * od0 + t];
#pragma unroll
            for (int i = 0; i < 4; ++i)
                acc[i] += win[2 * i] * w0 + win[2 * i + 1] * w1;
        }
#pragma unroll
        for (int i = 0; i < 4; ++i) {
            int od = od0 + i;
            if (od < 26) h6[(size_t)b * 910 + oc * 26 + od] = fmaxf(acc[i], 0.f);
        }
    }
}

// ---------------- NT-form tiled f32 GEMM, reg-prefetch + float4 LDS ----------------
template <int BM, int BN, int TM, int TN, bool GUARD, bool ARGMAX, bool SPLITK>
__global__ __launch_bounds__(256) void gemm_nt(const float* __restrict__ A,
                                               const float* __restrict__ B,
                                               const float* __restrict__ bias,
                                               float* __restrict__ C,
                                               const float* __restrict__ colscale,
                                               unsigned long long* __restrict__ keymax,
                                               int M, int N, int K) {
    constexpr int BK = 16;
    constexpr int AI = BM / 16, BI = BN / 16;
    __shared__ float As[BK][BM + 4];
    __shared__ float Bs[BK][BN + 4];
    int tid = threadIdx.x;
    int tx = tid % (BN / TN), ty = tid / (BN / TN);
    int row0 = blockIdx.y * BM;
    int col0 = blockIdx.x * BN;
    int kbase = 0, kend = K;
    if constexpr (SPLITK) {
        int nz = gridDim.z;
        int kchunk = (((K + nz - 1) / nz) + BK - 1) / BK * BK;
        kbase = blockIdx.z * kchunk;
        kend = kbase + kchunk;
        if (kend > K) kend = K;
    }
    int kk = tid % 16, ld = tid / 16;
    float ra[AI], rb[BI];
    auto loadA = [&](int k0, float* r) {
        int gk = k0 + kk;
#pragma unroll
        for (int i = 0; i < AI; ++i) {
            int gr = row0 + ld + 16 * i;
            float v = 0.f;
            if ((!GUARD && !SPLITK) || (gr < M && gk < kend)) v = A[(size_t)gr * K + gk];
            r[i] = v;
        }
    };
    auto loadB = [&](int k0, float* r) {
        int gk = k0 + kk;
#pragma unroll
        for (int i = 0; i < BI; ++i) {
            int gn = col0 + ld + 16 * i;
            float v = 0.f;
            if ((!GUARD && !SPLITK) || (gn < N && gk < kend)) v = B[(size_t)gn * K + gk];
            r[i] = v;
        }
    };
    auto stash = [&]() {
#pragma unroll
        for (int i = 0; i < AI; ++i) As[kk][ld + 16 * i] = ra[i];
#pragma unroll
        for (int i = 0; i < BI; ++i) Bs[kk][ld + 16 * i] = rb[i];
    };
    float acc[TM][TN] = {};
    int nt = (kend - kbase + BK - 1) / BK;
    loadA(kbase, ra); loadB(kbase, rb);
    stash();
    __syncthreads();
    for (int t = 0; t < nt; ++t) {
        bool more = (t + 1 < nt);
        if (more) { loadA(kbase + (t + 1) * BK, ra); loadB(kbase + (t + 1) * BK, rb); }
#pragma unroll
        for (int k = 0; k < BK; ++k) {
            float a[TM], b[TN];
            *(float4*)&a[0] = *(const float4*)&As[k][ty * TM];
            if constexpr (TM == 8) *(float4*)&a[4] = *(const float4*)&As[k][ty * TM + 4];
            *(float4*)&b[0] = *(const float4*)&Bs[k][tx * TN];
            if constexpr (TN == 8) *(float4*)&b[4] = *(const float4*)&Bs[k][tx * TN + 4];
#pragma unroll
            for (int i = 0; i < TM; ++i)
#pragma unroll
                for (int j = 0; j < TN; ++j) acc[i][j] += a[i] * b[j];
        }
        if (more) {
            __syncthreads();
            stash();
            __syncthreads();
        }
    }
    if constexpr (ARGMAX) {
        __shared__ unsigned long long red[BM][17];
#pragma unroll
        for (int i = 0; i < TM; ++i) {
            unsigned long long best = 0;
#pragma unroll
            for (int j = 0; j < TN; ++j) {
                int gc = col0 + tx * TN + j;
                float v = acc[i][j] * colscale[gc];
                unsigned u = __float_as_uint(v);
                unsigned ukey = (u & 0x80000000u) ? ~u : (u | 0x80000000u);
                unsigned long long key =
                    ((unsigned long long)ukey << 32) | (unsigned)(N - 1 - gc);
                if (key > best) best = key;
            }
            red[ty * TM + i][tx] = best;
        }
        __syncthreads();
        if (tid < BM) {
            unsigned long long best = 0;
#pragma unroll
            for (int q = 0; q < 16; ++q) {
                unsigned long long v = red[tid][q];
                if (v > best) best = v;
            }
            atomicMax(&keymax[row0 + tid], best);
        }
    } else {
#pragma unroll
        for (int i = 0; i < TM; ++i) {
            int gr = row0 + ty * TM + i;
            if (GUARD && gr >= M) continue;
#pragma unroll
            for (int j = 0; j < TN; ++j) {
                int gc = col0 + tx * TN + j;
                if (GUARD && gc >= N) continue;
                float v = acc[i][j];
                if constexpr (SPLITK) {
                    if (bias && blockIdx.z == 0) v += bias[gc];
                    atomicAdd(&C[(size_t)gr * N + gc], v);
                } else {
                    if (bias) v += bias[gc];
                    C[(size_t)gr * N + gc] = v;
                }
            }
        }
    }
}

// ---------------- G = mnew^T diag(1/||mnew_k||) mnew, split-K, reg-prefetch ----------------
__global__ __launch_bounds__(256) void gemm_tn_g(const float* __restrict__ mnew,
                                                 const float* __restrict__ nrm2,
                                                 float* __restrict__ G, int kchunk) {
    constexpr int BK = 16;
    __shared__ float As[BK][64];
    __shared__ float Bs[BK][64];
    int tid = threadIdx.x;
    int tx = tid % 16, ty = tid / 16;
    int c0 = blockIdx.y * 64, d0 = blockIdx.x * 64;
    int kbase = blockIdx.z * kchunk;
    int cl = tid % 64, kk0 = tid / 64;
    int gc0 = c0 + cl, gd0 = d0 + cl;
    bool cok = gc0 < CD, dok = gd0 < CD;
    float pa[4], pb[4];
    auto ld = [&](int k0) {
#pragma unroll
        for (int i = 0; i < 4; ++i) {
            int gk = k0 + kk0 + 4 * i;
            float s = 1.0f / fmaxf(nrm2[gk], 1e-12f);
            pa[i] = cok ? mnew[(size_t)gk * CD + gc0] * s : 0.f;
            pb[i] = dok ? mnew[(size_t)gk * CD + gd0] : 0.f;
        }
    };
    auto stash = [&]() {
#pragma unroll
        for (int i = 0; i < 4; ++i) {
            As[kk0 + 4 * i][cl] = pa[i];
            Bs[kk0 + 4 * i][cl] = pb[i];
        }
    };
    float acc[4][4] = {};
    int nt = kchunk / BK;
    ld(kbase); stash(); __syncthreads();
    for (int t = 0; t < nt; ++t) {
        bool more = (t + 1 < nt);
        if (more) ld(kbase + (t + 1) * BK);
#pragma unroll
        for (int k = 0; k < BK; ++k) {
            float a[4], b[4];
            *(float4*)&a[0] = *(const float4*)&As[k][ty * 4];
            *(float4*)&b[0] = *(const float4*)&Bs[k][tx * 4];
#pragma unroll
            for (int i = 0; i < 4; ++i)
#pragma unroll
                for (int j = 0; j < 4; ++j) acc[i][j] += a[i] * b[j];
        }
        if (more) { __syncthreads(); stash(); __syncthreads(); }
    }
#pragma unroll
    for (int i = 0; i < 4; ++i) {
        int gc = c0 + ty * 4 + i;
        if (gc >= CD) continue;
#pragma unroll
        for (int j = 0; j < 4; ++j) {
            int gd = d0 + tx * 4 + j;
            if (gd >= CD) continue;
            atomicAdd(&G[(size_t)gc * CD + gd], acc[i][j]);
        }
    }
}

// ---------------- helpers ----------------

__global__ __launch_bounds__(BLK) void rownorm_k(const float* __restrict__ in,
                                                 float* __restrict__ nrm, int rows, int cols) {
    int row  = blockIdx.x * (BLK / 64) + ((int)threadIdx.x / 64);
    int lane = threadIdx.x & 63;
    if (row >= rows) return;
    const float* p = in + (size_t)row * cols;
    float s = 0.f;
    for (int c = lane; c < cols; c += 64) { float v = p[c]; s += v * v; }
#pragma unroll
    for (int off = 32; off; off >>= 1) s += __shfl_down(s, off);
    if (lane == 0) nrm[row] = sqrtf(s);
}

__global__ __launch_bounds__(BLK) void scatter_k(const float* __restrict__ xx,
                                                 const unsigned long long* __restrict__ kb,
                                                 float* __restrict__ esum,
                                                 float* __restrict__ counts) {
    int idx = blockIdx.x * BLK + threadIdx.x;
    if (idx >= BB * CD) return;
    int n = idx / CD, c = idx % CD;
    int k = (KD - 1) - (int)(unsigned)(kb[n] & 0xffffffffull);
    atomicAdd(&esum[(size_t)k * CD + c], xx[idx]);
    if (c == 0) atomicAdd(&counts[k], 1.0f);
}

__global__ __launch_bounds__(BLK) void ss2_k(const float* __restrict__ esum,
                                             const float* __restrict__ counts,
                                             float* __restrict__ ss) {
    int k0 = blockIdx.x * 8;
    int tid = threadIdx.x;
    float a0 = 0.f, a1 = 0.f;
    for (int r = 0; r < 8; ++r) {
        int k = k0 + r;
        float rc = 1.0f / (counts[k] + 1e-6f);
        a0 += esum[(size_t)k * CD + tid] * rc;
        if (tid < CD - BLK) a1 += esum[(size_t)k * CD + BLK + tid] * rc;
    }
    atomicAdd(&ss[tid], a0);
    if (tid < CD - BLK) atomicAdd(&ss[BLK + tid], a1);
}

__global__ __launch_bounds__(BLK) void mnew_k(const float* __restrict__ m,
                                              const float* __restrict__ esum,
                                              const float* __restrict__ counts,
                                              const float* __restrict__ ss,
                                              float* __restrict__ mnew) {
    int idx = blockIdx.x * BLK + threadIdx.x;
    if (idx >= KD * CD) return;
    int k = idx / CD, c = idx % CD;
    float mean = esum[idx] / (counts[k] + 1e-6f);
    float pd = (mean - ss[c]) * (2.0f / ((float)KD * (float)(KD - 1)));
    mnew[idx] = m[idx] * 0.99f + (mean + pd) * 0.01f;
}

// Q[o][c] = sum_i cls_w[o][i] * up_w[i][c]
__global__ __launch_bounds__(BLK) void q_k(const float* __restrict__ cls_w,
                                           const float* __restrict__ up_w,
                                           float* __restrict__ Q) {
    int idx = blockIdx.x * BLK + threadIdx.x;
    if (idx >= 16 * CD) return;
    int o = idx / CD, c = idx % CD;
    float s = 0.f;
    for (int i = 0; i < CD; ++i) s += cls_w[o * CD + i] * up_w[(size_t)i * CD + c];
    Q[idx] = s;
}

// bias2[o] = cls_b[o] - sum_i up_b[i]*cls_w[o][i]
__global__ __launch_bounds__(64) void bias2_k(const float* __restrict__ cls_w,
                                              const float* __restrict__ up_b,
                                              const float* __restrict__ cls_b,
                                              float* __restrict__ bias2) {
    int o = threadIdx.x;
    if (o >= 16) return;
    float s = 0.f;
    for (int i = 0; i < CD; ++i) s += up_b[i] * cls_w[o * CD + i];
    bias2[o] = cls_b[o] - s;
}

// logits[b][o] = bias2[o] + fea[b].cls_w[o] - (t1[b]/u[b]) * Y[b].Q[o]
__global__ __launch_bounds__(BLK) void cls2_k(const float* __restrict__ fea,
                                              const float* __restrict__ Y,
                                              const float* __restrict__ t1,
                                              const float* __restrict__ u,
                                              const float* __restrict__ cls_w,
                                              const float* __restrict__ Q,
                                              const float* __restrict__ bias2,
                                              float* __restrict__ out) {
    int t = blockIdx.x * BLK + threadIdx.x;
    if (t >= BB * 16) return;
    int o = t % 16, b = t / 16;
    float rs = t1[b] / u[b];
    const float* fp = fea + (size_t)b * CD;
    const float* yp = Y + (size_t)b * CD;
    const float* cw = cls_w + o * CD;
    const float* qp = Q + o * CD;
    float a1 = 0.f, a2 = 0.f;
    for (int i = 0; i < CD; ++i) { a1 += fp[i] * cw[i]; a2 += yp[i] * qp[i]; }
    out[t] = bias2[o] + a1 - rs * a2;
}

// ---------------- launch ----------------

static inline int cdiv(int a, int b) { return (a + b - 1) / b; }

extern "C" void kernel_launch(void* const* d_in, const int* in_sizes, int n_in,
                              void* d_out, int out_size, void* d_ws, size_t ws_size,
                              hipStream_t stream) {
    const float* x       = (const float*)d_in[0];
    const float* conv1_w = (const float*)d_in[1];
    const float* conv1_b = (const float*)d_in[2];
    const float* pool1_w = (const float*)d_in[3];
    const float* pool1_b = (const float*)d_in[4];
    const float* conv2_w = (const float*)d_in[5];
    const float* conv2_b = (const float*)d_in[6];
    const float* pool2_w = (const float*)d_in[7];
    const float* pool2_b = (const float*)d_in[8];
    const float* conv3_w = (const float*)d_in[9];
    const float* conv3_b = (const float*)d_in[10];
    const float* conv4_w = (const float*)d_in[11];
    const float* conv4_b = (const float*)d_in[12];
    const float* feat_w  = (const float*)d_in[13];
    const float* feat_b  = (const float*)d_in[14];
    const float* feat1_w = (const float*)d_in[15];
    const float* feat1_b = (const float*)d_in[16];
    const float* mem     = (const float*)d_in[17];
    const float* up_w    = (const float*)d_in[18];
    const float* up_b    = (const float*)d_in[19];
    const float* cls_w   = (const float*)d_in[20];
    const float* cls_b   = (const float*)d_in[21];
    float* outp = (float*)d_out;

    float* ws = (float*)d_ws;
    size_t off = 0;
    auto alloc = [&](size_t n) { float* p = ws + off; off += n; return p; };

    unsigned long long* keybuf = (unsigned long long*)alloc(2 * BB);  // 8B aligned (off=0)
    float* h2c   = alloc((size_t)CH2 * 17820);
    float* h3    = alloc((size_t)BB * 35 * 99);
    float* h6    = alloc((size_t)BB * 910);
    float* fea   = alloc((size_t)BB * CD);   // fea,xx,Y contiguous -> one memset
    float* xx    = alloc((size_t)BB * CD);
    float* Y     = alloc((size_t)BB * CD);
    float* counts= alloc(KD);                // counts,esum,ssb contiguous -> one memset
    float* esum  = alloc((size_t)KD * CD);
    float* ssb   = alloc(CD);
    float* mnewb = alloc((size_t)KD * CD);
    float* G     = alloc((size_t)CD * CD);
    float* t1    = alloc(BB);
    float* u     = alloc(BB);
    float* Q     = alloc((size_t)16 * CD);
    float* bias2 = alloc(16);
    float* mnrm  = alloc(KD);
    float* nrm2  = alloc(KD);

    hipMemsetAsync(keybuf, 0, BB * sizeof(unsigned long long), stream);
    hipMemsetAsync(counts, 0, (KD + (size_t)KD * CD + CD) * sizeof(float), stream);
    hipMemsetAsync(fea, 0, (size_t)3 * BB * CD * sizeof(float), stream);
    hipMemsetAsync(G, 0, (size_t)CD * CD * sizeof(float), stream);

    // weight-only precomputes
    q_k<<<cdiv(16 * CD, BLK), BLK, 0, stream>>>(cls_w, up_w, Q);
    bias2_k<<<1, 64, 0, stream>>>(cls_w, up_b, cls_b, bias2);
    rownorm_k<<<cdiv(KD, 4), BLK, 0, stream>>>(mem, mnrm, KD, CD);

    // conv stack
    for (int ch = 0; ch < NCH2; ++ch) {
        int b0 = ch * CH2;
        dim3 g12(CH2, 3);
        fused12_k<<<g12, 256, 0, stream>>>(x, conv1_w, conv1_b, pool1_w, pool1_b, h2c, b0);
        conv2b_k<<<CH2, 256, 0, stream>>>(h2c, conv2_w, conv2_b, h3, b0);
    }
    fused345_k<<<BB, 256, 0, stream>>>(h3, pool2_w, pool2_b, conv3_w, conv3_b,
                                       conv4_w, conv4_b, h6);

    // fea = h6 @ feat_w^T + feat_b ; xx = fea @ feat1_w^T + feat1_b (split-K=2)
    {
        dim3 g(cdiv(CD, 64), BB / 64, 2);
        gemm_nt<64, 64, 4, 4, true, false, true><<<g, 256, 0, stream>>>(
            h6, feat_w, feat_b, fea, nullptr, nullptr, BB, CD, 910);
        gemm_nt<64, 64, 4, 4, true, false, true><<<g, 256, 0, stream>>>(
            fea, feat1_w, feat1_b, xx, nullptr, nullptr, BB, CD, CD);
    }

    rownorm_k<<<cdiv(BB, 4), BLK, 0, stream>>>(xx, t1, BB, CD);  // tend_1

    // fused score1 + argmax: raw = xx @ mem^T, key scaled by 1/||mem_k||
    {
        dim3 g(KD / 128, BB / 128);
        gemm_nt<128, 128, 8, 8, false, true, false><<<g, 256, 0, stream>>>(
            xx, mem, nullptr, nullptr, mnrm, keybuf, BB, KD, CD);
    }
    scatter_k<<<cdiv(BB * CD, BLK), BLK, 0, stream>>>(xx, keybuf, esum, counts);
    ss2_k<<<KD / 8, BLK, 0, stream>>>(esum, counts, ssb);
    mnew_k<<<cdiv(KD * CD, BLK), BLK, 0, stream>>>(mem, esum, counts, ssb, mnewb);

    rownorm_k<<<cdiv(KD, 4), BLK, 0, stream>>>(mnewb, nrm2, KD, CD);

    // G = mnew^T diag(1/||mnew_k||) mnew (symmetric), split-K over 8 chunks
    {
        dim3 g(cdiv(CD, 64), cdiv(CD, 64), 8);
        gemm_tn_g<<<g, 256, 0, stream>>>(mnewb, nrm2, G, KD / 8);
    }
    // Y = xx @ G (G symmetric -> NT form valid), split-K=2
    {
        dim3 g(cdiv(CD, 64), BB / 64, 2);
        gemm_nt<64, 64, 4, 4, true, false, true><<<g, 256, 0, stream>>>(
            xx, G, nullptr, Y, nullptr, nullptr, BB, CD, CD);
    }
    rownorm_k<<<cdiv(BB, 4), BLK, 0, stream>>>(Y, u, BB, CD);    // tend * t1g

    // logits = bias2 + fea@cls_w^T - (t1/u) * Y@Q^T
    cls2_k<<<cdiv(BB * 16, BLK), BLK, 0, stream>>>(fea, Y, t1, u, cls_w, Q, bias2, outp);
}